// Round 1
// baseline (4516.139 us; speedup 1.0000x reference)
//
#include <hip/hip_runtime.h>
#include <hip/hip_bf16.h>
#include <math.h>

#define BATCH 2
#define SEQL 2048
#define T 4096            // BATCH*SEQL tokens
#define DMODEL 1024
#define DINNER 2048
#define DSTATE 128
#define NH 32
#define HD 64
#define DPROJ 4384        // D_IN_PROJ
#define CONVCH 2304
#define NCH 16            // chunks per sequence
#define CHUNK 128
#define EPS 1e-5f

// ---------------- block reduce ----------------
__device__ __forceinline__ float blockReduceSum(float v) {
    __shared__ float red_[4];
    for (int off = 32; off > 0; off >>= 1) v += __shfl_down(v, off);
    int lane = threadIdx.x & 63, wid = threadIdx.x >> 6;
    if (lane == 0) red_[wid] = v;
    __syncthreads();
    if (threadIdx.x == 0) {
        float s = 0.f;
        int nw = blockDim.x >> 6;
        for (int i = 0; i < nw; ++i) s += red_[i];
        red_[0] = s;
    }
    __syncthreads();
    return red_[0];
}

// ---------------- input rmsnorm ----------------
__global__ __launch_bounds__(256) void k_rmsnorm(
    const float* __restrict__ x, const float* __restrict__ w,
    float* __restrict__ out, int ncol)
{
    int row = blockIdx.x;
    const float* xr = x + (size_t)row * ncol;
    float ss = 0.f;
    for (int i = threadIdx.x; i < ncol; i += blockDim.x) { float v = xr[i]; ss += v * v; }
    float tot = blockReduceSum(ss);
    float sc = rsqrtf(tot / ncol + EPS);
    for (int i = threadIdx.x; i < ncol; i += blockDim.x)
        out[(size_t)row * ncol + i] = xr[i] * sc * w[i];
}

// ---------------- generic fp32 GEMM: C[r,n] = sum_k A[src(r),k] * W[n,k] ----------------
#define GBM 64
#define GBN 64
#define GBK 16
__global__ __launch_bounds__(256) void k_gemm(
    const float* __restrict__ A, const float* __restrict__ W,
    float* __restrict__ C, int N, int K, int ldc, int flip,
    const float* __restrict__ bias, const float* __restrict__ resid, int ldr)
{
    __shared__ float As[GBK][GBM + 1];
    __shared__ float Ws[GBK][GBN + 1];
    int tid = threadIdx.x;
    int tm = tid & 15, tn = tid >> 4;
    int m0 = blockIdx.y * GBM, n0 = blockIdx.x * GBN;
    float acc[4][4] = {};
    for (int kt = 0; kt < K; kt += GBK) {
        for (int i = tid; i < GBM * GBK; i += 256) {
            int m = i >> 4, k = i & 15;
            int r = m0 + m;
            int sr = flip ? ((r & ~(SEQL - 1)) | (SEQL - 1 - (r & (SEQL - 1)))) : r;
            As[k][m] = A[(size_t)sr * K + kt + k];
        }
        for (int i = tid; i < GBN * GBK; i += 256) {
            int n = i >> 4, k = i & 15;
            int gn = n0 + n;
            Ws[k][n] = (gn < N) ? W[(size_t)gn * K + kt + k] : 0.f;
        }
        __syncthreads();
        #pragma unroll
        for (int k = 0; k < GBK; ++k) {
            float av[4], bv[4];
            #pragma unroll
            for (int u = 0; u < 4; ++u) av[u] = As[k][tm * 4 + u];
            #pragma unroll
            for (int v = 0; v < 4; ++v) bv[v] = Ws[k][tn * 4 + v];
            #pragma unroll
            for (int u = 0; u < 4; ++u)
                #pragma unroll
                for (int v = 0; v < 4; ++v) acc[u][v] += av[u] * bv[v];
        }
        __syncthreads();
    }
    for (int u = 0; u < 4; ++u) {
        int r = m0 + tm * 4 + u;
        for (int v = 0; v < 4; ++v) {
            int n = n0 + tn * 4 + v;
            if (n < N) {
                float val = acc[u][v];
                if (bias)  val += bias[n];
                if (resid) val += resid[(size_t)r * ldr + n];
                C[(size_t)r * ldc + n] = val;
            }
        }
    }
}

// ---------------- dt = softplus(raw + bias) ----------------
__global__ void k_dt(const float* __restrict__ zx, const float* __restrict__ dtb,
                     float* __restrict__ dt)
{
    int i = blockIdx.x * blockDim.x + threadIdx.x;
    if (i >= T * NH) return;
    int r = i / NH, h = i - r * NH;
    float v = zx[(size_t)r * DPROJ + DINNER + CONVCH + h] + dtb[h];
    dt[i] = (v > 20.f) ? v : log1pf(expf(v));
}

// ---------------- causal depthwise conv-4 + silu ----------------
__global__ void k_conv(const float* __restrict__ zx, const float* __restrict__ cw,
                       const float* __restrict__ cb, float* __restrict__ out)
{
    int i = blockIdx.x * blockDim.x + threadIdx.x;
    if (i >= T * CONVCH) return;
    int r = i / CONVCH, ch = i - r * CONVCH;
    int t = r & (SEQL - 1);
    int b0 = r - t;
    float acc = cb[ch];
    #pragma unroll
    for (int k = 0; k < 4; ++k) {
        int tt = t + k - 3;
        if (tt >= 0) acc += zx[(size_t)(b0 + tt) * DPROJ + DINNER + ch] * cw[ch * 4 + k];
    }
    out[i] = acc / (1.f + expf(-acc));
}

// ---------------- per-chunk cumsum of A*dt ----------------
__global__ void k_acs(const float* __restrict__ dt, const float* __restrict__ A_log,
                      float* __restrict__ acs, float* __restrict__ cd)
{
    int bid = blockIdx.x;            // (b*NH + h)*NCH + c
    int c = bid & 15;
    int bh = bid >> 4;
    int h = bh & 31;
    int b = bh >> 5;
    int l = threadIdx.x;
    __shared__ float s[128];
    float Ah = -expf(A_log[h]);
    int r = b * SEQL + c * CHUNK + l;
    s[l] = Ah * dt[(size_t)r * NH + h];
    __syncthreads();
    for (int off = 1; off < 128; off <<= 1) {
        float t = (l >= off) ? s[l - off] : 0.f;
        __syncthreads();
        s[l] += t;
        __syncthreads();
    }
    acs[(size_t)bid * 128 + l] = s[l];
    if (l == 127) cd[bid] = expf(s[127]);
}

// ---------------- per-(b,c,h): Y_diag and chunk states ----------------
__global__ __launch_bounds__(256) void k_chunk(
    const float* __restrict__ xbc, const float* __restrict__ dt,
    const float* __restrict__ acs, float* __restrict__ y, float* __restrict__ st)
{
    int h = blockIdx.x & 31;
    int bc = blockIdx.x >> 5;
    int c = bc & 15;
    int b = bc >> 4;
    int row0 = b * SEQL + c * CHUNK;
    __shared__ float Bs[16][129];
    __shared__ float Xs[16][65];
    __shared__ float Ms[128][17];
    __shared__ float acs_s[128];
    __shared__ float dec_s[128];
    int tid = threadIdx.x;
    if (tid < 128) acs_s[tid] = acs[(((size_t)(b * NH + h) * NCH + c) << 7) + tid];
    __syncthreads();
    float a_last = acs_s[127];
    if (tid < 128) dec_s[tid] = expf(a_last - acs_s[tid]);
    __syncthreads();

    int tl = tid >> 4, tp = tid & 15;     // Y: l = tl*8+u, p = tp*4+v
    int sn = tid & 127, pg = tid >> 7;    // states: n = sn, p = pg + 2*i
    float yacc[8][4] = {};
    float sacc[32] = {};

    for (int s0 = 0; s0 < 128; s0 += 16) {
        for (int i = tid; i < 16 * 128; i += 256) {
            int sl = i >> 7, n = i & 127;
            Bs[sl][n] = xbc[(size_t)(row0 + s0 + sl) * CONVCH + DINNER + n];
        }
        for (int i = tid; i < 16 * 64; i += 256) {
            int sl = i >> 6, p = i & 63;
            int rr = row0 + s0 + sl;
            Xs[sl][p] = xbc[(size_t)rr * CONVCH + h * HD + p] * dt[(size_t)rr * NH + h];
        }
        __syncthreads();
        // M[l][sl] = (s<=l) ? exp(acs[l]-acs[s]) * dot(C[l,:], B[s,:]) : 0
        for (int i = tid; i < 128 * 16; i += 256) {
            int l = i >> 4, sl = i & 15;
            int s = s0 + sl;
            float m = 0.f;
            if (s <= l) {
                const float* crow = xbc + (size_t)(row0 + l) * CONVCH + DINNER + DSTATE;
                float g = 0.f;
                #pragma unroll 4
                for (int n = 0; n < 128; ++n) g += crow[n] * Bs[sl][n];
                m = g * expf(acs_s[l] - acs_s[s]);
            }
            Ms[l][sl] = m;
        }
        __syncthreads();
        // Y_diag accumulate
        for (int sl = 0; sl < 16; ++sl) {
            float xv[4];
            #pragma unroll
            for (int v = 0; v < 4; ++v) xv[v] = Xs[sl][tp * 4 + v];
            #pragma unroll
            for (int u = 0; u < 8; ++u) {
                float m = Ms[tl * 8 + u][sl];
                #pragma unroll
                for (int v = 0; v < 4; ++v) yacc[u][v] += m * xv[v];
            }
        }
        // states accumulate: st[p,n] = sum_l B[l,n]*exp(a_last-acs[l])*X[l,p]
        for (int sl = 0; sl < 16; ++sl) {
            float bw = Bs[sl][sn] * dec_s[s0 + sl];
            #pragma unroll
            for (int i = 0; i < 32; ++i) sacc[i] += bw * Xs[sl][pg + (i << 1)];
        }
        __syncthreads();
    }
    for (int u = 0; u < 8; ++u) {
        size_t r = row0 + tl * 8 + u;
        for (int v = 0; v < 4; ++v)
            y[r * DINNER + h * HD + tp * 4 + v] = yacc[u][v];
    }
    size_t sb = (size_t)blockIdx.x * (HD * DSTATE);
    for (int i = 0; i < 32; ++i)
        st[sb + (size_t)(pg + (i << 1)) * DSTATE + sn] = sacc[i];
}

// ---------------- inter-chunk scan (in place: states -> prev) ----------------
__global__ void k_scan(float* __restrict__ st, const float* __restrict__ cd)
{
    int i = blockIdx.x * blockDim.x + threadIdx.x;
    if (i >= BATCH * NH * HD * DSTATE) return;
    int n = i & 127;
    int rest = i >> 7;
    int p = rest & 63; rest >>= 6;
    int h = rest & 31;
    int b = rest >> 5;
    float s = 0.f;
    for (int c = 0; c < NCH; ++c) {
        size_t idx = ((size_t)((b * NCH + c) * NH + h) * HD + p) * DSTATE + n;
        float v = st[idx];
        st[idx] = s;                                   // prev_c
        s = s * cd[(b * NH + h) * NCH + c] + v;        // carry
    }
}

// ---------------- Y_off += exp(acs[l]) * C @ prev^T  (+ xh*D) ----------------
__global__ __launch_bounds__(256) void k_yoff(
    const float* __restrict__ xbc, const float* __restrict__ prev,
    const float* __restrict__ acs, const float* __restrict__ Dp,
    float* __restrict__ y)
{
    int h = blockIdx.x & 31;
    int bc = blockIdx.x >> 5;
    int c = bc & 15;
    int b = bc >> 4;
    int row0 = b * SEQL + c * CHUNK;
    __shared__ float Pv[64][129];
    __shared__ float acs_s[128];
    int tid = threadIdx.x;
    size_t sb = (size_t)blockIdx.x * (HD * DSTATE);
    for (int i = tid; i < 64 * 128; i += 256) {
        int p = i >> 7, n = i & 127;
        Pv[p][n] = prev[sb + i];
    }
    if (tid < 128) acs_s[tid] = acs[(((size_t)(b * NH + h) * NCH + c) << 7) + tid];
    __syncthreads();
    int tl = tid >> 4, tp = tid & 15;
    float acc[8][4] = {};
    for (int n = 0; n < 128; ++n) {
        float pv[4];
        #pragma unroll
        for (int v = 0; v < 4; ++v) pv[v] = Pv[tp * 4 + v][n];
        #pragma unroll
        for (int u = 0; u < 8; ++u) {
            int l = tl * 8 + u;
            float cv = xbc[(size_t)(row0 + l) * CONVCH + DINNER + DSTATE + n];
            #pragma unroll
            for (int v = 0; v < 4; ++v) acc[u][v] += cv * pv[v];
        }
    }
    float Dh = Dp[h];
    for (int u = 0; u < 8; ++u) {
        int l = tl * 8 + u;
        size_t r = row0 + l;
        float e = expf(acs_s[l]);
        for (int v = 0; v < 4; ++v) {
            int p = tp * 4 + v;
            size_t yi = r * DINNER + h * HD + p;
            y[yi] += e * acc[u][v] + xbc[r * CONVCH + h * HD + p] * Dh;
        }
    }
}

// ---------------- gated rmsnorm (in place on y) ----------------
__global__ __launch_bounds__(256) void k_gate(
    float* __restrict__ y, const float* __restrict__ zx, const float* __restrict__ gw)
{
    int r = blockIdx.x;
    __shared__ float tbuf[DINNER];
    float ss = 0.f;
    for (int i = threadIdx.x; i < DINNER; i += 256) {
        float z = zx[(size_t)r * DPROJ + i];
        float t = y[(size_t)r * DINNER + i] * (z / (1.f + expf(-z)));
        tbuf[i] = t;
        ss += t * t;
    }
    float tot = blockReduceSum(ss);
    float sc = rsqrtf(tot / DINNER + EPS);
    for (int i = threadIdx.x; i < DINNER; i += 256)
        y[(size_t)r * DINNER + i] = tbuf[i] * sc * gw[i];
}

// ---------------- launch ----------------
extern "C" void kernel_launch(void* const* d_in, const int* in_sizes, int n_in,
                              void* d_out, int out_size, void* d_ws, size_t ws_size,
                              hipStream_t stream)
{
    const float* x         = (const float*)d_in[0];
    const float* norm_w    = (const float*)d_in[1];
    const float* out_w_blk = (const float*)d_in[2];
    const float* out_b_blk = (const float*)d_in[3];
    float* out = (float*)d_out;

    float* ws = (float*)d_ws;
    float* xn  = ws; ws += (size_t)T * DMODEL;
    float* zx  = ws; ws += (size_t)T * DPROJ;
    float* xbc = ws; ws += (size_t)T * CONVCH;
    float* dtb = ws; ws += (size_t)T * NH;
    float* acs = ws; ws += (size_t)BATCH * NH * NCH * CHUNK;
    float* cd  = ws; ws += (size_t)BATCH * NH * NCH;
    float* yb  = ws; ws += (size_t)T * DINNER;
    float* st  = ws; ws += (size_t)BATCH * NCH * NH * HD * DSTATE;
    float* cat = ws; ws += (size_t)T * DINNER;

    k_rmsnorm<<<T, 256, 0, stream>>>(x, norm_w, xn, DMODEL);

    for (int dir = 0; dir < 2; ++dir) {
        const float* in_w   = (const float*)d_in[4 + dir * 8 + 0];
        const float* conv_w = (const float*)d_in[4 + dir * 8 + 1];
        const float* conv_b = (const float*)d_in[4 + dir * 8 + 2];
        const float* dtbias = (const float*)d_in[4 + dir * 8 + 3];
        const float* A_log  = (const float*)d_in[4 + dir * 8 + 4];
        const float* Dp     = (const float*)d_in[4 + dir * 8 + 5];
        const float* gnw    = (const float*)d_in[4 + dir * 8 + 6];
        const float* out_w  = (const float*)d_in[4 + dir * 8 + 7];

        dim3 g1((DPROJ + GBN - 1) / GBN, T / GBM);
        k_gemm<<<g1, 256, 0, stream>>>(xn, in_w, zx, DPROJ, DMODEL, DPROJ, dir,
                                       nullptr, nullptr, 0);
        k_dt<<<(T * NH + 255) / 256, 256, 0, stream>>>(zx, dtbias, dtb);
        k_conv<<<(T * CONVCH + 255) / 256, 256, 0, stream>>>(zx, conv_w, conv_b, xbc);
        k_acs<<<BATCH * NH * NCH, 128, 0, stream>>>(dtb, A_log, acs, cd);
        k_chunk<<<BATCH * NCH * NH, 256, 0, stream>>>(xbc, dtb, acs, yb, st);
        k_scan<<<(BATCH * NH * HD * DSTATE + 255) / 256, 256, 0, stream>>>(st, cd);
        k_yoff<<<BATCH * NCH * NH, 256, 0, stream>>>(xbc, st, acs, Dp, yb);
        k_gate<<<T, 256, 0, stream>>>(yb, zx, gnw);
        dim3 g2(DMODEL / GBN, T / GBM);
        k_gemm<<<g2, 256, 0, stream>>>(yb, out_w, cat + dir * DMODEL, DMODEL, DINNER,
                                       2 * DMODEL, dir, nullptr, nullptr, 0);
    }

    dim3 g3(DMODEL / GBN, T / GBM);
    k_gemm<<<g3, 256, 0, stream>>>(cat, out_w_blk, out, DMODEL, DINNER, DMODEL, 0,
                                   out_b_blk, x, DMODEL);
}

// Round 2
// 1610.840 us; speedup vs baseline: 2.8036x; 2.8036x over previous
//
#include <hip/hip_runtime.h>
#include <hip/hip_bf16.h>
#include <math.h>

#define BATCH 2
#define SEQL 2048
#define T 4096            // BATCH*SEQL tokens
#define DMODEL 1024
#define DINNER 2048
#define DSTATE 128
#define NH 32
#define HD 64
#define DPROJ2 4352       // z (2048) + xBC (2304); dt handled separately in fp32
#define CONVCH 2304
#define NCH 16            // chunks per sequence
#define CHUNK 128
#define EPS 1e-5f

typedef unsigned short u16;
typedef __bf16 bf16x8 __attribute__((ext_vector_type(8)));
typedef float f32x4 __attribute__((ext_vector_type(4)));

__device__ __forceinline__ u16 f2b(float f) {
    union { float f; unsigned u; } v; v.f = f;
    unsigned r = v.u + 0x7fffu + ((v.u >> 16) & 1u);
    return (u16)(r >> 16);
}
__device__ __forceinline__ float b2f(u16 b) {
    union { unsigned u; float f; } v; v.u = ((unsigned)b) << 16;
    return v.f;
}
__device__ __forceinline__ int flipseq(int r) {
    return (r & ~(SEQL - 1)) | ((SEQL - 1) - (r & (SEQL - 1)));
}
__device__ __forceinline__ void gload16(const u16* g, u16* l) {
    __builtin_amdgcn_global_load_lds(
        (const __attribute__((address_space(1))) void*)g,
        (__attribute__((address_space(3))) void*)l, 16, 0, 0);
}

// ---------------- block reduce ----------------
__device__ __forceinline__ float blockReduceSum(float v) {
    __shared__ float red_[4];
    for (int off = 32; off > 0; off >>= 1) v += __shfl_down(v, off);
    int lane = threadIdx.x & 63, wid = threadIdx.x >> 6;
    if (lane == 0) red_[wid] = v;
    __syncthreads();
    if (threadIdx.x == 0) {
        float s = 0.f;
        int nw = blockDim.x >> 6;
        for (int i = 0; i < nw; ++i) s += red_[i];
        red_[0] = s;
    }
    __syncthreads();
    return red_[0];
}

// ---------------- input rmsnorm: writes fp32 and bf16 copies ----------------
__global__ __launch_bounds__(256) void k_rmsnorm(
    const float* __restrict__ x, const float* __restrict__ w,
    float* __restrict__ outf, u16* __restrict__ outb)
{
    int row = blockIdx.x;
    const float* xr = x + (size_t)row * DMODEL;
    float ss = 0.f;
    for (int i = threadIdx.x; i < DMODEL; i += 256) { float v = xr[i]; ss += v * v; }
    float tot = blockReduceSum(ss);
    float sc = rsqrtf(tot / DMODEL + EPS);
    for (int i = threadIdx.x; i < DMODEL; i += 256) {
        float v = xr[i] * sc * w[i];
        outf[(size_t)row * DMODEL + i] = v;
        outb[(size_t)row * DMODEL + i] = f2b(v);
    }
}

// ---------------- fp32 -> bf16 conversion ----------------
__global__ void k_f2b(const float* __restrict__ s, u16* __restrict__ d, int n)
{
    int i = (blockIdx.x * blockDim.x + threadIdx.x) * 4;
    if (i >= n) return;
    float4 v = *(const float4*)(s + i);
    ushort4 o;
    o.x = f2b(v.x); o.y = f2b(v.y); o.z = f2b(v.z); o.w = f2b(v.w);
    *(ushort4*)(d + i) = o;
}

// ---------------- bf16 MFMA GEMM: C[r,n] = sum_k A[src(r),k] * W[n,k] ----------------
// 128x128 tile, BK=32, 256 thr = 4 waves, each wave 64x64 (4x4 MFMA 16x16x32).
// m97 structure: global_load_lds width 16, unpadded LDS [row][32].
__global__ __launch_bounds__(256) void k_mm(
    const u16* __restrict__ A, const u16* __restrict__ W, int K, int flip,
    u16* __restrict__ Cb, float* __restrict__ Cf, int ldc, int coff,
    const float* __restrict__ bias, const float* __restrict__ resid, int ldr)
{
    __shared__ u16 As[128 * 32];
    __shared__ u16 Bs[128 * 32];
    int tid = threadIdx.x;
    int lane = tid & 63;
    int m0 = blockIdx.y * 128, n0 = blockIdx.x * 128;
    int wrow = ((tid >> 6) & 1) * 64, wcol = (tid >> 7) * 64;

    int srow = tid >> 2, skof = (tid & 3) * 8;
    int ar1 = m0 + srow, ar2 = ar1 + 64;
    if (flip) { ar1 = flipseq(ar1); ar2 = flipseq(ar2); }
    const u16* ga1 = A + (size_t)ar1 * K + skof;
    const u16* ga2 = A + (size_t)ar2 * K + skof;
    const u16* gb1 = W + (size_t)(n0 + srow) * K + skof;
    const u16* gb2 = gb1 + (size_t)64 * K;
    u16* la1 = As + tid * 8;
    u16* la2 = As + 2048 + tid * 8;
    u16* lb1 = Bs + tid * 8;
    u16* lb2 = Bs + 2048 + tid * 8;

    // fragment LDS offsets
    int aoff[4], boff[4];
    #pragma unroll
    for (int i = 0; i < 4; ++i) {
        aoff[i] = (wrow + i * 16 + (lane & 15)) * 32 + ((lane >> 4) * 8);
        boff[i] = (wcol + i * 16 + (lane & 15)) * 32 + ((lane >> 4) * 8);
    }

    f32x4 acc[4][4] = {};
    for (int kt = 0; kt < K; kt += 32) {
        gload16(ga1, la1); gload16(ga2, la2);
        gload16(gb1, lb1); gload16(gb2, lb2);
        ga1 += 32; ga2 += 32; gb1 += 32; gb2 += 32;
        __syncthreads();
        bf16x8 af[4], bf[4];
        #pragma unroll
        for (int i = 0; i < 4; ++i) af[i] = *(const bf16x8*)(As + aoff[i]);
        #pragma unroll
        for (int j = 0; j < 4; ++j) bf[j] = *(const bf16x8*)(Bs + boff[j]);
        #pragma unroll
        for (int i = 0; i < 4; ++i)
            #pragma unroll
            for (int j = 0; j < 4; ++j)
                acc[i][j] = __builtin_amdgcn_mfma_f32_16x16x32_bf16(af[i], bf[j], acc[i][j], 0, 0, 0);
        __syncthreads();
    }

    int rbase = m0 + wrow + ((lane >> 4) << 2);
    int cbase = n0 + wcol + (lane & 15);
    if (Cb) {
        #pragma unroll
        for (int i = 0; i < 4; ++i)
            #pragma unroll
            for (int j = 0; j < 4; ++j)
                #pragma unroll
                for (int r = 0; r < 4; ++r)
                    Cb[(size_t)(rbase + i * 16 + r) * ldc + coff + cbase + j * 16] = f2b(acc[i][j][r]);
    } else {
        #pragma unroll
        for (int i = 0; i < 4; ++i)
            #pragma unroll
            for (int j = 0; j < 4; ++j)
                #pragma unroll
                for (int r = 0; r < 4; ++r) {
                    int row = rbase + i * 16 + r, col = cbase + j * 16;
                    float v = acc[i][j][r];
                    if (bias)  v += bias[col];
                    if (resid) v += resid[(size_t)row * ldr + col];
                    Cf[(size_t)row * ldc + coff + col] = v;
                }
    }
}

// ---------------- dt = softplus(xn . w_dt + bias), fp32 ----------------
__global__ __launch_bounds__(256) void k_dt2(
    const float* __restrict__ xn, const float* __restrict__ in_w,
    const float* __restrict__ dtb, float* __restrict__ dt, int flip)
{
    int row = blockIdx.x;
    int src = flip ? flipseq(row) : row;
    __shared__ float xs[1024];
    ((float4*)xs)[threadIdx.x] = ((const float4*)(xn + (size_t)src * DMODEL))[threadIdx.x];
    __syncthreads();
    int h = threadIdx.x >> 3, part = threadIdx.x & 7;
    const float* w = in_w + (size_t)(DPROJ2 + h) * DMODEL;
    float s = 0.f;
    for (int kk = 0; kk < 128; ++kk) {
        int k = part + (kk << 3);
        s += xs[k] * w[k];
    }
    s += __shfl_down(s, 4, 8);
    s += __shfl_down(s, 2, 8);
    s += __shfl_down(s, 1, 8);
    if (part == 0) {
        float v = s + dtb[h];
        dt[(size_t)row * NH + h] = (v > 20.f) ? v : log1pf(expf(v));
    }
}

// ---------------- causal depthwise conv-4 + silu (bf16 in, fp32 out) ----------------
__global__ void k_conv(const u16* __restrict__ zx, const float* __restrict__ cw,
                       const float* __restrict__ cb, float* __restrict__ out)
{
    int i = blockIdx.x * blockDim.x + threadIdx.x;
    if (i >= T * CONVCH) return;
    int r = i / CONVCH, ch = i - r * CONVCH;
    int t = r & (SEQL - 1);
    int b0 = r - t;
    float acc = cb[ch];
    #pragma unroll
    for (int k = 0; k < 4; ++k) {
        int tt = t + k - 3;
        if (tt >= 0) acc += b2f(zx[(size_t)(b0 + tt) * DPROJ2 + DINNER + ch]) * cw[ch * 4 + k];
    }
    out[i] = acc / (1.f + expf(-acc));
}

// ---------------- per-chunk cumsum of A*dt ----------------
__global__ void k_acs(const float* __restrict__ dt, const float* __restrict__ A_log,
                      float* __restrict__ acs, float* __restrict__ cd)
{
    int bid = blockIdx.x;            // (b*NH + h)*NCH + c
    int c = bid & 15;
    int bh = bid >> 4;
    int h = bh & 31;
    int b = bh >> 5;
    int l = threadIdx.x;
    __shared__ float s[128];
    float Ah = -expf(A_log[h]);
    int r = b * SEQL + c * CHUNK + l;
    s[l] = Ah * dt[(size_t)r * NH + h];
    __syncthreads();
    for (int off = 1; off < 128; off <<= 1) {
        float t = (l >= off) ? s[l - off] : 0.f;
        __syncthreads();
        s[l] += t;
        __syncthreads();
    }
    acs[(size_t)bid * 128 + l] = s[l];
    if (l == 127) cd[bid] = expf(s[127]);
}

// ---------------- per-(b,c,h): Y_diag and chunk states ----------------
__global__ __launch_bounds__(256) void k_chunk(
    const float* __restrict__ xbc, const float* __restrict__ dt,
    const float* __restrict__ acs, float* __restrict__ y, float* __restrict__ st)
{
    int h = blockIdx.x & 31;
    int bc = blockIdx.x >> 5;
    int c = bc & 15;
    int b = bc >> 4;
    int row0 = b * SEQL + c * CHUNK;
    __shared__ float Bs[16][129];
    __shared__ float Xs[16][65];
    __shared__ float Ms[128][17];
    __shared__ float acs_s[128];
    __shared__ float dec_s[128];
    int tid = threadIdx.x;
    if (tid < 128) acs_s[tid] = acs[(((size_t)(b * NH + h) * NCH + c) << 7) + tid];
    __syncthreads();
    float a_last = acs_s[127];
    if (tid < 128) dec_s[tid] = expf(a_last - acs_s[tid]);
    __syncthreads();

    int tl = tid >> 4, tp = tid & 15;     // Y: l = tl*8+u, p = tp*4+v
    int sn = tid & 127, pg = tid >> 7;    // states: n = sn, p = pg + 2*i
    float yacc[8][4] = {};
    float sacc[32] = {};

    for (int s0 = 0; s0 < 128; s0 += 16) {
        for (int i = tid; i < 16 * 128; i += 256) {
            int sl = i >> 7, n = i & 127;
            Bs[sl][n] = xbc[(size_t)(row0 + s0 + sl) * CONVCH + DINNER + n];
        }
        for (int i = tid; i < 16 * 64; i += 256) {
            int sl = i >> 6, p = i & 63;
            int rr = row0 + s0 + sl;
            Xs[sl][p] = xbc[(size_t)rr * CONVCH + h * HD + p] * dt[(size_t)rr * NH + h];
        }
        __syncthreads();
        for (int i = tid; i < 128 * 16; i += 256) {
            int l = i >> 4, sl = i & 15;
            int s = s0 + sl;
            float m = 0.f;
            if (s <= l) {
                const float* crow = xbc + (size_t)(row0 + l) * CONVCH + DINNER + DSTATE;
                float g = 0.f;
                #pragma unroll 4
                for (int n = 0; n < 128; ++n) g += crow[n] * Bs[sl][n];
                m = g * expf(acs_s[l] - acs_s[s]);
            }
            Ms[l][sl] = m;
        }
        __syncthreads();
        for (int sl = 0; sl < 16; ++sl) {
            float xv[4];
            #pragma unroll
            for (int v = 0; v < 4; ++v) xv[v] = Xs[sl][tp * 4 + v];
            #pragma unroll
            for (int u = 0; u < 8; ++u) {
                float m = Ms[tl * 8 + u][sl];
                #pragma unroll
                for (int v = 0; v < 4; ++v) yacc[u][v] += m * xv[v];
            }
        }
        for (int sl = 0; sl < 16; ++sl) {
            float bw = Bs[sl][sn] * dec_s[s0 + sl];
            #pragma unroll
            for (int i = 0; i < 32; ++i) sacc[i] += bw * Xs[sl][pg + (i << 1)];
        }
        __syncthreads();
    }
    for (int u = 0; u < 8; ++u) {
        size_t r = row0 + tl * 8 + u;
        for (int v = 0; v < 4; ++v)
            y[r * DINNER + h * HD + tp * 4 + v] = yacc[u][v];
    }
    size_t sb = (size_t)blockIdx.x * (HD * DSTATE);
    for (int i = 0; i < 32; ++i)
        st[sb + (size_t)(pg + (i << 1)) * DSTATE + sn] = sacc[i];
}

// ---------------- inter-chunk scan (in place: states -> prev) ----------------
__global__ void k_scan(float* __restrict__ st, const float* __restrict__ cd)
{
    int i = blockIdx.x * blockDim.x + threadIdx.x;
    if (i >= BATCH * NH * HD * DSTATE) return;
    int n = i & 127;
    int rest = i >> 7;
    int p = rest & 63; rest >>= 6;
    int h = rest & 31;
    int b = rest >> 5;
    float s = 0.f;
    for (int c = 0; c < NCH; ++c) {
        size_t idx = ((size_t)((b * NCH + c) * NH + h) * HD + p) * DSTATE + n;
        float v = st[idx];
        st[idx] = s;                                   // prev_c
        s = s * cd[(b * NH + h) * NCH + c] + v;        // carry
    }
}

// ---------------- Y_off += exp(acs[l]) * C @ prev^T  (+ xh*D) ----------------
__global__ __launch_bounds__(256) void k_yoff(
    const float* __restrict__ xbc, const float* __restrict__ prev,
    const float* __restrict__ acs, const float* __restrict__ Dp,
    float* __restrict__ y)
{
    int h = blockIdx.x & 31;
    int bc = blockIdx.x >> 5;
    int c = bc & 15;
    int b = bc >> 4;
    int row0 = b * SEQL + c * CHUNK;
    __shared__ float Pv[64][129];
    __shared__ float acs_s[128];
    int tid = threadIdx.x;
    size_t sb = (size_t)blockIdx.x * (HD * DSTATE);
    for (int i = tid; i < 64 * 128; i += 256) {
        int p = i >> 7, n = i & 127;
        Pv[p][n] = prev[sb + i];
    }
    if (tid < 128) acs_s[tid] = acs[(((size_t)(b * NH + h) * NCH + c) << 7) + tid];
    __syncthreads();
    int tl = tid >> 4, tp = tid & 15;
    float acc[8][4] = {};
    for (int n = 0; n < 128; ++n) {
        float pv[4];
        #pragma unroll
        for (int v = 0; v < 4; ++v) pv[v] = Pv[tp * 4 + v][n];
        #pragma unroll
        for (int u = 0; u < 8; ++u) {
            int l = tl * 8 + u;
            float cv = xbc[(size_t)(row0 + l) * CONVCH + DINNER + DSTATE + n];
            #pragma unroll
            for (int v = 0; v < 4; ++v) acc[u][v] += cv * pv[v];
        }
    }
    float Dh = Dp[h];
    for (int u = 0; u < 8; ++u) {
        int l = tl * 8 + u;
        size_t r = row0 + l;
        float e = expf(acs_s[l]);
        for (int v = 0; v < 4; ++v) {
            int p = tp * 4 + v;
            size_t yi = r * DINNER + h * HD + p;
            y[yi] += e * acc[u][v] + xbc[r * CONVCH + h * HD + p] * Dh;
        }
    }
}

// ---------------- gated rmsnorm -> bf16 ----------------
__global__ __launch_bounds__(256) void k_gate(
    const float* __restrict__ y, const u16* __restrict__ zx,
    const float* __restrict__ gw, u16* __restrict__ out)
{
    int r = blockIdx.x;
    __shared__ float tbuf[DINNER];
    float ss = 0.f;
    for (int i = threadIdx.x; i < DINNER; i += 256) {
        float z = b2f(zx[(size_t)r * DPROJ2 + i]);
        float t = y[(size_t)r * DINNER + i] * (z / (1.f + expf(-z)));
        tbuf[i] = t;
        ss += t * t;
    }
    float tot = blockReduceSum(ss);
    float sc = rsqrtf(tot / DINNER + EPS);
    for (int i = threadIdx.x; i < DINNER; i += 256)
        out[(size_t)r * DINNER + i] = f2b(tbuf[i] * sc * gw[i]);
}

// ---------------- launch ----------------
extern "C" void kernel_launch(void* const* d_in, const int* in_sizes, int n_in,
                              void* d_out, int out_size, void* d_ws, size_t ws_size,
                              hipStream_t stream)
{
    const float* x         = (const float*)d_in[0];
    const float* norm_w    = (const float*)d_in[1];
    const float* out_w_blk = (const float*)d_in[2];
    const float* out_b_blk = (const float*)d_in[3];
    float* out = (float*)d_out;

    char* ws = (char*)d_ws;
    float* xn   = (float*)ws; ws += (size_t)T * DMODEL * 4;
    u16*  xnb   = (u16*)ws;   ws += (size_t)T * DMODEL * 2;
    u16*  zxb   = (u16*)ws;   ws += (size_t)T * DPROJ2 * 2;
    float* xbc  = (float*)ws; ws += (size_t)T * CONVCH * 4;
    float* dtb  = (float*)ws; ws += (size_t)T * NH * 4;
    float* acs  = (float*)ws; ws += (size_t)BATCH * NH * NCH * CHUNK * 4;
    float* cd   = (float*)ws; ws += (size_t)BATCH * NH * NCH * 4;
    float* yb   = (float*)ws; ws += (size_t)T * DINNER * 4;
    u16*  ybb   = (u16*)ws;   ws += (size_t)T * DINNER * 2;
    float* st   = (float*)ws; ws += (size_t)BATCH * NCH * NH * HD * DSTATE * 4;
    u16*  catb  = (u16*)ws;   ws += (size_t)T * DINNER * 2;
    u16*  inwb  = (u16*)ws;   ws += (size_t)DPROJ2 * DMODEL * 2;
    u16*  outwb = (u16*)ws;   ws += (size_t)DMODEL * DINNER * 2;
    u16*  owbb  = (u16*)ws;   ws += (size_t)DMODEL * DINNER * 2;

    k_rmsnorm<<<T, 256, 0, stream>>>(x, norm_w, xn, xnb);
    {
        int n = DMODEL * DINNER;
        k_f2b<<<(n / 4 + 255) / 256, 256, 0, stream>>>(out_w_blk, owbb, n);
    }

    for (int dir = 0; dir < 2; ++dir) {
        const float* in_w   = (const float*)d_in[4 + dir * 8 + 0];
        const float* conv_w = (const float*)d_in[4 + dir * 8 + 1];
        const float* conv_b = (const float*)d_in[4 + dir * 8 + 2];
        const float* dtbias = (const float*)d_in[4 + dir * 8 + 3];
        const float* A_log  = (const float*)d_in[4 + dir * 8 + 4];
        const float* Dp     = (const float*)d_in[4 + dir * 8 + 5];
        const float* gnw    = (const float*)d_in[4 + dir * 8 + 6];
        const float* out_w  = (const float*)d_in[4 + dir * 8 + 7];

        {   // convert weights to bf16 (in_w: first 4352 rows only; dt rows stay fp32)
            int n1 = DPROJ2 * DMODEL;
            k_f2b<<<(n1 / 4 + 255) / 256, 256, 0, stream>>>(in_w, inwb, n1);
            int n2 = DMODEL * DINNER;
            k_f2b<<<(n2 / 4 + 255) / 256, 256, 0, stream>>>(out_w, outwb, n2);
        }

        // in-proj: zx[4096 x 4352] bf16 out
        dim3 g1(DPROJ2 / 128, T / 128);
        k_mm<<<g1, 256, 0, stream>>>(xnb, inwb, DMODEL, dir,
                                     zxb, nullptr, DPROJ2, 0, nullptr, nullptr, 0);
        // dt in fp32
        k_dt2<<<T, 256, 0, stream>>>(xn, in_w, dtbias, dtb, dir);

        k_conv<<<(T * CONVCH + 255) / 256, 256, 0, stream>>>(zxb, conv_w, conv_b, xbc);
        k_acs<<<BATCH * NH * NCH, 128, 0, stream>>>(dtb, A_log, acs, cd);
        k_chunk<<<BATCH * NCH * NH, 256, 0, stream>>>(xbc, dtb, acs, yb, st);
        k_scan<<<(BATCH * NH * HD * DSTATE + 255) / 256, 256, 0, stream>>>(st, cd);
        k_yoff<<<BATCH * NCH * NH, 256, 0, stream>>>(xbc, st, acs, Dp, yb);
        k_gate<<<T, 256, 0, stream>>>(yb, zxb, gnw, ybb);

        // out-proj -> cat (bf16), bwd rows un-flipped at A-read
        dim3 g2(DMODEL / 128, T / 128);
        k_mm<<<g2, 256, 0, stream>>>(ybb, outwb, DINNER, dir,
                                     catb, nullptr, 2 * DMODEL, dir * DMODEL,
                                     nullptr, nullptr, 0);
    }

    // final: out = cat @ out_w_blk^T + bias + x
    dim3 g3(DMODEL / 128, T / 128);
    k_mm<<<g3, 256, 0, stream>>>(catb, owbb, DINNER, 0,
                                 nullptr, out, DMODEL, 0, out_b_blk, x, DMODEL);
}

// Round 3
// 823.456 us; speedup vs baseline: 5.4844x; 1.9562x over previous
//
#include <hip/hip_runtime.h>
#include <hip/hip_bf16.h>
#include <math.h>

#define BATCH 2
#define SEQL 2048
#define T 4096            // BATCH*SEQL tokens
#define DMODEL 1024
#define DINNER 2048
#define DSTATE 128
#define NH 32
#define HD 64
#define DPROJ2 4352       // z (2048) + xBC (2304); dt handled separately in fp32
#define CONVCH 2304
#define NCH 16            // chunks per sequence
#define CHUNK 128
#define EPS 1e-5f

typedef unsigned short u16;
typedef __bf16 bf16x8 __attribute__((ext_vector_type(8)));
typedef float f32x4 __attribute__((ext_vector_type(4)));

__device__ __forceinline__ u16 f2b(float f) {
    union { float f; unsigned u; } v; v.f = f;
    unsigned r = v.u + 0x7fffu + ((v.u >> 16) & 1u);
    return (u16)(r >> 16);
}
__device__ __forceinline__ float b2f(u16 b) {
    union { unsigned u; float f; } v; v.u = ((unsigned)b) << 16;
    return v.f;
}
__device__ __forceinline__ int flipseq(int r) {
    return (r & ~(SEQL - 1)) | ((SEQL - 1) - (r & (SEQL - 1)));
}
__device__ __forceinline__ void gload16(const u16* g, u16* l) {
    __builtin_amdgcn_global_load_lds(
        (const __attribute__((address_space(1))) void*)g,
        (__attribute__((address_space(3))) void*)l, 16, 0, 0);
}

// ---------------- block reduce ----------------
__device__ __forceinline__ float blockReduceSum(float v) {
    __shared__ float red_[4];
    for (int off = 32; off > 0; off >>= 1) v += __shfl_down(v, off);
    int lane = threadIdx.x & 63, wid = threadIdx.x >> 6;
    if (lane == 0) red_[wid] = v;
    __syncthreads();
    if (threadIdx.x == 0) {
        float s = 0.f;
        int nw = blockDim.x >> 6;
        for (int i = 0; i < nw; ++i) s += red_[i];
        red_[0] = s;
    }
    __syncthreads();
    return red_[0];
}

// ---------------- input rmsnorm: writes fp32 and bf16 copies ----------------
__global__ __launch_bounds__(256) void k_rmsnorm(
    const float* __restrict__ x, const float* __restrict__ w,
    float* __restrict__ outf, u16* __restrict__ outb)
{
    int row = blockIdx.x;
    const float* xr = x + (size_t)row * DMODEL;
    float ss = 0.f;
    for (int i = threadIdx.x; i < DMODEL; i += 256) { float v = xr[i]; ss += v * v; }
    float tot = blockReduceSum(ss);
    float sc = rsqrtf(tot / DMODEL + EPS);
    for (int i = threadIdx.x; i < DMODEL; i += 256) {
        float v = xr[i] * sc * w[i];
        outf[(size_t)row * DMODEL + i] = v;
        outb[(size_t)row * DMODEL + i] = f2b(v);
    }
}

// ---------------- fp32 -> bf16 conversion ----------------
__global__ void k_f2b(const float* __restrict__ s, u16* __restrict__ d, int n)
{
    int i = (blockIdx.x * blockDim.x + threadIdx.x) * 4;
    if (i >= n) return;
    float4 v = *(const float4*)(s + i);
    ushort4 o;
    o.x = f2b(v.x); o.y = f2b(v.y); o.z = f2b(v.z); o.w = f2b(v.w);
    *(ushort4*)(d + i) = o;
}

// ---------------- bf16 MFMA GEMM: C[r,n] = sum_k A[src(r),k] * W[n,k] ----------------
__global__ __launch_bounds__(256) void k_mm(
    const u16* __restrict__ A, const u16* __restrict__ W, int K, int flip,
    u16* __restrict__ Cb, float* __restrict__ Cf, int ldc, int coff,
    const float* __restrict__ bias, const float* __restrict__ resid, int ldr)
{
    __shared__ u16 As[128 * 32];
    __shared__ u16 Bs[128 * 32];
    int tid = threadIdx.x;
    int lane = tid & 63;
    int m0 = blockIdx.y * 128, n0 = blockIdx.x * 128;
    int wrow = ((tid >> 6) & 1) * 64, wcol = (tid >> 7) * 64;

    int srow = tid >> 2, skof = (tid & 3) * 8;
    int ar1 = m0 + srow, ar2 = ar1 + 64;
    if (flip) { ar1 = flipseq(ar1); ar2 = flipseq(ar2); }
    const u16* ga1 = A + (size_t)ar1 * K + skof;
    const u16* ga2 = A + (size_t)ar2 * K + skof;
    const u16* gb1 = W + (size_t)(n0 + srow) * K + skof;
    const u16* gb2 = gb1 + (size_t)64 * K;
    u16* la1 = As + tid * 8;
    u16* la2 = As + 2048 + tid * 8;
    u16* lb1 = Bs + tid * 8;
    u16* lb2 = Bs + 2048 + tid * 8;

    int aoff[4], boff[4];
    #pragma unroll
    for (int i = 0; i < 4; ++i) {
        aoff[i] = (wrow + i * 16 + (lane & 15)) * 32 + ((lane >> 4) * 8);
        boff[i] = (wcol + i * 16 + (lane & 15)) * 32 + ((lane >> 4) * 8);
    }

    f32x4 acc[4][4] = {};
    for (int kt = 0; kt < K; kt += 32) {
        gload16(ga1, la1); gload16(ga2, la2);
        gload16(gb1, lb1); gload16(gb2, lb2);
        ga1 += 32; ga2 += 32; gb1 += 32; gb2 += 32;
        __syncthreads();
        bf16x8 af[4], bf[4];
        #pragma unroll
        for (int i = 0; i < 4; ++i) af[i] = *(const bf16x8*)(As + aoff[i]);
        #pragma unroll
        for (int j = 0; j < 4; ++j) bf[j] = *(const bf16x8*)(Bs + boff[j]);
        #pragma unroll
        for (int i = 0; i < 4; ++i)
            #pragma unroll
            for (int j = 0; j < 4; ++j)
                acc[i][j] = __builtin_amdgcn_mfma_f32_16x16x32_bf16(af[i], bf[j], acc[i][j], 0, 0, 0);
        __syncthreads();
    }

    int rbase = m0 + wrow + ((lane >> 4) << 2);
    int cbase = n0 + wcol + (lane & 15);
    if (Cb) {
        #pragma unroll
        for (int i = 0; i < 4; ++i)
            #pragma unroll
            for (int j = 0; j < 4; ++j)
                #pragma unroll
                for (int r = 0; r < 4; ++r)
                    Cb[(size_t)(rbase + i * 16 + r) * ldc + coff + cbase + j * 16] = f2b(acc[i][j][r]);
    } else {
        #pragma unroll
        for (int i = 0; i < 4; ++i)
            #pragma unroll
            for (int j = 0; j < 4; ++j)
                #pragma unroll
                for (int r = 0; r < 4; ++r) {
                    int row = rbase + i * 16 + r, col = cbase + j * 16;
                    float v = acc[i][j][r];
                    if (bias)  v += bias[col];
                    if (resid) v += resid[(size_t)row * ldr + col];
                    Cf[(size_t)row * ldc + coff + col] = v;
                }
    }
}

// ---------------- dt = softplus(xn . w_dt + bias), fp32 ----------------
__global__ __launch_bounds__(256) void k_dt2(
    const float* __restrict__ xn, const float* __restrict__ in_w,
    const float* __restrict__ dtb, float* __restrict__ dt, int flip)
{
    int row = blockIdx.x;
    int src = flip ? flipseq(row) : row;
    __shared__ float xs[1024];
    ((float4*)xs)[threadIdx.x] = ((const float4*)(xn + (size_t)src * DMODEL))[threadIdx.x];
    __syncthreads();
    int h = threadIdx.x >> 3, part = threadIdx.x & 7;
    const float* w = in_w + (size_t)(DPROJ2 + h) * DMODEL;
    float s = 0.f;
    for (int kk = 0; kk < 128; ++kk) {
        int k = part + (kk << 3);
        s += xs[k] * w[k];
    }
    s += __shfl_down(s, 4, 8);
    s += __shfl_down(s, 2, 8);
    s += __shfl_down(s, 1, 8);
    if (part == 0) {
        float v = s + dtb[h];
        dt[(size_t)row * NH + h] = (v > 20.f) ? v : log1pf(expf(v));
    }
}

// ---------------- conv4 + silu -> bf16 xbcb; x-part also * dt -> xdtb ----------------
__global__ void k_conv(const u16* __restrict__ zx, const float* __restrict__ cw,
                       const float* __restrict__ cb, const float* __restrict__ dt,
                       u16* __restrict__ xbcb, u16* __restrict__ xdtb)
{
    int i = blockIdx.x * blockDim.x + threadIdx.x;
    if (i >= T * CONVCH) return;
    int r = i / CONVCH, ch = i - r * CONVCH;
    int t = r & (SEQL - 1);
    int b0 = r - t;
    float acc = cb[ch];
    #pragma unroll
    for (int k = 0; k < 4; ++k) {
        int tt = t + k - 3;
        if (tt >= 0) acc += b2f(zx[(size_t)(b0 + tt) * DPROJ2 + DINNER + ch]) * cw[ch * 4 + k];
    }
    float v = acc / (1.f + __expf(-acc));
    xbcb[i] = f2b(v);
    if (ch < DINNER)
        xdtb[(size_t)r * DINNER + ch] = f2b(v * dt[(size_t)r * NH + (ch >> 6)]);
}

// ---------------- per-chunk cumsum of A*dt ----------------
__global__ void k_acs(const float* __restrict__ dt, const float* __restrict__ A_log,
                      float* __restrict__ acs, float* __restrict__ cd)
{
    int bid = blockIdx.x;            // (b*NH + h)*NCH + c
    int c = bid & 15;
    int bh = bid >> 4;
    int h = bh & 31;
    int b = bh >> 5;
    int l = threadIdx.x;
    __shared__ float s[128];
    float Ah = -expf(A_log[h]);
    int r = b * SEQL + c * CHUNK + l;
    s[l] = Ah * dt[(size_t)r * NH + h];
    __syncthreads();
    for (int off = 1; off < 128; off <<= 1) {
        float t = (l >= off) ? s[l - off] : 0.f;
        __syncthreads();
        s[l] += t;
        __syncthreads();
    }
    acs[(size_t)bid * 128 + l] = s[l];
    if (l == 127) cd[bid] = expf(s[127]);
}

// ---------------- per-(b,c,h): MFMA Y_diag + chunk states ----------------
// S = C@B^T (masked, *L) -> P (LDS roundtrip) ; Y = P@X ; st = (X*dt)^T@(B*dec)
#define LDW 136
__global__ __launch_bounds__(256) void k_chunk(
    const u16* __restrict__ xbcb, const u16* __restrict__ xdtb,
    const float* __restrict__ acs, float* __restrict__ y, float* __restrict__ st)
{
    __shared__ u16 S0[128 * LDW];   // Bs -> Ps -> Bt(dec-folded)
    __shared__ u16 Xt[64 * LDW];    // Xt[p][l] = X[l][p]*dt[l]
    __shared__ float acs_s[128];
    __shared__ float dec_s[128];
    int tid = threadIdx.x;
    int lane = tid & 63;
    int w = tid >> 6;
    int h = blockIdx.x & 31;
    int bc = blockIdx.x >> 5;
    int c = bc & 15, b = bc >> 4;
    int row0 = b * SEQL + c * CHUNK;

    if (tid < 128) {
        float a = acs[(((size_t)(b * NH + h) * NCH + c) << 7) + tid];
        acs_s[tid] = a;
    }
    // stage Bs: S0[s][n] = B[s][n] (bf16 copy)
    for (int i = tid; i < 128 * 16; i += 256) {
        int s = i >> 4, m8 = (i & 15) * 8;
        *(uint4*)(S0 + s * LDW + m8) =
            *(const uint4*)(xbcb + (size_t)(row0 + s) * CONVCH + DINNER + m8);
    }
    // stage Xt (transpose of xdtb slice)
    for (int i = tid; i < 128 * 16; i += 256) {
        int l = i >> 4, pg = (i & 15) * 4;
        ushort4 v = *(const ushort4*)(xdtb + (size_t)(row0 + l) * DINNER + h * HD + pg);
        Xt[(pg + 0) * LDW + l] = v.x; Xt[(pg + 1) * LDW + l] = v.y;
        Xt[(pg + 2) * LDW + l] = v.z; Xt[(pg + 3) * LDW + l] = v.w;
    }
    __syncthreads();
    float a_last = acs_s[127];
    if (tid < 128) dec_s[tid] = __expf(a_last - acs_s[tid]);

    // ---- S phase: S[l][s] = sum_n C[l][n]*B[s][n] ----
    int wrow = (w & 1) * 64, wcol = (w >> 1) * 64;
    const u16* cbase = xbcb + (size_t)row0 * CONVCH + DINNER + DSTATE;
    f32x4 sacc[4][4] = {};
    for (int kk = 0; kk < 4; ++kk) {
        bf16x8 af[4], bfr[4];
        #pragma unroll
        for (int i = 0; i < 4; ++i)
            af[i] = *(const bf16x8*)(cbase + (size_t)(wrow + i * 16 + (lane & 15)) * CONVCH
                                     + kk * 32 + (lane >> 4) * 8);
        #pragma unroll
        for (int j = 0; j < 4; ++j)
            bfr[j] = *(const bf16x8*)(S0 + (wcol + j * 16 + (lane & 15)) * LDW
                                      + kk * 32 + (lane >> 4) * 8);
        #pragma unroll
        for (int i = 0; i < 4; ++i)
            #pragma unroll
            for (int j = 0; j < 4; ++j)
                if (wcol + j * 16 <= wrow + i * 16 + 15)
                    sacc[i][j] = __builtin_amdgcn_mfma_f32_16x16x32_bf16(af[i], bfr[j], sacc[i][j], 0, 0, 0);
    }
    __syncthreads();   // all Bs reads done
    // ---- mask * L, write P (bf16) into S0 ----
    #pragma unroll
    for (int i = 0; i < 4; ++i)
        #pragma unroll
        for (int j = 0; j < 4; ++j) {
            int s = wcol + j * 16 + (lane & 15);
            #pragma unroll
            for (int r = 0; r < 4; ++r) {
                int l = wrow + i * 16 + (lane >> 4) * 4 + r;
                float v = (s <= l) ? sacc[i][j][r] * __expf(acs_s[l] - acs_s[s]) : 0.f;
                S0[l * LDW + s] = f2b(v);
            }
        }
    __syncthreads();
    // ---- Y phase: Y[l][p] = sum_s P[l][s]*X[s][p] ----
    f32x4 yacc[2][4] = {};
    for (int kk = 0; kk < 4; ++kk) {
        bf16x8 af[2], bfr[4];
        #pragma unroll
        for (int i = 0; i < 2; ++i)
            af[i] = *(const bf16x8*)(S0 + (w * 32 + i * 16 + (lane & 15)) * LDW
                                     + kk * 32 + (lane >> 4) * 8);
        #pragma unroll
        for (int j = 0; j < 4; ++j)
            bfr[j] = *(const bf16x8*)(Xt + (j * 16 + (lane & 15)) * LDW
                                      + kk * 32 + (lane >> 4) * 8);
        #pragma unroll
        for (int i = 0; i < 2; ++i)
            #pragma unroll
            for (int j = 0; j < 4; ++j)
                yacc[i][j] = __builtin_amdgcn_mfma_f32_16x16x32_bf16(af[i], bfr[j], yacc[i][j], 0, 0, 0);
    }
    #pragma unroll
    for (int i = 0; i < 2; ++i)
        #pragma unroll
        for (int j = 0; j < 4; ++j)
            #pragma unroll
            for (int r = 0; r < 4; ++r) {
                int l = w * 32 + i * 16 + (lane >> 4) * 4 + r;
                int p = j * 16 + (lane & 15);
                y[(size_t)(row0 + l) * DINNER + h * HD + p] = yacc[i][j][r];
            }
    __syncthreads();   // all P reads done
    // ---- stage Bt: S0[n][l] = B[l][n]*dec[l] ----
    for (int i = tid; i < 128 * 32; i += 256) {
        int l = i >> 5, ng = (i & 31) * 4;
        ushort4 v = *(const ushort4*)(xbcb + (size_t)(row0 + l) * CONVCH + DINNER + ng);
        float d = dec_s[l];
        S0[(ng + 0) * LDW + l] = f2b(b2f(v.x) * d);
        S0[(ng + 1) * LDW + l] = f2b(b2f(v.y) * d);
        S0[(ng + 2) * LDW + l] = f2b(b2f(v.z) * d);
        S0[(ng + 3) * LDW + l] = f2b(b2f(v.w) * d);
    }
    __syncthreads();
    // ---- states: st[p][n] = sum_l Xt[p][l]*Bt[n][l] ----
    f32x4 tacc[8] = {};
    for (int kk = 0; kk < 4; ++kk) {
        bf16x8 afs = *(const bf16x8*)(Xt + (w * 16 + (lane & 15)) * LDW
                                      + kk * 32 + (lane >> 4) * 8);
        #pragma unroll
        for (int j = 0; j < 8; ++j) {
            bf16x8 bfs = *(const bf16x8*)(S0 + (j * 16 + (lane & 15)) * LDW
                                          + kk * 32 + (lane >> 4) * 8);
            tacc[j] = __builtin_amdgcn_mfma_f32_16x16x32_bf16(afs, bfs, tacc[j], 0, 0, 0);
        }
    }
    size_t sb = (size_t)blockIdx.x * (HD * DSTATE);
    #pragma unroll
    for (int j = 0; j < 8; ++j)
        #pragma unroll
        for (int r = 0; r < 4; ++r) {
            int p = w * 16 + (lane >> 4) * 4 + r;
            int n = j * 16 + (lane & 15);
            st[sb + (size_t)p * DSTATE + n] = tacc[j][r];
        }
}

// ---------------- inter-chunk scan (in place: states -> prev) ----------------
__global__ void k_scan(float* __restrict__ st, const float* __restrict__ cd)
{
    int i = blockIdx.x * blockDim.x + threadIdx.x;
    if (i >= BATCH * NH * HD * DSTATE) return;
    int n = i & 127;
    int rest = i >> 7;
    int p = rest & 63; rest >>= 6;
    int h = rest & 31;
    int b = rest >> 5;
    float s = 0.f;
    for (int c = 0; c < NCH; ++c) {
        size_t idx = ((size_t)((b * NCH + c) * NH + h) * HD + p) * DSTATE + n;
        float v = st[idx];
        st[idx] = s;                                   // prev_c
        s = s * cd[(b * NH + h) * NCH + c] + v;        // carry
    }
}

// ---------------- Y_off: y += exp(acs[l]) * C@prev^T + xh*D  (MFMA) ----------------
__global__ __launch_bounds__(256) void k_yoff(
    const u16* __restrict__ xbcb, const float* __restrict__ prev,
    const float* __restrict__ acs, const float* __restrict__ Dp,
    float* __restrict__ y)
{
    __shared__ u16 Pv[64 * LDW];
    __shared__ float acs_s[128];
    int tid = threadIdx.x, lane = tid & 63, w = tid >> 6;
    int h = blockIdx.x & 31;
    int bc = blockIdx.x >> 5;
    int c = bc & 15, b = bc >> 4;
    int row0 = b * SEQL + c * CHUNK;
    size_t sb = (size_t)blockIdx.x * (HD * DSTATE);
    for (int i = tid; i < 64 * 32; i += 256) {
        int p = i >> 5, ng = (i & 31) * 4;
        float4 v = *(const float4*)(prev + sb + (size_t)p * DSTATE + ng);
        ushort4 o; o.x = f2b(v.x); o.y = f2b(v.y); o.z = f2b(v.z); o.w = f2b(v.w);
        *(ushort4*)(Pv + p * LDW + ng) = o;
    }
    if (tid < 128) acs_s[tid] = acs[(((size_t)(b * NH + h) * NCH + c) << 7) + tid];
    __syncthreads();
    const u16* cbase = xbcb + (size_t)row0 * CONVCH + DINNER + DSTATE;
    f32x4 acc[2][4] = {};
    for (int kk = 0; kk < 4; ++kk) {
        bf16x8 af[2], bfr[4];
        #pragma unroll
        for (int i = 0; i < 2; ++i)
            af[i] = *(const bf16x8*)(cbase + (size_t)(w * 32 + i * 16 + (lane & 15)) * CONVCH
                                     + kk * 32 + (lane >> 4) * 8);
        #pragma unroll
        for (int j = 0; j < 4; ++j)
            bfr[j] = *(const bf16x8*)(Pv + (j * 16 + (lane & 15)) * LDW
                                      + kk * 32 + (lane >> 4) * 8);
        #pragma unroll
        for (int i = 0; i < 2; ++i)
            #pragma unroll
            for (int j = 0; j < 4; ++j)
                acc[i][j] = __builtin_amdgcn_mfma_f32_16x16x32_bf16(af[i], bfr[j], acc[i][j], 0, 0, 0);
    }
    float Dh = Dp[h];
    #pragma unroll
    for (int i = 0; i < 2; ++i)
        #pragma unroll
        for (int j = 0; j < 4; ++j)
            #pragma unroll
            for (int r = 0; r < 4; ++r) {
                int l = w * 32 + i * 16 + (lane >> 4) * 4 + r;
                int p = j * 16 + (lane & 15);
                size_t yi = (size_t)(row0 + l) * DINNER + h * HD + p;
                y[yi] += __expf(acs_s[l]) * acc[i][j][r]
                       + b2f(xbcb[(size_t)(row0 + l) * CONVCH + h * HD + p]) * Dh;
            }
}

// ---------------- gated rmsnorm -> bf16 ----------------
__global__ __launch_bounds__(256) void k_gate(
    const float* __restrict__ y, const u16* __restrict__ zx,
    const float* __restrict__ gw, u16* __restrict__ out)
{
    int r = blockIdx.x;
    __shared__ float tbuf[DINNER];
    float ss = 0.f;
    for (int i = threadIdx.x; i < DINNER; i += 256) {
        float z = b2f(zx[(size_t)r * DPROJ2 + i]);
        float t = y[(size_t)r * DINNER + i] * (z / (1.f + expf(-z)));
        tbuf[i] = t;
        ss += t * t;
    }
    float tot = blockReduceSum(ss);
    float sc = rsqrtf(tot / DINNER + EPS);
    for (int i = threadIdx.x; i < DINNER; i += 256)
        out[(size_t)r * DINNER + i] = f2b(tbuf[i] * sc * gw[i]);
}

// ---------------- launch ----------------
extern "C" void kernel_launch(void* const* d_in, const int* in_sizes, int n_in,
                              void* d_out, int out_size, void* d_ws, size_t ws_size,
                              hipStream_t stream)
{
    const float* x         = (const float*)d_in[0];
    const float* norm_w    = (const float*)d_in[1];
    const float* out_w_blk = (const float*)d_in[2];
    const float* out_b_blk = (const float*)d_in[3];
    float* out = (float*)d_out;

    char* ws = (char*)d_ws;
    float* xn   = (float*)ws; ws += (size_t)T * DMODEL * 4;
    u16*  xnb   = (u16*)ws;   ws += (size_t)T * DMODEL * 2;
    u16*  zxb   = (u16*)ws;   ws += (size_t)T * DPROJ2 * 2;
    u16*  xbcb  = (u16*)ws;   ws += (size_t)T * CONVCH * 2;
    u16*  xdtb  = (u16*)ws;   ws += (size_t)T * DINNER * 2;
    float* dtb  = (float*)ws; ws += (size_t)T * NH * 4;
    float* acs  = (float*)ws; ws += (size_t)BATCH * NH * NCH * CHUNK * 4;
    float* cd   = (float*)ws; ws += (size_t)BATCH * NH * NCH * 4;
    float* yb   = (float*)ws; ws += (size_t)T * DINNER * 4;
    u16*  ybb   = (u16*)ws;   ws += (size_t)T * DINNER * 2;
    float* st   = (float*)ws; ws += (size_t)BATCH * NCH * NH * HD * DSTATE * 4;
    u16*  catb  = (u16*)ws;   ws += (size_t)T * DINNER * 2;
    u16*  inwb  = (u16*)ws;   ws += (size_t)DPROJ2 * DMODEL * 2;
    u16*  outwb = (u16*)ws;   ws += (size_t)DMODEL * DINNER * 2;
    u16*  owbb  = (u16*)ws;   ws += (size_t)DMODEL * DINNER * 2;

    k_rmsnorm<<<T, 256, 0, stream>>>(x, norm_w, xn, xnb);
    {
        int n = DMODEL * DINNER;
        k_f2b<<<(n / 4 + 255) / 256, 256, 0, stream>>>(out_w_blk, owbb, n);
    }

    for (int dir = 0; dir < 2; ++dir) {
        const float* in_w   = (const float*)d_in[4 + dir * 8 + 0];
        const float* conv_w = (const float*)d_in[4 + dir * 8 + 1];
        const float* conv_b = (const float*)d_in[4 + dir * 8 + 2];
        const float* dtbias = (const float*)d_in[4 + dir * 8 + 3];
        const float* A_log  = (const float*)d_in[4 + dir * 8 + 4];
        const float* Dp     = (const float*)d_in[4 + dir * 8 + 5];
        const float* gnw    = (const float*)d_in[4 + dir * 8 + 6];
        const float* out_w  = (const float*)d_in[4 + dir * 8 + 7];

        {
            int n1 = DPROJ2 * DMODEL;
            k_f2b<<<(n1 / 4 + 255) / 256, 256, 0, stream>>>(in_w, inwb, n1);
            int n2 = DMODEL * DINNER;
            k_f2b<<<(n2 / 4 + 255) / 256, 256, 0, stream>>>(out_w, outwb, n2);
        }

        dim3 g1(DPROJ2 / 128, T / 128);
        k_mm<<<g1, 256, 0, stream>>>(xnb, inwb, DMODEL, dir,
                                     zxb, nullptr, DPROJ2, 0, nullptr, nullptr, 0);
        k_dt2<<<T, 256, 0, stream>>>(xn, in_w, dtbias, dtb, dir);

        k_conv<<<(T * CONVCH + 255) / 256, 256, 0, stream>>>(zxb, conv_w, conv_b, dtb, xbcb, xdtb);
        k_acs<<<BATCH * NH * NCH, 128, 0, stream>>>(dtb, A_log, acs, cd);
        k_chunk<<<BATCH * NCH * NH, 256, 0, stream>>>(xbcb, xdtb, acs, yb, st);
        k_scan<<<(BATCH * NH * HD * DSTATE + 255) / 256, 256, 0, stream>>>(st, cd);
        k_yoff<<<BATCH * NCH * NH, 256, 0, stream>>>(xbcb, st, acs, Dp, yb);
        k_gate<<<T, 256, 0, stream>>>(yb, zxb, gnw, ybb);

        dim3 g2(DMODEL / 128, T / 128);
        k_mm<<<g2, 256, 0, stream>>>(ybb, outwb, DINNER, dir,
                                     catb, nullptr, 2 * DMODEL, dir * DMODEL,
                                     nullptr, nullptr, 0);
    }

    dim3 g3(DMODEL / 128, T / 128);
    k_mm<<<g3, 256, 0, stream>>>(catb, owbb, DINNER, 0,
                                 nullptr, out, DMODEL, 0, out_b_blk, x, DMODEL);
}

// Round 4
// 740.196 us; speedup vs baseline: 6.1013x; 1.1125x over previous
//
#include <hip/hip_runtime.h>
#include <hip/hip_bf16.h>
#include <math.h>

#define BATCH 2
#define SEQL 2048
#define T 4096            // BATCH*SEQL tokens
#define DMODEL 1024
#define DINNER 2048
#define DSTATE 128
#define NH 32
#define HD 64
#define DPROJ2 4352       // z (2048) + xBC (2304); dt handled separately in fp32
#define CONVCH 2304
#define NCH 16            // chunks per sequence
#define CHUNK 128
#define EPS 1e-5f

typedef unsigned short u16;
typedef __bf16 bf16x8 __attribute__((ext_vector_type(8)));
typedef float f32x4 __attribute__((ext_vector_type(4)));

__device__ __forceinline__ u16 f2b(float f) {
    union { float f; unsigned u; } v; v.f = f;
    unsigned r = v.u + 0x7fffu + ((v.u >> 16) & 1u);
    return (u16)(r >> 16);
}
__device__ __forceinline__ float b2f(u16 b) {
    union { unsigned u; float f; } v; v.u = ((unsigned)b) << 16;
    return v.f;
}
__device__ __forceinline__ int flipseq(int r) {
    return (r & ~(SEQL - 1)) | ((SEQL - 1) - (r & (SEQL - 1)));
}
__device__ __forceinline__ void gload16(const u16* g, u16* l) {
    __builtin_amdgcn_global_load_lds(
        (const __attribute__((address_space(1))) void*)g,
        (__attribute__((address_space(3))) void*)l, 16, 0, 0);
}

// ---------------- block reduce ----------------
__device__ __forceinline__ float blockReduceSum(float v) {
    __shared__ float red_[4];
    for (int off = 32; off > 0; off >>= 1) v += __shfl_down(v, off);
    int lane = threadIdx.x & 63, wid = threadIdx.x >> 6;
    if (lane == 0) red_[wid] = v;
    __syncthreads();
    if (threadIdx.x == 0) {
        float s = 0.f;
        int nw = blockDim.x >> 6;
        for (int i = 0; i < nw; ++i) s += red_[i];
        red_[0] = s;
    }
    __syncthreads();
    return red_[0];
}

// ---------------- input rmsnorm: writes fp32 and bf16 copies ----------------
__global__ __launch_bounds__(256) void k_rmsnorm(
    const float* __restrict__ x, const float* __restrict__ w,
    float* __restrict__ outf, u16* __restrict__ outb)
{
    int row = blockIdx.x;
    const float* xr = x + (size_t)row * DMODEL;
    float ss = 0.f;
    for (int i = threadIdx.x; i < DMODEL; i += 256) { float v = xr[i]; ss += v * v; }
    float tot = blockReduceSum(ss);
    float sc = rsqrtf(tot / DMODEL + EPS);
    for (int i = threadIdx.x; i < DMODEL; i += 256) {
        float v = xr[i] * sc * w[i];
        outf[(size_t)row * DMODEL + i] = v;
        outb[(size_t)row * DMODEL + i] = f2b(v);
    }
}

// ---------------- fp32 -> bf16 conversion ----------------
__global__ void k_f2b(const float* __restrict__ s, u16* __restrict__ d, int n)
{
    int i = (blockIdx.x * blockDim.x + threadIdx.x) * 4;
    if (i >= n) return;
    float4 v = *(const float4*)(s + i);
    ushort4 o;
    o.x = f2b(v.x); o.y = f2b(v.y); o.z = f2b(v.z); o.w = f2b(v.w);
    *(ushort4*)(d + i) = o;
}

// ---------------- bf16 MFMA GEMM, 128x128 tile ----------------
__global__ __launch_bounds__(256) void k_mm(
    const u16* __restrict__ A, const u16* __restrict__ W, int K, int flip,
    u16* __restrict__ Cb, float* __restrict__ Cf, int ldc, int coff,
    const float* __restrict__ bias, const float* __restrict__ resid, int ldr)
{
    __shared__ u16 As[128 * 32];
    __shared__ u16 Bs[128 * 32];
    int tid = threadIdx.x;
    int lane = tid & 63;
    int m0 = blockIdx.y * 128, n0 = blockIdx.x * 128;
    int wrow = ((tid >> 6) & 1) * 64, wcol = (tid >> 7) * 64;

    int srow = tid >> 2, skof = (tid & 3) * 8;
    int ar1 = m0 + srow, ar2 = ar1 + 64;
    if (flip) { ar1 = flipseq(ar1); ar2 = flipseq(ar2); }
    const u16* ga1 = A + (size_t)ar1 * K + skof;
    const u16* ga2 = A + (size_t)ar2 * K + skof;
    const u16* gb1 = W + (size_t)(n0 + srow) * K + skof;
    const u16* gb2 = gb1 + (size_t)64 * K;
    u16* la1 = As + tid * 8;
    u16* la2 = As + 2048 + tid * 8;
    u16* lb1 = Bs + tid * 8;
    u16* lb2 = Bs + 2048 + tid * 8;

    int aoff[4], boff[4];
    #pragma unroll
    for (int i = 0; i < 4; ++i) {
        aoff[i] = (wrow + i * 16 + (lane & 15)) * 32 + ((lane >> 4) * 8);
        boff[i] = (wcol + i * 16 + (lane & 15)) * 32 + ((lane >> 4) * 8);
    }

    f32x4 acc[4][4] = {};
    for (int kt = 0; kt < K; kt += 32) {
        gload16(ga1, la1); gload16(ga2, la2);
        gload16(gb1, lb1); gload16(gb2, lb2);
        ga1 += 32; ga2 += 32; gb1 += 32; gb2 += 32;
        __syncthreads();
        bf16x8 af[4], bf[4];
        #pragma unroll
        for (int i = 0; i < 4; ++i) af[i] = *(const bf16x8*)(As + aoff[i]);
        #pragma unroll
        for (int j = 0; j < 4; ++j) bf[j] = *(const bf16x8*)(Bs + boff[j]);
        #pragma unroll
        for (int i = 0; i < 4; ++i)
            #pragma unroll
            for (int j = 0; j < 4; ++j)
                acc[i][j] = __builtin_amdgcn_mfma_f32_16x16x32_bf16(af[i], bf[j], acc[i][j], 0, 0, 0);
        __syncthreads();
    }

    int rbase = m0 + wrow + ((lane >> 4) << 2);
    int cbase = n0 + wcol + (lane & 15);
    if (Cb) {
        #pragma unroll
        for (int i = 0; i < 4; ++i)
            #pragma unroll
            for (int j = 0; j < 4; ++j)
                #pragma unroll
                for (int r = 0; r < 4; ++r)
                    Cb[(size_t)(rbase + i * 16 + r) * ldc + coff + cbase + j * 16] = f2b(acc[i][j][r]);
    } else {
        #pragma unroll
        for (int i = 0; i < 4; ++i)
            #pragma unroll
            for (int j = 0; j < 4; ++j)
                #pragma unroll
                for (int r = 0; r < 4; ++r) {
                    int row = rbase + i * 16 + r, col = cbase + j * 16;
                    float v = acc[i][j][r];
                    if (bias)  v += bias[col];
                    if (resid) v += resid[(size_t)row * ldr + col];
                    Cf[(size_t)row * ldc + coff + col] = v;
                }
    }
}

// ---------------- bf16 MFMA GEMM, 64x64 tile (for small-N latency-bound GEMMs) ----------------
// 256 thr = 4 waves, each wave 32x32 (2x2 MFMA 16x16x32). Grid 4x larger than 128-tile:
// 4 blocks/CU hide each other's global_load_lds barrier drains (1 block/CU was 9.6% occ, 98us).
__global__ __launch_bounds__(256) void k_mm64(
    const u16* __restrict__ A, const u16* __restrict__ W, int K, int flip,
    u16* __restrict__ Cb, float* __restrict__ Cf, int ldc, int coff,
    const float* __restrict__ bias, const float* __restrict__ resid, int ldr)
{
    __shared__ u16 As[64 * 32];
    __shared__ u16 Bs[64 * 32];
    int tid = threadIdx.x;
    int lane = tid & 63;
    int w = tid >> 6;
    int m0 = blockIdx.y * 64, n0 = blockIdx.x * 64;
    int wrow = (w & 1) * 32, wcol = (w >> 1) * 32;

    int srow = tid >> 2, skof = (tid & 3) * 8;
    int ar = m0 + srow;
    if (flip) ar = flipseq(ar);
    const u16* ga = A + (size_t)ar * K + skof;
    const u16* gb = W + (size_t)(n0 + srow) * K + skof;
    u16* la = As + tid * 8;
    u16* lb = Bs + tid * 8;

    int aoff[2], boff[2];
    #pragma unroll
    for (int i = 0; i < 2; ++i) {
        aoff[i] = (wrow + i * 16 + (lane & 15)) * 32 + ((lane >> 4) * 8);
        boff[i] = (wcol + i * 16 + (lane & 15)) * 32 + ((lane >> 4) * 8);
    }

    f32x4 acc[2][2] = {};
    for (int kt = 0; kt < K; kt += 32) {
        gload16(ga, la);
        gload16(gb, lb);
        ga += 32; gb += 32;
        __syncthreads();
        bf16x8 af[2], bf[2];
        #pragma unroll
        for (int i = 0; i < 2; ++i) af[i] = *(const bf16x8*)(As + aoff[i]);
        #pragma unroll
        for (int j = 0; j < 2; ++j) bf[j] = *(const bf16x8*)(Bs + boff[j]);
        #pragma unroll
        for (int i = 0; i < 2; ++i)
            #pragma unroll
            for (int j = 0; j < 2; ++j)
                acc[i][j] = __builtin_amdgcn_mfma_f32_16x16x32_bf16(af[i], bf[j], acc[i][j], 0, 0, 0);
        __syncthreads();
    }

    int rbase = m0 + wrow + ((lane >> 4) << 2);
    int cbase = n0 + wcol + (lane & 15);
    if (Cb) {
        #pragma unroll
        for (int i = 0; i < 2; ++i)
            #pragma unroll
            for (int j = 0; j < 2; ++j)
                #pragma unroll
                for (int r = 0; r < 4; ++r)
                    Cb[(size_t)(rbase + i * 16 + r) * ldc + coff + cbase + j * 16] = f2b(acc[i][j][r]);
    } else {
        #pragma unroll
        for (int i = 0; i < 2; ++i)
            #pragma unroll
            for (int j = 0; j < 2; ++j)
                #pragma unroll
                for (int r = 0; r < 4; ++r) {
                    int row = rbase + i * 16 + r, col = cbase + j * 16;
                    float v = acc[i][j][r];
                    if (bias)  v += bias[col];
                    if (resid) v += resid[(size_t)row * ldr + col];
                    Cf[(size_t)row * ldc + coff + col] = v;
                }
    }
}

// ---------------- dt = softplus(xn . w_dt + bias), fp32, 4 rows/block ----------------
__global__ __launch_bounds__(256) void k_dt2(
    const float* __restrict__ xn, const float* __restrict__ in_w,
    const float* __restrict__ dtb, float* __restrict__ dt, int flip)
{
    int r0 = blockIdx.x * 4;
    __shared__ float xs[4][1024];
    int tid = threadIdx.x;
    #pragma unroll
    for (int rr = 0; rr < 4; ++rr) {
        int src = flip ? flipseq(r0 + rr) : (r0 + rr);
        ((float4*)xs[rr])[tid] = ((const float4*)(xn + (size_t)src * DMODEL))[tid];
    }
    __syncthreads();
    int h = tid >> 3, part = tid & 7;
    const float* w = in_w + (size_t)(DPROJ2 + h) * DMODEL;
    float a0 = 0.f, a1 = 0.f, a2 = 0.f, a3 = 0.f;
    for (int kk = 0; kk < 128; ++kk) {
        int k = part + (kk << 3);
        float wv = w[k];
        a0 += xs[0][k] * wv; a1 += xs[1][k] * wv;
        a2 += xs[2][k] * wv; a3 += xs[3][k] * wv;
    }
    #pragma unroll
    for (int off = 4; off > 0; off >>= 1) {
        a0 += __shfl_down(a0, off, 8); a1 += __shfl_down(a1, off, 8);
        a2 += __shfl_down(a2, off, 8); a3 += __shfl_down(a3, off, 8);
    }
    if (part == 0) {
        float bsh = dtb[h];
        float vv[4] = {a0, a1, a2, a3};
        #pragma unroll
        for (int rr = 0; rr < 4; ++rr) {
            float v = vv[rr] + bsh;
            dt[(size_t)(r0 + rr) * NH + h] = (v > 20.f) ? v : log1pf(expf(v));
        }
    }
}

// ---------------- conv4 + silu -> bf16 xbcb; x-part also * dt -> xdtb (8 ch/thread) ----------------
__global__ void k_conv(const u16* __restrict__ zx, const float* __restrict__ cw,
                       const float* __restrict__ cb, const float* __restrict__ dt,
                       u16* __restrict__ xbcb, u16* __restrict__ xdtb)
{
    int idx = blockIdx.x * blockDim.x + threadIdx.x;
    if (idx >= T * (CONVCH / 8)) return;
    int r = idx / (CONVCH / 8);
    int c8 = (idx - r * (CONVCH / 8)) * 8;
    int t = r & (SEQL - 1);
    int b0 = r - t;
    float4 cwv[8];
    #pragma unroll
    for (int j = 0; j < 8; ++j) cwv[j] = *(const float4*)(cw + (size_t)(c8 + j) * 4);
    float acc[8];
    {
        float4 c0 = *(const float4*)(cb + c8);
        float4 c1 = *(const float4*)(cb + c8 + 4);
        acc[0] = c0.x; acc[1] = c0.y; acc[2] = c0.z; acc[3] = c0.w;
        acc[4] = c1.x; acc[5] = c1.y; acc[6] = c1.z; acc[7] = c1.w;
    }
    #pragma unroll
    for (int k = 0; k < 4; ++k) {
        int tt = t + k - 3;
        if (tt < 0) continue;
        const u16* src = zx + (size_t)(b0 + tt) * DPROJ2 + DINNER + c8;
        ushort4 v0 = *(const ushort4*)src;
        ushort4 v1 = *(const ushort4*)(src + 4);
        float xv[8] = {b2f(v0.x), b2f(v0.y), b2f(v0.z), b2f(v0.w),
                       b2f(v1.x), b2f(v1.y), b2f(v1.z), b2f(v1.w)};
        #pragma unroll
        for (int j = 0; j < 8; ++j) {
            float wv = (k == 0) ? cwv[j].x : (k == 1) ? cwv[j].y : (k == 2) ? cwv[j].z : cwv[j].w;
            acc[j] += xv[j] * wv;
        }
    }
    ushort4 o0, o1;
    float s[8];
    #pragma unroll
    for (int j = 0; j < 8; ++j) s[j] = acc[j] / (1.f + __expf(-acc[j]));
    o0.x = f2b(s[0]); o0.y = f2b(s[1]); o0.z = f2b(s[2]); o0.w = f2b(s[3]);
    o1.x = f2b(s[4]); o1.y = f2b(s[5]); o1.z = f2b(s[6]); o1.w = f2b(s[7]);
    *(ushort4*)(xbcb + (size_t)r * CONVCH + c8) = o0;
    *(ushort4*)(xbcb + (size_t)r * CONVCH + c8 + 4) = o1;
    if (c8 < DINNER) {
        float dv = dt[(size_t)r * NH + (c8 >> 6)];
        ushort4 d0, d1;
        d0.x = f2b(s[0] * dv); d0.y = f2b(s[1] * dv); d0.z = f2b(s[2] * dv); d0.w = f2b(s[3] * dv);
        d1.x = f2b(s[4] * dv); d1.y = f2b(s[5] * dv); d1.z = f2b(s[6] * dv); d1.w = f2b(s[7] * dv);
        *(ushort4*)(xdtb + (size_t)r * DINNER + c8) = d0;
        *(ushort4*)(xdtb + (size_t)r * DINNER + c8 + 4) = d1;
    }
}

// ---------------- per-chunk cumsum of A*dt ----------------
__global__ void k_acs(const float* __restrict__ dt, const float* __restrict__ A_log,
                      float* __restrict__ acs, float* __restrict__ cd)
{
    int bid = blockIdx.x;            // (b*NH + h)*NCH + c
    int c = bid & 15;
    int bh = bid >> 4;
    int h = bh & 31;
    int b = bh >> 5;
    int l = threadIdx.x;
    __shared__ float s[128];
    float Ah = -expf(A_log[h]);
    int r = b * SEQL + c * CHUNK + l;
    s[l] = Ah * dt[(size_t)r * NH + h];
    __syncthreads();
    for (int off = 1; off < 128; off <<= 1) {
        float t = (l >= off) ? s[l - off] : 0.f;
        __syncthreads();
        s[l] += t;
        __syncthreads();
    }
    acs[(size_t)bid * 128 + l] = s[l];
    if (l == 127) cd[bid] = expf(s[127]);
}

// ---------------- per-(b,c,h): MFMA Y_diag + chunk states ----------------
#define LDW 136
__global__ __launch_bounds__(256) void k_chunk(
    const u16* __restrict__ xbcb, const u16* __restrict__ xdtb,
    const float* __restrict__ acs, float* __restrict__ y, float* __restrict__ st)
{
    __shared__ u16 S0[128 * LDW];   // Bs -> Ps -> Bt(dec-folded)
    __shared__ u16 Xt[64 * LDW];    // Xt[p][l] = X[l][p]*dt[l]
    __shared__ float acs_s[128];
    __shared__ float dec_s[128];
    int tid = threadIdx.x;
    int lane = tid & 63;
    int w = tid >> 6;
    int h = blockIdx.x & 31;
    int bc = blockIdx.x >> 5;
    int c = bc & 15, b = bc >> 4;
    int row0 = b * SEQL + c * CHUNK;

    if (tid < 128) {
        float a = acs[(((size_t)(b * NH + h) * NCH + c) << 7) + tid];
        acs_s[tid] = a;
    }
    for (int i = tid; i < 128 * 16; i += 256) {
        int s = i >> 4, m8 = (i & 15) * 8;
        *(uint4*)(S0 + s * LDW + m8) =
            *(const uint4*)(xbcb + (size_t)(row0 + s) * CONVCH + DINNER + m8);
    }
    for (int i = tid; i < 128 * 16; i += 256) {
        int l = i >> 4, pg = (i & 15) * 4;
        ushort4 v = *(const ushort4*)(xdtb + (size_t)(row0 + l) * DINNER + h * HD + pg);
        Xt[(pg + 0) * LDW + l] = v.x; Xt[(pg + 1) * LDW + l] = v.y;
        Xt[(pg + 2) * LDW + l] = v.z; Xt[(pg + 3) * LDW + l] = v.w;
    }
    __syncthreads();
    float a_last = acs_s[127];
    if (tid < 128) dec_s[tid] = __expf(a_last - acs_s[tid]);

    int wrow = (w & 1) * 64, wcol = (w >> 1) * 64;
    const u16* cbase = xbcb + (size_t)row0 * CONVCH + DINNER + DSTATE;
    f32x4 sacc[4][4] = {};
    for (int kk = 0; kk < 4; ++kk) {
        bf16x8 af[4], bfr[4];
        #pragma unroll
        for (int i = 0; i < 4; ++i)
            af[i] = *(const bf16x8*)(cbase + (size_t)(wrow + i * 16 + (lane & 15)) * CONVCH
                                     + kk * 32 + (lane >> 4) * 8);
        #pragma unroll
        for (int j = 0; j < 4; ++j)
            bfr[j] = *(const bf16x8*)(S0 + (wcol + j * 16 + (lane & 15)) * LDW
                                      + kk * 32 + (lane >> 4) * 8);
        #pragma unroll
        for (int i = 0; i < 4; ++i)
            #pragma unroll
            for (int j = 0; j < 4; ++j)
                if (wcol + j * 16 <= wrow + i * 16 + 15)
                    sacc[i][j] = __builtin_amdgcn_mfma_f32_16x16x32_bf16(af[i], bfr[j], sacc[i][j], 0, 0, 0);
    }
    __syncthreads();
    #pragma unroll
    for (int i = 0; i < 4; ++i)
        #pragma unroll
        for (int j = 0; j < 4; ++j) {
            int s = wcol + j * 16 + (lane & 15);
            #pragma unroll
            for (int r = 0; r < 4; ++r) {
                int l = wrow + i * 16 + (lane >> 4) * 4 + r;
                float v = (s <= l) ? sacc[i][j][r] * __expf(acs_s[l] - acs_s[s]) : 0.f;
                S0[l * LDW + s] = f2b(v);
            }
        }
    __syncthreads();
    f32x4 yacc[2][4] = {};
    for (int kk = 0; kk < 4; ++kk) {
        bf16x8 af[2], bfr[4];
        #pragma unroll
        for (int i = 0; i < 2; ++i)
            af[i] = *(const bf16x8*)(S0 + (w * 32 + i * 16 + (lane & 15)) * LDW
                                     + kk * 32 + (lane >> 4) * 8);
        #pragma unroll
        for (int j = 0; j < 4; ++j)
            bfr[j] = *(const bf16x8*)(Xt + (j * 16 + (lane & 15)) * LDW
                                      + kk * 32 + (lane >> 4) * 8);
        #pragma unroll
        for (int i = 0; i < 2; ++i)
            #pragma unroll
            for (int j = 0; j < 4; ++j)
                yacc[i][j] = __builtin_amdgcn_mfma_f32_16x16x32_bf16(af[i], bfr[j], yacc[i][j], 0, 0, 0);
    }
    #pragma unroll
    for (int i = 0; i < 2; ++i)
        #pragma unroll
        for (int j = 0; j < 4; ++j)
            #pragma unroll
            for (int r = 0; r < 4; ++r) {
                int l = w * 32 + i * 16 + (lane >> 4) * 4 + r;
                int p = j * 16 + (lane & 15);
                y[(size_t)(row0 + l) * DINNER + h * HD + p] = yacc[i][j][r];
            }
    __syncthreads();
    for (int i = tid; i < 128 * 32; i += 256) {
        int l = i >> 5, ng = (i & 31) * 4;
        ushort4 v = *(const ushort4*)(xbcb + (size_t)(row0 + l) * CONVCH + DINNER + ng);
        float d = dec_s[l];
        S0[(ng + 0) * LDW + l] = f2b(b2f(v.x) * d);
        S0[(ng + 1) * LDW + l] = f2b(b2f(v.y) * d);
        S0[(ng + 2) * LDW + l] = f2b(b2f(v.z) * d);
        S0[(ng + 3) * LDW + l] = f2b(b2f(v.w) * d);
    }
    __syncthreads();
    f32x4 tacc[8] = {};
    for (int kk = 0; kk < 4; ++kk) {
        bf16x8 afs = *(const bf16x8*)(Xt + (w * 16 + (lane & 15)) * LDW
                                      + kk * 32 + (lane >> 4) * 8);
        #pragma unroll
        for (int j = 0; j < 8; ++j) {
            bf16x8 bfs = *(const bf16x8*)(S0 + (j * 16 + (lane & 15)) * LDW
                                          + kk * 32 + (lane >> 4) * 8);
            tacc[j] = __builtin_amdgcn_mfma_f32_16x16x32_bf16(afs, bfs, tacc[j], 0, 0, 0);
        }
    }
    size_t sb = (size_t)blockIdx.x * (HD * DSTATE);
    #pragma unroll
    for (int j = 0; j < 8; ++j)
        #pragma unroll
        for (int r = 0; r < 4; ++r) {
            int p = w * 16 + (lane >> 4) * 4 + r;
            int n = j * 16 + (lane & 15);
            st[sb + (size_t)p * DSTATE + n] = tacc[j][r];
        }
}

// ---------------- inter-chunk scan (in place: states -> prev) ----------------
__global__ void k_scan(float* __restrict__ st, const float* __restrict__ cd)
{
    int i = blockIdx.x * blockDim.x + threadIdx.x;
    if (i >= BATCH * NH * HD * DSTATE) return;
    int n = i & 127;
    int rest = i >> 7;
    int p = rest & 63; rest >>= 6;
    int h = rest & 31;
    int b = rest >> 5;
    float s = 0.f;
    for (int c = 0; c < NCH; ++c) {
        size_t idx = ((size_t)((b * NCH + c) * NH + h) * HD + p) * DSTATE + n;
        float v = st[idx];
        st[idx] = s;                                   // prev_c
        s = s * cd[(b * NH + h) * NCH + c] + v;        // carry
    }
}

// ---------------- Y_off: y += exp(acs[l]) * C@prev^T + xh*D  (MFMA) ----------------
__global__ __launch_bounds__(256) void k_yoff(
    const u16* __restrict__ xbcb, const float* __restrict__ prev,
    const float* __restrict__ acs, const float* __restrict__ Dp,
    float* __restrict__ y)
{
    __shared__ u16 Pv[64 * LDW];
    __shared__ float acs_s[128];
    int tid = threadIdx.x, lane = tid & 63, w = tid >> 6;
    int h = blockIdx.x & 31;
    int bc = blockIdx.x >> 5;
    int c = bc & 15, b = bc >> 4;
    int row0 = b * SEQL + c * CHUNK;
    size_t sb = (size_t)blockIdx.x * (HD * DSTATE);
    for (int i = tid; i < 64 * 32; i += 256) {
        int p = i >> 5, ng = (i & 31) * 4;
        float4 v = *(const float4*)(prev + sb + (size_t)p * DSTATE + ng);
        ushort4 o; o.x = f2b(v.x); o.y = f2b(v.y); o.z = f2b(v.z); o.w = f2b(v.w);
        *(ushort4*)(Pv + p * LDW + ng) = o;
    }
    if (tid < 128) acs_s[tid] = acs[(((size_t)(b * NH + h) * NCH + c) << 7) + tid];
    __syncthreads();
    const u16* cbase = xbcb + (size_t)row0 * CONVCH + DINNER + DSTATE;
    f32x4 acc[2][4] = {};
    for (int kk = 0; kk < 4; ++kk) {
        bf16x8 af[2], bfr[4];
        #pragma unroll
        for (int i = 0; i < 2; ++i)
            af[i] = *(const bf16x8*)(cbase + (size_t)(w * 32 + i * 16 + (lane & 15)) * CONVCH
                                     + kk * 32 + (lane >> 4) * 8);
        #pragma unroll
        for (int j = 0; j < 4; ++j)
            bfr[j] = *(const bf16x8*)(Pv + (j * 16 + (lane & 15)) * LDW
                                      + kk * 32 + (lane >> 4) * 8);
        #pragma unroll
        for (int i = 0; i < 2; ++i)
            #pragma unroll
            for (int j = 0; j < 4; ++j)
                acc[i][j] = __builtin_amdgcn_mfma_f32_16x16x32_bf16(af[i], bfr[j], acc[i][j], 0, 0, 0);
    }
    float Dh = Dp[h];
    #pragma unroll
    for (int i = 0; i < 2; ++i)
        #pragma unroll
        for (int j = 0; j < 4; ++j)
            #pragma unroll
            for (int r = 0; r < 4; ++r) {
                int l = w * 32 + i * 16 + (lane >> 4) * 4 + r;
                int p = j * 16 + (lane & 15);
                size_t yi = (size_t)(row0 + l) * DINNER + h * HD + p;
                y[yi] += __expf(acs_s[l]) * acc[i][j][r]
                       + b2f(xbcb[(size_t)(row0 + l) * CONVCH + h * HD + p]) * Dh;
            }
}

// ---------------- gated rmsnorm -> bf16 ----------------
__global__ __launch_bounds__(256) void k_gate(
    const float* __restrict__ y, const u16* __restrict__ zx,
    const float* __restrict__ gw, u16* __restrict__ out)
{
    int r = blockIdx.x;
    __shared__ float tbuf[DINNER];
    int tid = threadIdx.x;
    float ss = 0.f;
    #pragma unroll
    for (int it = 0; it < 2; ++it) {
        int i = (it * 256 + tid) * 4;
        float4 yv = *(const float4*)(y + (size_t)r * DINNER + i);
        ushort4 zv = *(const ushort4*)(zx + (size_t)r * DPROJ2 + i);
        float z0 = b2f(zv.x), z1 = b2f(zv.y), z2 = b2f(zv.z), z3 = b2f(zv.w);
        float t0 = yv.x * (z0 / (1.f + __expf(-z0)));
        float t1 = yv.y * (z1 / (1.f + __expf(-z1)));
        float t2 = yv.z * (z2 / (1.f + __expf(-z2)));
        float t3 = yv.w * (z3 / (1.f + __expf(-z3)));
        tbuf[i] = t0; tbuf[i + 1] = t1; tbuf[i + 2] = t2; tbuf[i + 3] = t3;
        ss += t0 * t0 + t1 * t1 + t2 * t2 + t3 * t3;
    }
    float tot = blockReduceSum(ss);
    float sc = rsqrtf(tot / DINNER + EPS);
    #pragma unroll
    for (int it = 0; it < 2; ++it) {
        int i = (it * 256 + tid) * 4;
        ushort4 o;
        o.x = f2b(tbuf[i] * sc * gw[i]);
        o.y = f2b(tbuf[i + 1] * sc * gw[i + 1]);
        o.z = f2b(tbuf[i + 2] * sc * gw[i + 2]);
        o.w = f2b(tbuf[i + 3] * sc * gw[i + 3]);
        *(ushort4*)(out + (size_t)r * DINNER + i) = o;
    }
}

// ---------------- launch ----------------
extern "C" void kernel_launch(void* const* d_in, const int* in_sizes, int n_in,
                              void* d_out, int out_size, void* d_ws, size_t ws_size,
                              hipStream_t stream)
{
    const float* x         = (const float*)d_in[0];
    const float* norm_w    = (const float*)d_in[1];
    const float* out_w_blk = (const float*)d_in[2];
    const float* out_b_blk = (const float*)d_in[3];
    float* out = (float*)d_out;

    char* ws = (char*)d_ws;
    float* xn   = (float*)ws; ws += (size_t)T * DMODEL * 4;
    u16*  xnb   = (u16*)ws;   ws += (size_t)T * DMODEL * 2;
    u16*  zxb   = (u16*)ws;   ws += (size_t)T * DPROJ2 * 2;
    u16*  xbcb  = (u16*)ws;   ws += (size_t)T * CONVCH * 2;
    u16*  xdtb  = (u16*)ws;   ws += (size_t)T * DINNER * 2;
    float* dtb  = (float*)ws; ws += (size_t)T * NH * 4;
    float* acs  = (float*)ws; ws += (size_t)BATCH * NH * NCH * CHUNK * 4;
    float* cd   = (float*)ws; ws += (size_t)BATCH * NH * NCH * 4;
    float* yb   = (float*)ws; ws += (size_t)T * DINNER * 4;
    u16*  ybb   = (u16*)ws;   ws += (size_t)T * DINNER * 2;
    float* st   = (float*)ws; ws += (size_t)BATCH * NCH * NH * HD * DSTATE * 4;
    u16*  catb  = (u16*)ws;   ws += (size_t)T * DINNER * 2;
    u16*  inwb  = (u16*)ws;   ws += (size_t)DPROJ2 * DMODEL * 2;
    u16*  outwb = (u16*)ws;   ws += (size_t)DMODEL * DINNER * 2;
    u16*  owbb  = (u16*)ws;   ws += (size_t)DMODEL * DINNER * 2;

    k_rmsnorm<<<T, 256, 0, stream>>>(x, norm_w, xn, xnb);
    {
        int n = DMODEL * DINNER;
        k_f2b<<<(n / 4 + 255) / 256, 256, 0, stream>>>(out_w_blk, owbb, n);
    }

    for (int dir = 0; dir < 2; ++dir) {
        const float* in_w   = (const float*)d_in[4 + dir * 8 + 0];
        const float* conv_w = (const float*)d_in[4 + dir * 8 + 1];
        const float* conv_b = (const float*)d_in[4 + dir * 8 + 2];
        const float* dtbias = (const float*)d_in[4 + dir * 8 + 3];
        const float* A_log  = (const float*)d_in[4 + dir * 8 + 4];
        const float* Dp     = (const float*)d_in[4 + dir * 8 + 5];
        const float* gnw    = (const float*)d_in[4 + dir * 8 + 6];
        const float* out_w  = (const float*)d_in[4 + dir * 8 + 7];

        {
            int n1 = DPROJ2 * DMODEL;
            k_f2b<<<(n1 / 4 + 255) / 256, 256, 0, stream>>>(in_w, inwb, n1);
            int n2 = DMODEL * DINNER;
            k_f2b<<<(n2 / 4 + 255) / 256, 256, 0, stream>>>(out_w, outwb, n2);
        }

        dim3 g1(DPROJ2 / 128, T / 128);
        k_mm<<<g1, 256, 0, stream>>>(xnb, inwb, DMODEL, dir,
                                     zxb, nullptr, DPROJ2, 0, nullptr, nullptr, 0);
        k_dt2<<<T / 4, 256, 0, stream>>>(xn, in_w, dtbias, dtb, dir);

        k_conv<<<(T * (CONVCH / 8) + 255) / 256, 256, 0, stream>>>(zxb, conv_w, conv_b, dtb, xbcb, xdtb);
        k_acs<<<BATCH * NH * NCH, 128, 0, stream>>>(dtb, A_log, acs, cd);
        k_chunk<<<BATCH * NCH * NH, 256, 0, stream>>>(xbcb, xdtb, acs, yb, st);
        k_scan<<<(BATCH * NH * HD * DSTATE + 255) / 256, 256, 0, stream>>>(st, cd);
        k_yoff<<<BATCH * NCH * NH, 256, 0, stream>>>(xbcb, st, acs, Dp, yb);
        k_gate<<<T, 256, 0, stream>>>(yb, zxb, gnw, ybb);

        dim3 g2(DMODEL / 64, T / 64);
        k_mm64<<<g2, 256, 0, stream>>>(ybb, outwb, DINNER, dir,
                                       catb, nullptr, 2 * DMODEL, dir * DMODEL,
                                       nullptr, nullptr, 0);
    }

    dim3 g3(DMODEL / 64, T / 64);
    k_mm64<<<g3, 256, 0, stream>>>(catb, owbb, DINNER, 0,
                                   nullptr, out, DMODEL, 0, out_b_blk, x, DMODEL);
}

// Round 6
// 727.574 us; speedup vs baseline: 6.2071x; 1.0173x over previous
//
#include <hip/hip_runtime.h>
#include <hip/hip_bf16.h>
#include <math.h>

#define BATCH 2
#define SEQL 2048
#define T 4096            // BATCH*SEQL tokens
#define DMODEL 1024
#define DINNER 2048
#define DSTATE 128
#define NH 32
#define HD 64
#define DPROJ2 4352       // z (2048) + xBC (2304); dt handled separately in fp32
#define CONVCH 2304
#define NCH 16            // chunks per sequence
#define CHUNK 128
#define EPS 1e-5f

#define N_INW ((size_t)DPROJ2 * DMODEL)   // 4,456,448
#define N_OUTW ((size_t)DMODEL * DINNER)  // 2,097,152
#define N_ST ((size_t)BATCH * NCH * NH * HD * DSTATE)  // 8,388,608 per dir

typedef unsigned short u16;
typedef __bf16 bf16x8 __attribute__((ext_vector_type(8)));
typedef float f32x4 __attribute__((ext_vector_type(4)));

__device__ __forceinline__ u16 f2b(float f) {
    union { float f; unsigned u; } v; v.f = f;
    unsigned r = v.u + 0x7fffu + ((v.u >> 16) & 1u);
    return (u16)(r >> 16);
}
__device__ __forceinline__ float b2f(u16 b) {
    union { unsigned u; float f; } v; v.u = ((unsigned)b) << 16;
    return v.f;
}
__device__ __forceinline__ int flipseq(int r) {
    return (r & ~(SEQL - 1)) | ((SEQL - 1) - (r & (SEQL - 1)));
}
__device__ __forceinline__ void gload16(const u16* g, u16* l) {
    __builtin_amdgcn_global_load_lds(
        (const __attribute__((address_space(1))) void*)g,
        (__attribute__((address_space(3))) void*)l, 16, 0, 0);
}

// ---------------- block reduce ----------------
__device__ __forceinline__ float blockReduceSum(float v) {
    __shared__ float red_[4];
    for (int off = 32; off > 0; off >>= 1) v += __shfl_down(v, off);
    int lane = threadIdx.x & 63, wid = threadIdx.x >> 6;
    if (lane == 0) red_[wid] = v;
    __syncthreads();
    if (threadIdx.x == 0) {
        float s = 0.f;
        int nw = blockDim.x >> 6;
        for (int i = 0; i < nw; ++i) s += red_[i];
        red_[0] = s;
    }
    __syncthreads();
    return red_[0];
}

// ---------------- input rmsnorm -> bf16 ----------------
__global__ __launch_bounds__(256) void k_rmsnorm(
    const float* __restrict__ x, const float* __restrict__ w,
    u16* __restrict__ outb)
{
    int row = blockIdx.x;
    const float* xr = x + (size_t)row * DMODEL;
    float ss = 0.f;
    for (int i = threadIdx.x; i < DMODEL; i += 256) { float v = xr[i]; ss += v * v; }
    float tot = blockReduceSum(ss);
    float sc = rsqrtf(tot / DMODEL + EPS);
    for (int i = threadIdx.x; i < DMODEL; i += 256)
        outb[(size_t)row * DMODEL + i] = f2b(xr[i] * sc * w[i]);
}

// ---------------- all weights fp32 -> bf16, one launch ----------------
__global__ void k_f2b_all(
    const float* __restrict__ s0, const float* __restrict__ s1,  // f_in_w, b_in_w
    const float* __restrict__ s2, const float* __restrict__ s3,  // f_out_w, b_out_w
    const float* __restrict__ s4,                                // out_w_blk
    u16* __restrict__ d_inwb, u16* __restrict__ d_outwb, u16* __restrict__ d_owbb)
{
    size_t i = ((size_t)blockIdx.x * 256 + threadIdx.x) * 4;
    const float* s; u16* d; size_t off;
    if (i < 2 * N_INW) {
        int dir = i >= N_INW;
        off = i - (size_t)dir * N_INW;
        s = dir ? s1 : s0; d = d_inwb + (size_t)dir * N_INW;
    } else {
        size_t j = i - 2 * N_INW;
        if (j < 2 * N_OUTW) {
            int dir = j >= N_OUTW;
            off = j - (size_t)dir * N_OUTW;
            s = dir ? s3 : s2; d = d_outwb + (size_t)dir * N_OUTW;
        } else {
            off = j - 2 * N_OUTW;
            if (off >= N_OUTW) return;
            s = s4; d = d_owbb;
        }
    }
    float4 v = *(const float4*)(s + off);
    ushort4 o;
    o.x = f2b(v.x); o.y = f2b(v.y); o.z = f2b(v.z); o.w = f2b(v.w);
    *(ushort4*)(d + off) = o;
}

// ---------------- in-proj: bf16 MFMA GEMM 128x128, z = dir, split z/xBC outputs ----------------
__global__ __launch_bounds__(256) void k_mm_in(
    const u16* __restrict__ A, const u16* __restrict__ W0,
    u16* __restrict__ zb0, u16* __restrict__ xbcraw0)
{
    const int K = DMODEL;
    int dir = blockIdx.z;
    const u16* W = W0 + (size_t)dir * N_INW;

    __shared__ u16 As[128 * 32];
    __shared__ u16 Bs[128 * 32];
    int tid = threadIdx.x;
    int lane = tid & 63;
    int m0 = blockIdx.y * 128, n0 = blockIdx.x * 128;
    int wrow = ((tid >> 6) & 1) * 64, wcol = (tid >> 7) * 64;

    int srow = tid >> 2, skof = (tid & 3) * 8;
    int ar1 = m0 + srow, ar2 = ar1 + 64;
    if (dir) { ar1 = flipseq(ar1); ar2 = flipseq(ar2); }
    const u16* ga1 = A + (size_t)ar1 * K + skof;
    const u16* ga2 = A + (size_t)ar2 * K + skof;
    const u16* gb1 = W + (size_t)(n0 + srow) * K + skof;
    const u16* gb2 = gb1 + (size_t)64 * K;
    u16* la1 = As + tid * 8;
    u16* la2 = As + 2048 + tid * 8;
    u16* lb1 = Bs + tid * 8;
    u16* lb2 = Bs + 2048 + tid * 8;

    int aoff[4], boff[4];
    #pragma unroll
    for (int i = 0; i < 4; ++i) {
        aoff[i] = (wrow + i * 16 + (lane & 15)) * 32 + ((lane >> 4) * 8);
        boff[i] = (wcol + i * 16 + (lane & 15)) * 32 + ((lane >> 4) * 8);
    }

    f32x4 acc[4][4] = {};
    for (int kt = 0; kt < K; kt += 32) {
        gload16(ga1, la1); gload16(ga2, la2);
        gload16(gb1, lb1); gload16(gb2, lb2);
        ga1 += 32; ga2 += 32; gb1 += 32; gb2 += 32;
        __syncthreads();
        bf16x8 af[4], bfv[4];
        #pragma unroll
        for (int i = 0; i < 4; ++i) af[i] = *(const bf16x8*)(As + aoff[i]);
        #pragma unroll
        for (int j = 0; j < 4; ++j) bfv[j] = *(const bf16x8*)(Bs + boff[j]);
        #pragma unroll
        for (int i = 0; i < 4; ++i)
            #pragma unroll
            for (int j = 0; j < 4; ++j)
                acc[i][j] = __builtin_amdgcn_mfma_f32_16x16x32_bf16(af[i], bfv[j], acc[i][j], 0, 0, 0);
        __syncthreads();
    }

    int rbase = m0 + wrow + ((lane >> 4) << 2);
    int cbase = n0 + wcol + (lane & 15);
    if (n0 < DINNER) {       // z tile
        u16* Cz = zb0 + (size_t)dir * T * DINNER;
        #pragma unroll
        for (int i = 0; i < 4; ++i)
            #pragma unroll
            for (int j = 0; j < 4; ++j)
                #pragma unroll
                for (int r = 0; r < 4; ++r)
                    Cz[(size_t)(rbase + i * 16 + r) * DINNER + cbase + j * 16] = f2b(acc[i][j][r]);
    } else {                 // xBC tile
        u16* Cx = xbcraw0 + (size_t)dir * T * CONVCH - DINNER;
        #pragma unroll
        for (int i = 0; i < 4; ++i)
            #pragma unroll
            for (int j = 0; j < 4; ++j)
                #pragma unroll
                for (int r = 0; r < 4; ++r)
                    Cx[(size_t)(rbase + i * 16 + r) * CONVCH + cbase + j * 16] = f2b(acc[i][j][r]);
    }
}

// ---------------- bf16 MFMA GEMM, 64x64 tile, z-batched ----------------
__global__ __launch_bounds__(256) void k_mm64(
    const u16* __restrict__ A, size_t astride,
    const u16* __restrict__ W, size_t wstride, int K,
    u16* __restrict__ Cb, float* __restrict__ Cf, int ldc, int coffStride, int flipZ1,
    const float* __restrict__ bias, const float* __restrict__ resid, int ldr)
{
    int dir = blockIdx.z;
    A += (size_t)dir * astride;
    W += (size_t)dir * wstride;
    int coff = dir * coffStride;
    int flip = flipZ1 && dir;

    __shared__ u16 As[64 * 32];
    __shared__ u16 Bs[64 * 32];
    int tid = threadIdx.x;
    int lane = tid & 63;
    int w = tid >> 6;
    int m0 = blockIdx.y * 64, n0 = blockIdx.x * 64;
    int wrow = (w & 1) * 32, wcol = (w >> 1) * 32;

    int srow = tid >> 2, skof = (tid & 3) * 8;
    int ar = m0 + srow;
    if (flip) ar = flipseq(ar);
    const u16* ga = A + (size_t)ar * K + skof;
    const u16* gb = W + (size_t)(n0 + srow) * K + skof;
    u16* la = As + tid * 8;
    u16* lb = Bs + tid * 8;

    int aoff[2], boff[2];
    #pragma unroll
    for (int i = 0; i < 2; ++i) {
        aoff[i] = (wrow + i * 16 + (lane & 15)) * 32 + ((lane >> 4) * 8);
        boff[i] = (wcol + i * 16 + (lane & 15)) * 32 + ((lane >> 4) * 8);
    }

    f32x4 acc[2][2] = {};
    for (int kt = 0; kt < K; kt += 32) {
        gload16(ga, la);
        gload16(gb, lb);
        ga += 32; gb += 32;
        __syncthreads();
        bf16x8 af[2], bfv[2];
        #pragma unroll
        for (int i = 0; i < 2; ++i) af[i] = *(const bf16x8*)(As + aoff[i]);
        #pragma unroll
        for (int j = 0; j < 2; ++j) bfv[j] = *(const bf16x8*)(Bs + boff[j]);
        #pragma unroll
        for (int i = 0; i < 2; ++i)
            #pragma unroll
            for (int j = 0; j < 2; ++j)
                acc[i][j] = __builtin_amdgcn_mfma_f32_16x16x32_bf16(af[i], bfv[j], acc[i][j], 0, 0, 0);
        __syncthreads();
    }

    int rbase = m0 + wrow + ((lane >> 4) << 2);
    int cbase = n0 + wcol + (lane & 15);
    if (Cb) {
        #pragma unroll
        for (int i = 0; i < 2; ++i)
            #pragma unroll
            for (int j = 0; j < 2; ++j)
                #pragma unroll
                for (int r = 0; r < 4; ++r)
                    Cb[(size_t)(rbase + i * 16 + r) * ldc + coff + cbase + j * 16] = f2b(acc[i][j][r]);
    } else {
        #pragma unroll
        for (int i = 0; i < 2; ++i)
            #pragma unroll
            for (int j = 0; j < 2; ++j)
                #pragma unroll
                for (int r = 0; r < 4; ++r) {
                    int row = rbase + i * 16 + r, col = cbase + j * 16;
                    float v = acc[i][j][r];
                    if (bias)  v += bias[col];
                    if (resid) v += resid[(size_t)row * ldr + col];
                    Cf[(size_t)row * ldc + coff + col] = v;
                }
    }
}

// ---------------- dt = softplus(xn . w_dt + bias), 4 rows/block, z = dir ----------------
__global__ __launch_bounds__(256) void k_dt2(
    const u16* __restrict__ xnb,
    const float* __restrict__ inw_f, const float* __restrict__ inw_b,
    const float* __restrict__ dtb_f, const float* __restrict__ dtb_b,
    float* __restrict__ dt)
{
    int dir = blockIdx.z;
    const float* wbase = dir ? inw_b : inw_f;
    const float* dtbia = dir ? dtb_b : dtb_f;
    float* dtp = dt + (size_t)dir * T * NH;

    int r0 = blockIdx.x * 4;
    __shared__ float xs[4][1024];
    int tid = threadIdx.x;
    #pragma unroll
    for (int rr = 0; rr < 4; ++rr) {
        int src = dir ? flipseq(r0 + rr) : (r0 + rr);
        ushort4 v = *(const ushort4*)(xnb + (size_t)src * DMODEL + tid * 4);
        xs[rr][tid * 4 + 0] = b2f(v.x); xs[rr][tid * 4 + 1] = b2f(v.y);
        xs[rr][tid * 4 + 2] = b2f(v.z); xs[rr][tid * 4 + 3] = b2f(v.w);
    }
    __syncthreads();
    int h = tid >> 3, part = tid & 7;
    const float* w = wbase + (size_t)(DPROJ2 + h) * DMODEL;
    float a0 = 0.f, a1 = 0.f, a2 = 0.f, a3 = 0.f;
    for (int kk = 0; kk < 128; ++kk) {
        int k = part + (kk << 3);
        float wv = w[k];
        a0 += xs[0][k] * wv; a1 += xs[1][k] * wv;
        a2 += xs[2][k] * wv; a3 += xs[3][k] * wv;
    }
    #pragma unroll
    for (int off = 4; off > 0; off >>= 1) {
        a0 += __shfl_down(a0, off, 8); a1 += __shfl_down(a1, off, 8);
        a2 += __shfl_down(a2, off, 8); a3 += __shfl_down(a3, off, 8);
    }
    if (part == 0) {
        float bsh = dtbia[h];
        float vv[4] = {a0, a1, a2, a3};
        #pragma unroll
        for (int rr = 0; rr < 4; ++rr) {
            float v = vv[rr] + bsh;
            dtp[(size_t)(r0 + rr) * NH + h] = (v > 20.f) ? v : log1pf(expf(v));
        }
    }
}

// ---------------- conv4 + silu -> bf16 xbcb; x-part * dt -> xdtb; z = dir ----------------
__global__ void k_conv(const u16* __restrict__ xraw0,
                       const float* __restrict__ cw_f, const float* __restrict__ cw_b,
                       const float* __restrict__ cb_f, const float* __restrict__ cb_b,
                       const float* __restrict__ dt0,
                       u16* __restrict__ xbcb0, u16* __restrict__ xdtb0)
{
    int dir = blockIdx.z;
    const u16* xraw = xraw0 + (size_t)dir * T * CONVCH;
    const float* cw = dir ? cw_b : cw_f;
    const float* cb = dir ? cb_b : cb_f;
    const float* dt = dt0 + (size_t)dir * T * NH;
    u16* xbcb = xbcb0 + (size_t)dir * T * CONVCH;
    u16* xdtb = xdtb0 + (size_t)dir * T * DINNER;

    int idx = blockIdx.x * blockDim.x + threadIdx.x;
    if (idx >= T * (CONVCH / 8)) return;
    int r = idx / (CONVCH / 8);
    int c8 = (idx - r * (CONVCH / 8)) * 8;
    int t = r & (SEQL - 1);
    int b0 = r - t;
    float4 cwv[8];
    #pragma unroll
    for (int j = 0; j < 8; ++j) cwv[j] = *(const float4*)(cw + (size_t)(c8 + j) * 4);
    float acc[8];
    {
        float4 c0 = *(const float4*)(cb + c8);
        float4 c1 = *(const float4*)(cb + c8 + 4);
        acc[0] = c0.x; acc[1] = c0.y; acc[2] = c0.z; acc[3] = c0.w;
        acc[4] = c1.x; acc[5] = c1.y; acc[6] = c1.z; acc[7] = c1.w;
    }
    #pragma unroll
    for (int k = 0; k < 4; ++k) {
        int tt = t + k - 3;
        if (tt < 0) continue;
        const u16* src = xraw + (size_t)(b0 + tt) * CONVCH + c8;
        ushort4 v0 = *(const ushort4*)src;
        ushort4 v1 = *(const ushort4*)(src + 4);
        float xv[8] = {b2f(v0.x), b2f(v0.y), b2f(v0.z), b2f(v0.w),
                       b2f(v1.x), b2f(v1.y), b2f(v1.z), b2f(v1.w)};
        #pragma unroll
        for (int j = 0; j < 8; ++j) {
            float wv = (k == 0) ? cwv[j].x : (k == 1) ? cwv[j].y : (k == 2) ? cwv[j].z : cwv[j].w;
            acc[j] += xv[j] * wv;
        }
    }
    ushort4 o0, o1;
    float s[8];
    #pragma unroll
    for (int j = 0; j < 8; ++j) s[j] = acc[j] / (1.f + __expf(-acc[j]));
    o0.x = f2b(s[0]); o0.y = f2b(s[1]); o0.z = f2b(s[2]); o0.w = f2b(s[3]);
    o1.x = f2b(s[4]); o1.y = f2b(s[5]); o1.z = f2b(s[6]); o1.w = f2b(s[7]);
    *(ushort4*)(xbcb + (size_t)r * CONVCH + c8) = o0;
    *(ushort4*)(xbcb + (size_t)r * CONVCH + c8 + 4) = o1;
    if (c8 < DINNER) {
        float dv = dt[(size_t)r * NH + (c8 >> 6)];
        ushort4 d0, d1;
        d0.x = f2b(s[0] * dv); d0.y = f2b(s[1] * dv); d0.z = f2b(s[2] * dv); d0.w = f2b(s[3] * dv);
        d1.x = f2b(s[4] * dv); d1.y = f2b(s[5] * dv); d1.z = f2b(s[6] * dv); d1.w = f2b(s[7] * dv);
        *(ushort4*)(xdtb + (size_t)r * DINNER + c8) = d0;
        *(ushort4*)(xdtb + (size_t)r * DINNER + c8 + 4) = d1;
    }
}

// ---------------- per-chunk cumsum of A*dt; z = dir ----------------
__global__ void k_acs(const float* __restrict__ dt0,
                      const float* __restrict__ Alog_f, const float* __restrict__ Alog_b,
                      float* __restrict__ acs0, float* __restrict__ cd0)
{
    int dir = blockIdx.z;
    const float* dt = dt0 + (size_t)dir * T * NH;
    const float* A_log = dir ? Alog_b : Alog_f;
    float* acs = acs0 + (size_t)dir * BATCH * NH * NCH * CHUNK;
    float* cd = cd0 + (size_t)dir * BATCH * NH * NCH;

    int bid = blockIdx.x;            // (b*NH + h)*NCH + c
    int c = bid & 15;
    int bh = bid >> 4;
    int h = bh & 31;
    int b = bh >> 5;
    int l = threadIdx.x;
    __shared__ float s[128];
    float Ah = -expf(A_log[h]);
    int r = b * SEQL + c * CHUNK + l;
    s[l] = Ah * dt[(size_t)r * NH + h];
    __syncthreads();
    for (int off = 1; off < 128; off <<= 1) {
        float t = (l >= off) ? s[l - off] : 0.f;
        __syncthreads();
        s[l] += t;
        __syncthreads();
    }
    acs[(size_t)bid * 128 + l] = s[l];
    if (l == 127) cd[bid] = expf(s[127]);
}

// ---------------- per-(b,c,h): MFMA Y_diag + chunk states; z = dir ----------------
#define LDW 136
__global__ __launch_bounds__(256) void k_chunk(
    const u16* __restrict__ xbcb0, const u16* __restrict__ xdtb0,
    const float* __restrict__ acs0, u16* __restrict__ y0, u16* __restrict__ st0)
{
    int dir = blockIdx.z;
    const u16* xbcb = xbcb0 + (size_t)dir * T * CONVCH;
    const u16* xdtb = xdtb0 + (size_t)dir * T * DINNER;
    const float* acs = acs0 + (size_t)dir * BATCH * NH * NCH * CHUNK;
    u16* y = y0 + (size_t)dir * T * DINNER;
    u16* st = st0 + (size_t)dir * N_ST;

    __shared__ u16 S0[128 * LDW];   // Bs -> Ps -> Bt(dec-folded)
    __shared__ u16 Xt[64 * LDW];    // Xt[p][l] = X[l][p]*dt[l]
    __shared__ float acs_s[128];
    __shared__ float dec_s[128];
    int tid = threadIdx.x;
    int lane = tid & 63;
    int w = tid >> 6;
    int h = blockIdx.x & 31;
    int bc = blockIdx.x >> 5;
    int c = bc & 15, b = bc >> 4;
    int row0 = b * SEQL + c * CHUNK;

    if (tid < 128) {
        float a = acs[(((size_t)(b * NH + h) * NCH + c) << 7) + tid];
        acs_s[tid] = a;
    }
    for (int i = tid; i < 128 * 16; i += 256) {
        int s = i >> 4, m8 = (i & 15) * 8;
        *(uint4*)(S0 + s * LDW + m8) =
            *(const uint4*)(xbcb + (size_t)(row0 + s) * CONVCH + DINNER + m8);
    }
    for (int i = tid; i < 128 * 16; i += 256) {
        int l = i >> 4, pg = (i & 15) * 4;
        ushort4 v = *(const ushort4*)(xdtb + (size_t)(row0 + l) * DINNER + h * HD + pg);
        Xt[(pg + 0) * LDW + l] = v.x; Xt[(pg + 1) * LDW + l] = v.y;
        Xt[(pg + 2) * LDW + l] = v.z; Xt[(pg + 3) * LDW + l] = v.w;
    }
    __syncthreads();
    float a_last = acs_s[127];
    if (tid < 128) dec_s[tid] = __expf(a_last - acs_s[tid]);

    int wrow = (w & 1) * 64, wcol = (w >> 1) * 64;
    const u16* cbase = xbcb + (size_t)row0 * CONVCH + DINNER + DSTATE;
    f32x4 sacc[4][4] = {};
    for (int kk = 0; kk < 4; ++kk) {
        bf16x8 af[4], bfr[4];
        #pragma unroll
        for (int i = 0; i < 4; ++i)
            af[i] = *(const bf16x8*)(cbase + (size_t)(wrow + i * 16 + (lane & 15)) * CONVCH
                                     + kk * 32 + (lane >> 4) * 8);
        #pragma unroll
        for (int j = 0; j < 4; ++j)
            bfr[j] = *(const bf16x8*)(S0 + (wcol + j * 16 + (lane & 15)) * LDW
                                      + kk * 32 + (lane >> 4) * 8);
        #pragma unroll
        for (int i = 0; i < 4; ++i)
            #pragma unroll
            for (int j = 0; j < 4; ++j)
                if (wcol + j * 16 <= wrow + i * 16 + 15)
                    sacc[i][j] = __builtin_amdgcn_mfma_f32_16x16x32_bf16(af[i], bfr[j], sacc[i][j], 0, 0, 0);
    }
    __syncthreads();
    #pragma unroll
    for (int i = 0; i < 4; ++i)
        #pragma unroll
        for (int j = 0; j < 4; ++j) {
            int s = wcol + j * 16 + (lane & 15);
            #pragma unroll
            for (int r = 0; r < 4; ++r) {
                int l = wrow + i * 16 + (lane >> 4) * 4 + r;
                float v = (s <= l) ? sacc[i][j][r] * __expf(acs_s[l] - acs_s[s]) : 0.f;
                S0[l * LDW + s] = f2b(v);
            }
        }
    __syncthreads();
    f32x4 yacc[2][4] = {};
    for (int kk = 0; kk < 4; ++kk) {
        bf16x8 af[2], bfr[4];
        #pragma unroll
        for (int i = 0; i < 2; ++i)
            af[i] = *(const bf16x8*)(S0 + (w * 32 + i * 16 + (lane & 15)) * LDW
                                     + kk * 32 + (lane >> 4) * 8);
        #pragma unroll
        for (int j = 0; j < 4; ++j)
            bfr[j] = *(const bf16x8*)(Xt + (j * 16 + (lane & 15)) * LDW
                                      + kk * 32 + (lane >> 4) * 8);
        #pragma unroll
        for (int i = 0; i < 2; ++i)
            #pragma unroll
            for (int j = 0; j < 4; ++j)
                yacc[i][j] = __builtin_amdgcn_mfma_f32_16x16x32_bf16(af[i], bfr[j], yacc[i][j], 0, 0, 0);
    }
    #pragma unroll
    for (int i = 0; i < 2; ++i)
        #pragma unroll
        for (int j = 0; j < 4; ++j)
            #pragma unroll
            for (int r = 0; r < 4; ++r) {
                int l = w * 32 + i * 16 + (lane >> 4) * 4 + r;
                int p = j * 16 + (lane & 15);
                y[(size_t)(row0 + l) * DINNER + h * HD + p] = f2b(yacc[i][j][r]);
            }
    __syncthreads();
    for (int i = tid; i < 128 * 32; i += 256) {
        int l = i >> 5, ng = (i & 31) * 4;
        ushort4 v = *(const ushort4*)(xbcb + (size_t)(row0 + l) * CONVCH + DINNER + ng);
        float d = dec_s[l];
        S0[(ng + 0) * LDW + l] = f2b(b2f(v.x) * d);
        S0[(ng + 1) * LDW + l] = f2b(b2f(v.y) * d);
        S0[(ng + 2) * LDW + l] = f2b(b2f(v.z) * d);
        S0[(ng + 3) * LDW + l] = f2b(b2f(v.w) * d);
    }
    __syncthreads();
    f32x4 tacc[8] = {};
    for (int kk = 0; kk < 4; ++kk) {
        bf16x8 afs = *(const bf16x8*)(Xt + (w * 16 + (lane & 15)) * LDW
                                      + kk * 32 + (lane >> 4) * 8);
        #pragma unroll
        for (int j = 0; j < 8; ++j) {
            bf16x8 bfs = *(const bf16x8*)(S0 + (j * 16 + (lane & 15)) * LDW
                                          + kk * 32 + (lane >> 4) * 8);
            tacc[j] = __builtin_amdgcn_mfma_f32_16x16x32_bf16(afs, bfs, tacc[j], 0, 0, 0);
        }
    }
    size_t sb = (size_t)blockIdx.x * (HD * DSTATE);
    #pragma unroll
    for (int j = 0; j < 8; ++j)
        #pragma unroll
        for (int r = 0; r < 4; ++r) {
            int p = w * 16 + (lane >> 4) * 4 + r;
            int n = j * 16 + (lane & 15);
            st[sb + (size_t)p * DSTATE + n] = f2b(tacc[j][r]);
        }
}

// ---------------- inter-chunk scan (in place, bf16), both dirs ----------------
__global__ void k_scan(u16* __restrict__ st0, const float* __restrict__ cd0)
{
    int i = blockIdx.x * blockDim.x + threadIdx.x;
    if (i >= 2 * BATCH * NH * HD * DSTATE) return;
    int dir = i >> 19;                  // BATCH*NH*HD*DSTATE == 1<<19
    int j = i & ((1 << 19) - 1);
    u16* st = st0 + (size_t)dir * N_ST;
    const float* cd = cd0 + (size_t)dir * BATCH * NH * NCH;
    int n = j & 127;
    int rest = j >> 7;
    int p = rest & 63; rest >>= 6;
    int h = rest & 31;
    int b = rest >> 5;
    float s = 0.f;
    for (int c = 0; c < NCH; ++c) {
        size_t idx = ((size_t)((b * NCH + c) * NH + h) * HD + p) * DSTATE + n;
        float v = b2f(st[idx]);
        st[idx] = f2b(s);                              // prev_c
        s = s * cd[(b * NH + h) * NCH + c] + v;        // carry (fp32)
    }
}

// ---------------- Y_off: y += exp(acs[l]) * C@prev^T + xh*D; z = dir ----------------
__global__ __launch_bounds__(256) void k_yoff(
    const u16* __restrict__ xbcb0, const u16* __restrict__ prev0,
    const float* __restrict__ acs0,
    const float* __restrict__ D_f, const float* __restrict__ D_b,
    u16* __restrict__ y0)
{
    int dir = blockIdx.z;
    const u16* xbcb = xbcb0 + (size_t)dir * T * CONVCH;
    const u16* prev = prev0 + (size_t)dir * N_ST;
    const float* acs = acs0 + (size_t)dir * BATCH * NH * NCH * CHUNK;
    const float* Dp = dir ? D_b : D_f;
    u16* y = y0 + (size_t)dir * T * DINNER;

    __shared__ u16 Pv[64 * LDW];
    __shared__ float acs_s[128];
    int tid = threadIdx.x, lane = tid & 63, w = tid >> 6;
    int h = blockIdx.x & 31;
    int bc = blockIdx.x >> 5;
    int c = bc & 15, b = bc >> 4;
    int row0 = b * SEQL + c * CHUNK;
    size_t sb = (size_t)blockIdx.x * (HD * DSTATE);
    for (int i = tid; i < 64 * 16; i += 256) {
        int p = i >> 4, m8 = (i & 15) * 8;
        *(uint4*)(Pv + p * LDW + m8) = *(const uint4*)(prev + sb + (size_t)p * DSTATE + m8);
    }
    if (tid < 128) acs_s[tid] = acs[(((size_t)(b * NH + h) * NCH + c) << 7) + tid];
    __syncthreads();
    const u16* cbase = xbcb + (size_t)row0 * CONVCH + DINNER + DSTATE;
    f32x4 acc[2][4] = {};
    for (int kk = 0; kk < 4; ++kk) {
        bf16x8 af[2], bfr[4];
        #pragma unroll
        for (int i = 0; i < 2; ++i)
            af[i] = *(const bf16x8*)(cbase + (size_t)(w * 32 + i * 16 + (lane & 15)) * CONVCH
                                     + kk * 32 + (lane >> 4) * 8);
        #pragma unroll
        for (int j = 0; j < 4; ++j)
            bfr[j] = *(const bf16x8*)(Pv + (j * 16 + (lane & 15)) * LDW
                                      + kk * 32 + (lane >> 4) * 8);
        #pragma unroll
        for (int i = 0; i < 2; ++i)
            #pragma unroll
            for (int j = 0; j < 4; ++j)
                acc[i][j] = __builtin_amdgcn_mfma_f32_16x16x32_bf16(af[i], bfr[j], acc[i][j], 0, 0, 0);
    }
    float Dh = Dp[h];
    #pragma unroll
    for (int i = 0; i < 2; ++i)
        #pragma unroll
        for (int j = 0; j < 4; ++j)
            #pragma unroll
            for (int r = 0; r < 4; ++r) {
                int l = w * 32 + i * 16 + (lane >> 4) * 4 + r;
                int p = j * 16 + (lane & 15);
                size_t yi = (size_t)(row0 + l) * DINNER + h * HD + p;
                float val = b2f(y[yi]) + __expf(acs_s[l]) * acc[i][j][r]
                          + b2f(xbcb[(size_t)(row0 + l) * CONVCH + h * HD + p]) * Dh;
                y[yi] = f2b(val);
            }
}

// ---------------- gated rmsnorm -> bf16; z = dir ----------------
__global__ __launch_bounds__(256) void k_gate(
    const u16* __restrict__ y0, const u16* __restrict__ zb0,
    const float* __restrict__ gw_f, const float* __restrict__ gw_b,
    u16* __restrict__ out0)
{
    int dir = blockIdx.z;
    const u16* y = y0 + (size_t)dir * T * DINNER;
    const u16* zb = zb0 + (size_t)dir * T * DINNER;
    const float* gw = dir ? gw_b : gw_f;
    u16* out = out0 + (size_t)dir * T * DINNER;

    int r = blockIdx.x;
    __shared__ float tbuf[DINNER];
    int tid = threadIdx.x;
    float ss = 0.f;
    #pragma unroll
    for (int it = 0; it < 2; ++it) {
        int i = (it * 256 + tid) * 4;
        ushort4 yv = *(const ushort4*)(y + (size_t)r * DINNER + i);
        ushort4 zv = *(const ushort4*)(zb + (size_t)r * DINNER + i);
        float z0 = b2f(zv.x), z1 = b2f(zv.y), z2 = b2f(zv.z), z3 = b2f(zv.w);
        float t0 = b2f(yv.x) * (z0 / (1.f + __expf(-z0)));
        float t1 = b2f(yv.y) * (z1 / (1.f + __expf(-z1)));
        float t2 = b2f(yv.z) * (z2 / (1.f + __expf(-z2)));
        float t3 = b2f(yv.w) * (z3 / (1.f + __expf(-z3)));
        tbuf[i] = t0; tbuf[i + 1] = t1; tbuf[i + 2] = t2; tbuf[i + 3] = t3;
        ss += t0 * t0 + t1 * t1 + t2 * t2 + t3 * t3;
    }
    float tot = blockReduceSum(ss);
    float sc = rsqrtf(tot / DINNER + EPS);
    #pragma unroll
    for (int it = 0; it < 2; ++it) {
        int i = (it * 256 + tid) * 4;
        ushort4 o;
        o.x = f2b(tbuf[i] * sc * gw[i]);
        o.y = f2b(tbuf[i + 1] * sc * gw[i + 1]);
        o.z = f2b(tbuf[i + 2] * sc * gw[i + 2]);
        o.w = f2b(tbuf[i + 3] * sc * gw[i + 3]);
        *(ushort4*)(out + (size_t)r * DINNER + i) = o;
    }
}

// ---------------- launch ----------------
extern "C" void kernel_launch(void* const* d_in, const int* in_sizes, int n_in,
                              void* d_out, int out_size, void* d_ws, size_t ws_size,
                              hipStream_t stream)
{
    const float* x         = (const float*)d_in[0];
    const float* norm_w    = (const float*)d_in[1];
    const float* out_w_blk = (const float*)d_in[2];
    const float* out_b_blk = (const float*)d_in[3];
    const float* f_in_w    = (const float*)d_in[4];
    const float* f_conv_w  = (const float*)d_in[5];
    const float* f_conv_b  = (const float*)d_in[6];
    const float* f_dt_bias = (const float*)d_in[7];
    const float* f_A_log   = (const float*)d_in[8];
    const float* f_D       = (const float*)d_in[9];
    const float* f_gnorm_w = (const float*)d_in[10];
    const float* f_out_w   = (const float*)d_in[11];
    const float* b_in_w    = (const float*)d_in[12];
    const float* b_conv_w  = (const float*)d_in[13];
    const float* b_conv_b  = (const float*)d_in[14];
    const float* b_dt_bias = (const float*)d_in[15];
    const float* b_A_log   = (const float*)d_in[16];
    const float* b_D       = (const float*)d_in[17];
    const float* b_gnorm_w = (const float*)d_in[18];
    const float* b_out_w   = (const float*)d_in[19];
    float* out = (float*)d_out;

    // ---- workspace layout with liveness overlap (total ~207 MB) ----
    char* ws = (char*)d_ws;
    u16*  xnb    = (u16*)ws;   ws += (size_t)T * DMODEL * 2;          // 8.4 MB
    u16*  zb     = (u16*)ws;   ws += (size_t)2 * T * DINNER * 2;      // 33.6 MB (z, live->gate)
    u16*  xbcraw = (u16*)ws;   ws += (size_t)2 * T * CONVCH * 2;      // 37.7 MB (dead after conv)
    u16*  xbcb   = (u16*)ws;   ws += (size_t)2 * T * CONVCH * 2;      // 37.7 MB (dead after yoff)
    u16*  xdtb   = (u16*)ws;   ws += (size_t)2 * T * DINNER * 2;      // 33.6 MB (dead after chunk)
    float* dtb   = (float*)ws; ws += (size_t)2 * T * NH * 4;          // 1 MB
    float* acs   = (float*)ws; ws += (size_t)2 * BATCH * NH * NCH * CHUNK * 4;  // 1 MB
    float* cd    = (float*)ws; ws += (size_t)2 * BATCH * NH * NCH * 4;          // 8 KB
    u16*  stb    = (u16*)ws;   ws += (size_t)2 * N_ST * 2;            // 33.6 MB (bf16)
    u16*  inwb   = (u16*)ws;   ws += (size_t)2 * N_INW * 2;           // 17.8 MB
    u16*  outwb  = (u16*)ws;   ws += (size_t)2 * N_OUTW * 2;          // 8.4 MB
    u16*  owbb   = (u16*)ws;   ws += (size_t)N_OUTW * 2;              // 4.2 MB
    // aliases (liveness-safe reuse)
    u16*  yb16 = xbcraw;   // Y (bf16, 2*T*DINNER <= 2*T*CONVCH), written by k_chunk
    u16*  ybb  = xdtb;     // gated-norm output, written by k_gate
    u16*  catb = xbcb;     // concat buffer (T*2*DMODEL <= 2*T*CONVCH), written by out-proj

    k_rmsnorm<<<T, 256, 0, stream>>>(x, norm_w, xnb);
    {
        size_t tot = 2 * N_INW + 3 * N_OUTW;
        int blocks = (int)((tot / 4 + 255) / 256);
        k_f2b_all<<<blocks, 256, 0, stream>>>(f_in_w, b_in_w, f_out_w, b_out_w,
                                              out_w_blk, inwb, outwb, owbb);
    }

    // in-proj both dirs: z -> zb, xBC -> xbcraw
    {
        dim3 g(DPROJ2 / 128, T / 128, 2);
        k_mm_in<<<g, 256, 0, stream>>>(xnb, inwb, zb, xbcraw);
    }
    {
        dim3 g(T / 4, 1, 2);
        k_dt2<<<g, 256, 0, stream>>>(xnb, f_in_w, b_in_w, f_dt_bias, b_dt_bias, dtb);
    }
    {
        dim3 g((T * (CONVCH / 8) + 255) / 256, 1, 2);
        k_conv<<<g, 256, 0, stream>>>(xbcraw, f_conv_w, b_conv_w, f_conv_b, b_conv_b,
                                      dtb, xbcb, xdtb);
    }
    {
        dim3 g(BATCH * NH * NCH, 1, 2);
        k_acs<<<g, 128, 0, stream>>>(dtb, f_A_log, b_A_log, acs, cd);
    }
    {
        dim3 g(BATCH * NCH * NH, 1, 2);
        k_chunk<<<g, 256, 0, stream>>>(xbcb, xdtb, acs, yb16, stb);
    }
    k_scan<<<(2 * BATCH * NH * HD * DSTATE) / 256, 256, 0, stream>>>(stb, cd);
    {
        dim3 g(BATCH * NCH * NH, 1, 2);
        k_yoff<<<g, 256, 0, stream>>>(xbcb, stb, acs, f_D, b_D, yb16);
    }
    {
        dim3 g(T, 1, 2);
        k_gate<<<g, 256, 0, stream>>>(yb16, zb, f_gnorm_w, b_gnorm_w, ybb);
    }
    // out-proj both dirs -> catb (bf16), bwd rows un-flipped at A-read
    {
        dim3 g(DMODEL / 64, T / 64, 2);
        k_mm64<<<g, 256, 0, stream>>>(ybb, (size_t)T * DINNER,
                                      outwb, N_OUTW, DINNER,
                                      catb, nullptr, 2 * DMODEL, DMODEL, 1,
                                      nullptr, nullptr, 0);
    }
    // final: out = cat @ out_w_blk^T + bias + x
    {
        dim3 g(DMODEL / 64, T / 64, 1);
        k_mm64<<<g, 256, 0, stream>>>(catb, 0,
                                      owbb, 0, DINNER,
                                      nullptr, out, DMODEL, 0, 0,
                                      out_b_blk, x, DMODEL);
    }
}

// Round 7
// 644.420 us; speedup vs baseline: 7.0081x; 1.1290x over previous
//
#include <hip/hip_runtime.h>
#include <hip/hip_bf16.h>
#include <math.h>

#define BATCH 2
#define SEQL 2048
#define T 4096            // BATCH*SEQL tokens
#define DMODEL 1024
#define DINNER 2048
#define DSTATE 128
#define NH 32
#define HD 64
#define DPROJ2 4352       // z (2048) + xBC (2304); dt handled separately in fp32
#define CONVCH 2304
#define NCH 16            // chunks per sequence
#define CHUNK 128
#define EPS 1e-5f

#define N_INW ((size_t)DPROJ2 * DMODEL)   // 4,456,448
#define N_OUTW ((size_t)DMODEL * DINNER)  // 2,097,152
#define N_ST ((size_t)BATCH * NCH * NH * HD * DSTATE)  // 8,388,608 per dir

typedef unsigned short u16;
typedef __bf16 bf16x8 __attribute__((ext_vector_type(8)));
typedef float f32x4 __attribute__((ext_vector_type(4)));

__device__ __forceinline__ u16 f2b(float f) {
    union { float f; unsigned u; } v; v.f = f;
    unsigned r = v.u + 0x7fffu + ((v.u >> 16) & 1u);
    return (u16)(r >> 16);
}
__device__ __forceinline__ float b2f(u16 b) {
    union { unsigned u; float f; } v; v.u = ((unsigned)b) << 16;
    return v.f;
}
__device__ __forceinline__ int flipseq(int r) {
    return (r & ~(SEQL - 1)) | ((SEQL - 1) - (r & (SEQL - 1)));
}
__device__ __forceinline__ void gload16(const u16* g, u16* l) {
    __builtin_amdgcn_global_load_lds(
        (const __attribute__((address_space(1))) void*)g,
        (__attribute__((address_space(3))) void*)l, 16, 0, 0);
}

// ---------------- block reduce ----------------
__device__ __forceinline__ float blockReduceSum(float v) {
    __shared__ float red_[4];
    for (int off = 32; off > 0; off >>= 1) v += __shfl_down(v, off);
    int lane = threadIdx.x & 63, wid = threadIdx.x >> 6;
    if (lane == 0) red_[wid] = v;
    __syncthreads();
    if (threadIdx.x == 0) {
        float s = 0.f;
        int nw = blockDim.x >> 6;
        for (int i = 0; i < nw; ++i) s += red_[i];
        red_[0] = s;
    }
    __syncthreads();
    return red_[0];
}

// ---------------- input rmsnorm -> bf16 ----------------
__global__ __launch_bounds__(256) void k_rmsnorm(
    const float* __restrict__ x, const float* __restrict__ w,
    u16* __restrict__ outb)
{
    int row = blockIdx.x;
    const float* xr = x + (size_t)row * DMODEL;
    float ss = 0.f;
    for (int i = threadIdx.x; i < DMODEL; i += 256) { float v = xr[i]; ss += v * v; }
    float tot = blockReduceSum(ss);
    float sc = rsqrtf(tot / DMODEL + EPS);
    for (int i = threadIdx.x; i < DMODEL; i += 256)
        outb[(size_t)row * DMODEL + i] = f2b(xr[i] * sc * w[i]);
}

// ---------------- all weights fp32 -> bf16, one launch ----------------
__global__ void k_f2b_all(
    const float* __restrict__ s0, const float* __restrict__ s1,  // f_in_w, b_in_w
    const float* __restrict__ s2, const float* __restrict__ s3,  // f_out_w, b_out_w
    const float* __restrict__ s4,                                // out_w_blk
    u16* __restrict__ d_inwb, u16* __restrict__ d_outwb, u16* __restrict__ d_owbb)
{
    size_t i = ((size_t)blockIdx.x * 256 + threadIdx.x) * 4;
    const float* s; u16* d; size_t off;
    if (i < 2 * N_INW) {
        int dir = i >= N_INW;
        off = i - (size_t)dir * N_INW;
        s = dir ? s1 : s0; d = d_inwb + (size_t)dir * N_INW;
    } else {
        size_t j = i - 2 * N_INW;
        if (j < 2 * N_OUTW) {
            int dir = j >= N_OUTW;
            off = j - (size_t)dir * N_OUTW;
            s = dir ? s3 : s2; d = d_outwb + (size_t)dir * N_OUTW;
        } else {
            off = j - 2 * N_OUTW;
            if (off >= N_OUTW) return;
            s = s4; d = d_owbb;
        }
    }
    float4 v = *(const float4*)(s + off);
    ushort4 o;
    o.x = f2b(v.x); o.y = f2b(v.y); o.z = f2b(v.z); o.w = f2b(v.w);
    *(ushort4*)(d + off) = o;
}

// ---------------- in-proj: bf16 MFMA GEMM 128x128, z = dir ----------------
// Output-target select hoisted above the K-loop (block-uniform) — the in-loop
// branch version compiled to 132 VGPR and halved occupancy (R6 regression).
__global__ __launch_bounds__(256, 4) void k_mm_in(
    const u16* __restrict__ A, const u16* __restrict__ W0,
    u16* __restrict__ zb0, u16* __restrict__ xbcraw0)
{
    const int K = DMODEL;
    int dir = blockIdx.z;
    const u16* W = W0 + (size_t)dir * N_INW;
    int m0 = blockIdx.y * 128, n0 = blockIdx.x * 128;

    // block-uniform output select (stays in scalar regs)
    u16* Cout;
    int ldcc, nbase;
    if (n0 < DINNER) {
        Cout = zb0 + (size_t)dir * T * DINNER;
        ldcc = DINNER;
        nbase = n0;
    } else {
        Cout = xbcraw0 + (size_t)dir * T * CONVCH;
        ldcc = CONVCH;
        nbase = n0 - DINNER;
    }

    __shared__ u16 As[128 * 32];
    __shared__ u16 Bs[128 * 32];
    int tid = threadIdx.x;
    int lane = tid & 63;
    int wrow = ((tid >> 6) & 1) * 64, wcol = (tid >> 7) * 64;

    int srow = tid >> 2, skof = (tid & 3) * 8;
    int ar1 = m0 + srow, ar2 = ar1 + 64;
    if (dir) { ar1 = flipseq(ar1); ar2 = flipseq(ar2); }
    const u16* ga1 = A + (size_t)ar1 * K + skof;
    const u16* ga2 = A + (size_t)ar2 * K + skof;
    const u16* gb1 = W + (size_t)(n0 + srow) * K + skof;
    const u16* gb2 = gb1 + (size_t)64 * K;
    u16* la1 = As + tid * 8;
    u16* la2 = As + 2048 + tid * 8;
    u16* lb1 = Bs + tid * 8;
    u16* lb2 = Bs + 2048 + tid * 8;

    int aoff[4], boff[4];
    #pragma unroll
    for (int i = 0; i < 4; ++i) {
        aoff[i] = (wrow + i * 16 + (lane & 15)) * 32 + ((lane >> 4) * 8);
        boff[i] = (wcol + i * 16 + (lane & 15)) * 32 + ((lane >> 4) * 8);
    }

    f32x4 acc[4][4] = {};
    for (int kt = 0; kt < K; kt += 32) {
        gload16(ga1, la1); gload16(ga2, la2);
        gload16(gb1, lb1); gload16(gb2, lb2);
        ga1 += 32; ga2 += 32; gb1 += 32; gb2 += 32;
        __syncthreads();
        bf16x8 af[4], bfv[4];
        #pragma unroll
        for (int i = 0; i < 4; ++i) af[i] = *(const bf16x8*)(As + aoff[i]);
        #pragma unroll
        for (int j = 0; j < 4; ++j) bfv[j] = *(const bf16x8*)(Bs + boff[j]);
        #pragma unroll
        for (int i = 0; i < 4; ++i)
            #pragma unroll
            for (int j = 0; j < 4; ++j)
                acc[i][j] = __builtin_amdgcn_mfma_f32_16x16x32_bf16(af[i], bfv[j], acc[i][j], 0, 0, 0);
        __syncthreads();
    }

    int rbase = m0 + wrow + ((lane >> 4) << 2);
    int cbase = nbase + wcol + (lane & 15);
    #pragma unroll
    for (int i = 0; i < 4; ++i)
        #pragma unroll
        for (int j = 0; j < 4; ++j)
            #pragma unroll
            for (int r = 0; r < 4; ++r)
                Cout[(size_t)(rbase + i * 16 + r) * ldcc + cbase + j * 16] = f2b(acc[i][j][r]);
}

// ---------------- bf16 MFMA GEMM, 64x64 tile, z-batched ----------------
__global__ __launch_bounds__(256) void k_mm64(
    const u16* __restrict__ A, size_t astride,
    const u16* __restrict__ W, size_t wstride, int K,
    u16* __restrict__ Cb, float* __restrict__ Cf, int ldc, int coffStride, int flipZ1,
    const float* __restrict__ bias, const float* __restrict__ resid, int ldr)
{
    int dir = blockIdx.z;
    A += (size_t)dir * astride;
    W += (size_t)dir * wstride;
    int coff = dir * coffStride;
    int flip = flipZ1 && dir;

    __shared__ u16 As[64 * 32];
    __shared__ u16 Bs[64 * 32];
    int tid = threadIdx.x;
    int lane = tid & 63;
    int w = tid >> 6;
    int m0 = blockIdx.y * 64, n0 = blockIdx.x * 64;
    int wrow = (w & 1) * 32, wcol = (w >> 1) * 32;

    int srow = tid >> 2, skof = (tid & 3) * 8;
    int ar = m0 + srow;
    if (flip) ar = flipseq(ar);
    const u16* ga = A + (size_t)ar * K + skof;
    const u16* gb = W + (size_t)(n0 + srow) * K + skof;
    u16* la = As + tid * 8;
    u16* lb = Bs + tid * 8;

    int aoff[2], boff[2];
    #pragma unroll
    for (int i = 0; i < 2; ++i) {
        aoff[i] = (wrow + i * 16 + (lane & 15)) * 32 + ((lane >> 4) * 8);
        boff[i] = (wcol + i * 16 + (lane & 15)) * 32 + ((lane >> 4) * 8);
    }

    f32x4 acc[2][2] = {};
    for (int kt = 0; kt < K; kt += 32) {
        gload16(ga, la);
        gload16(gb, lb);
        ga += 32; gb += 32;
        __syncthreads();
        bf16x8 af[2], bfv[2];
        #pragma unroll
        for (int i = 0; i < 2; ++i) af[i] = *(const bf16x8*)(As + aoff[i]);
        #pragma unroll
        for (int j = 0; j < 2; ++j) bfv[j] = *(const bf16x8*)(Bs + boff[j]);
        #pragma unroll
        for (int i = 0; i < 2; ++i)
            #pragma unroll
            for (int j = 0; j < 2; ++j)
                acc[i][j] = __builtin_amdgcn_mfma_f32_16x16x32_bf16(af[i], bfv[j], acc[i][j], 0, 0, 0);
        __syncthreads();
    }

    int rbase = m0 + wrow + ((lane >> 4) << 2);
    int cbase = n0 + wcol + (lane & 15);
    if (Cb) {
        #pragma unroll
        for (int i = 0; i < 2; ++i)
            #pragma unroll
            for (int j = 0; j < 2; ++j)
                #pragma unroll
                for (int r = 0; r < 4; ++r)
                    Cb[(size_t)(rbase + i * 16 + r) * ldc + coff + cbase + j * 16] = f2b(acc[i][j][r]);
    } else {
        #pragma unroll
        for (int i = 0; i < 2; ++i)
            #pragma unroll
            for (int j = 0; j < 2; ++j)
                #pragma unroll
                for (int r = 0; r < 4; ++r) {
                    int row = rbase + i * 16 + r, col = cbase + j * 16;
                    float v = acc[i][j][r];
                    if (bias)  v += bias[col];
                    if (resid) v += resid[(size_t)row * ldr + col];
                    Cf[(size_t)row * ldc + coff + col] = v;
                }
    }
}

// ---------------- dt = softplus(xn . w_dt + bias), 4 rows/block, z = dir ----------------
__global__ __launch_bounds__(256) void k_dt2(
    const u16* __restrict__ xnb,
    const float* __restrict__ inw_f, const float* __restrict__ inw_b,
    const float* __restrict__ dtb_f, const float* __restrict__ dtb_b,
    float* __restrict__ dt)
{
    int dir = blockIdx.z;
    const float* wbase = dir ? inw_b : inw_f;
    const float* dtbia = dir ? dtb_b : dtb_f;
    float* dtp = dt + (size_t)dir * T * NH;

    int r0 = blockIdx.x * 4;
    __shared__ float xs[4][1024];
    int tid = threadIdx.x;
    #pragma unroll
    for (int rr = 0; rr < 4; ++rr) {
        int src = dir ? flipseq(r0 + rr) : (r0 + rr);
        ushort4 v = *(const ushort4*)(xnb + (size_t)src * DMODEL + tid * 4);
        xs[rr][tid * 4 + 0] = b2f(v.x); xs[rr][tid * 4 + 1] = b2f(v.y);
        xs[rr][tid * 4 + 2] = b2f(v.z); xs[rr][tid * 4 + 3] = b2f(v.w);
    }
    __syncthreads();
    int h = tid >> 3, part = tid & 7;
    const float* w = wbase + (size_t)(DPROJ2 + h) * DMODEL;
    float a0 = 0.f, a1 = 0.f, a2 = 0.f, a3 = 0.f;
    for (int kk = 0; kk < 128; ++kk) {
        int k = part + (kk << 3);
        float wv = w[k];
        a0 += xs[0][k] * wv; a1 += xs[1][k] * wv;
        a2 += xs[2][k] * wv; a3 += xs[3][k] * wv;
    }
    #pragma unroll
    for (int off = 4; off > 0; off >>= 1) {
        a0 += __shfl_down(a0, off, 8); a1 += __shfl_down(a1, off, 8);
        a2 += __shfl_down(a2, off, 8); a3 += __shfl_down(a3, off, 8);
    }
    if (part == 0) {
        float bsh = dtbia[h];
        float vv[4] = {a0, a1, a2, a3};
        #pragma unroll
        for (int rr = 0; rr < 4; ++rr) {
            float v = vv[rr] + bsh;
            dtp[(size_t)(r0 + rr) * NH + h] = (v > 20.f) ? v : log1pf(expf(v));
        }
    }
}

// ---------------- conv4 + silu -> bf16 xbcb; x-part * dt -> xdtb; z = dir ----------------
__global__ void k_conv(const u16* __restrict__ xraw0,
                       const float* __restrict__ cw_f, const float* __restrict__ cw_b,
                       const float* __restrict__ cb_f, const float* __restrict__ cb_b,
                       const float* __restrict__ dt0,
                       u16* __restrict__ xbcb0, u16* __restrict__ xdtb0)
{
    int dir = blockIdx.z;
    const u16* xraw = xraw0 + (size_t)dir * T * CONVCH;
    const float* cw = dir ? cw_b : cw_f;
    const float* cb = dir ? cb_b : cb_f;
    const float* dt = dt0 + (size_t)dir * T * NH;
    u16* xbcb = xbcb0 + (size_t)dir * T * CONVCH;
    u16* xdtb = xdtb0 + (size_t)dir * T * DINNER;

    int idx = blockIdx.x * blockDim.x + threadIdx.x;
    if (idx >= T * (CONVCH / 8)) return;
    int r = idx / (CONVCH / 8);
    int c8 = (idx - r * (CONVCH / 8)) * 8;
    int t = r & (SEQL - 1);
    int b0 = r - t;
    float4 cwv[8];
    #pragma unroll
    for (int j = 0; j < 8; ++j) cwv[j] = *(const float4*)(cw + (size_t)(c8 + j) * 4);
    float acc[8];
    {
        float4 c0 = *(const float4*)(cb + c8);
        float4 c1 = *(const float4*)(cb + c8 + 4);
        acc[0] = c0.x; acc[1] = c0.y; acc[2] = c0.z; acc[3] = c0.w;
        acc[4] = c1.x; acc[5] = c1.y; acc[6] = c1.z; acc[7] = c1.w;
    }
    #pragma unroll
    for (int k = 0; k < 4; ++k) {
        int tt = t + k - 3;
        if (tt < 0) continue;
        const u16* src = xraw + (size_t)(b0 + tt) * CONVCH + c8;
        ushort4 v0 = *(const ushort4*)src;
        ushort4 v1 = *(const ushort4*)(src + 4);
        float xv[8] = {b2f(v0.x), b2f(v0.y), b2f(v0.z), b2f(v0.w),
                       b2f(v1.x), b2f(v1.y), b2f(v1.z), b2f(v1.w)};
        #pragma unroll
        for (int j = 0; j < 8; ++j) {
            float wv = (k == 0) ? cwv[j].x : (k == 1) ? cwv[j].y : (k == 2) ? cwv[j].z : cwv[j].w;
            acc[j] += xv[j] * wv;
        }
    }
    ushort4 o0, o1;
    float s[8];
    #pragma unroll
    for (int j = 0; j < 8; ++j) s[j] = acc[j] / (1.f + __expf(-acc[j]));
    o0.x = f2b(s[0]); o0.y = f2b(s[1]); o0.z = f2b(s[2]); o0.w = f2b(s[3]);
    o1.x = f2b(s[4]); o1.y = f2b(s[5]); o1.z = f2b(s[6]); o1.w = f2b(s[7]);
    *(ushort4*)(xbcb + (size_t)r * CONVCH + c8) = o0;
    *(ushort4*)(xbcb + (size_t)r * CONVCH + c8 + 4) = o1;
    if (c8 < DINNER) {
        float dv = dt[(size_t)r * NH + (c8 >> 6)];
        ushort4 d0, d1;
        d0.x = f2b(s[0] * dv); d0.y = f2b(s[1] * dv); d0.z = f2b(s[2] * dv); d0.w = f2b(s[3] * dv);
        d1.x = f2b(s[4] * dv); d1.y = f2b(s[5] * dv); d1.z = f2b(s[6] * dv); d1.w = f2b(s[7] * dv);
        *(ushort4*)(xdtb + (size_t)r * DINNER + c8) = d0;
        *(ushort4*)(xdtb + (size_t)r * DINNER + c8 + 4) = d1;
    }
}

// ---------------- per-chunk cumsum of A*dt; z = dir ----------------
__global__ void k_acs(const float* __restrict__ dt0,
                      const float* __restrict__ Alog_f, const float* __restrict__ Alog_b,
                      float* __restrict__ acs0, float* __restrict__ cd0)
{
    int dir = blockIdx.z;
    const float* dt = dt0 + (size_t)dir * T * NH;
    const float* A_log = dir ? Alog_b : Alog_f;
    float* acs = acs0 + (size_t)dir * BATCH * NH * NCH * CHUNK;
    float* cd = cd0 + (size_t)dir * BATCH * NH * NCH;

    int bid = blockIdx.x;            // (b*NH + h)*NCH + c
    int c = bid & 15;
    int bh = bid >> 4;
    int h = bh & 31;
    int b = bh >> 5;
    int l = threadIdx.x;
    __shared__ float s[128];
    float Ah = -expf(A_log[h]);
    int r = b * SEQL + c * CHUNK + l;
    s[l] = Ah * dt[(size_t)r * NH + h];
    __syncthreads();
    for (int off = 1; off < 128; off <<= 1) {
        float t = (l >= off) ? s[l - off] : 0.f;
        __syncthreads();
        s[l] += t;
        __syncthreads();
    }
    acs[(size_t)bid * 128 + l] = s[l];
    if (l == 127) cd[bid] = expf(s[127]);
}

// ---------------- per-(b,c,h): MFMA Y_diag + chunk states; z = dir ----------------
#define LDW 136
__global__ __launch_bounds__(256) void k_chunk(
    const u16* __restrict__ xbcb0, const u16* __restrict__ xdtb0,
    const float* __restrict__ acs0, u16* __restrict__ y0, u16* __restrict__ st0)
{
    int dir = blockIdx.z;
    const u16* xbcb = xbcb0 + (size_t)dir * T * CONVCH;
    const u16* xdtb = xdtb0 + (size_t)dir * T * DINNER;
    const float* acs = acs0 + (size_t)dir * BATCH * NH * NCH * CHUNK;
    u16* y = y0 + (size_t)dir * T * DINNER;
    u16* st = st0 + (size_t)dir * N_ST;

    __shared__ u16 S0[128 * LDW];   // Bs -> Ps -> Bt(dec-folded)
    __shared__ u16 Xt[64 * LDW];    // Xt[p][l] = X[l][p]*dt[l]
    __shared__ float acs_s[128];
    __shared__ float dec_s[128];
    int tid = threadIdx.x;
    int lane = tid & 63;
    int w = tid >> 6;
    int h = blockIdx.x & 31;
    int bc = blockIdx.x >> 5;
    int c = bc & 15, b = bc >> 4;
    int row0 = b * SEQL + c * CHUNK;

    if (tid < 128) {
        float a = acs[(((size_t)(b * NH + h) * NCH + c) << 7) + tid];
        acs_s[tid] = a;
    }
    for (int i = tid; i < 128 * 16; i += 256) {
        int s = i >> 4, m8 = (i & 15) * 8;
        *(uint4*)(S0 + s * LDW + m8) =
            *(const uint4*)(xbcb + (size_t)(row0 + s) * CONVCH + DINNER + m8);
    }
    for (int i = tid; i < 128 * 16; i += 256) {
        int l = i >> 4, pg = (i & 15) * 4;
        ushort4 v = *(const ushort4*)(xdtb + (size_t)(row0 + l) * DINNER + h * HD + pg);
        Xt[(pg + 0) * LDW + l] = v.x; Xt[(pg + 1) * LDW + l] = v.y;
        Xt[(pg + 2) * LDW + l] = v.z; Xt[(pg + 3) * LDW + l] = v.w;
    }
    __syncthreads();
    float a_last = acs_s[127];
    if (tid < 128) dec_s[tid] = __expf(a_last - acs_s[tid]);

    int wrow = (w & 1) * 64, wcol = (w >> 1) * 64;
    const u16* cbase = xbcb + (size_t)row0 * CONVCH + DINNER + DSTATE;
    f32x4 sacc[4][4] = {};
    for (int kk = 0; kk < 4; ++kk) {
        bf16x8 af[4], bfr[4];
        #pragma unroll
        for (int i = 0; i < 4; ++i)
            af[i] = *(const bf16x8*)(cbase + (size_t)(wrow + i * 16 + (lane & 15)) * CONVCH
                                     + kk * 32 + (lane >> 4) * 8);
        #pragma unroll
        for (int j = 0; j < 4; ++j)
            bfr[j] = *(const bf16x8*)(S0 + (wcol + j * 16 + (lane & 15)) * LDW
                                      + kk * 32 + (lane >> 4) * 8);
        #pragma unroll
        for (int i = 0; i < 4; ++i)
            #pragma unroll
            for (int j = 0; j < 4; ++j)
                if (wcol + j * 16 <= wrow + i * 16 + 15)
                    sacc[i][j] = __builtin_amdgcn_mfma_f32_16x16x32_bf16(af[i], bfr[j], sacc[i][j], 0, 0, 0);
    }
    __syncthreads();
    #pragma unroll
    for (int i = 0; i < 4; ++i)
        #pragma unroll
        for (int j = 0; j < 4; ++j) {
            int s = wcol + j * 16 + (lane & 15);
            #pragma unroll
            for (int r = 0; r < 4; ++r) {
                int l = wrow + i * 16 + (lane >> 4) * 4 + r;
                float v = (s <= l) ? sacc[i][j][r] * __expf(acs_s[l] - acs_s[s]) : 0.f;
                S0[l * LDW + s] = f2b(v);
            }
        }
    __syncthreads();
    f32x4 yacc[2][4] = {};
    for (int kk = 0; kk < 4; ++kk) {
        bf16x8 af[2], bfr[4];
        #pragma unroll
        for (int i = 0; i < 2; ++i)
            af[i] = *(const bf16x8*)(S0 + (w * 32 + i * 16 + (lane & 15)) * LDW
                                     + kk * 32 + (lane >> 4) * 8);
        #pragma unroll
        for (int j = 0; j < 4; ++j)
            bfr[j] = *(const bf16x8*)(Xt + (j * 16 + (lane & 15)) * LDW
                                      + kk * 32 + (lane >> 4) * 8);
        #pragma unroll
        for (int i = 0; i < 2; ++i)
            #pragma unroll
            for (int j = 0; j < 4; ++j)
                yacc[i][j] = __builtin_amdgcn_mfma_f32_16x16x32_bf16(af[i], bfr[j], yacc[i][j], 0, 0, 0);
    }
    #pragma unroll
    for (int i = 0; i < 2; ++i)
        #pragma unroll
        for (int j = 0; j < 4; ++j)
            #pragma unroll
            for (int r = 0; r < 4; ++r) {
                int l = w * 32 + i * 16 + (lane >> 4) * 4 + r;
                int p = j * 16 + (lane & 15);
                y[(size_t)(row0 + l) * DINNER + h * HD + p] = f2b(yacc[i][j][r]);
            }
    __syncthreads();
    for (int i = tid; i < 128 * 32; i += 256) {
        int l = i >> 5, ng = (i & 31) * 4;
        ushort4 v = *(const ushort4*)(xbcb + (size_t)(row0 + l) * CONVCH + DINNER + ng);
        float d = dec_s[l];
        S0[(ng + 0) * LDW + l] = f2b(b2f(v.x) * d);
        S0[(ng + 1) * LDW + l] = f2b(b2f(v.y) * d);
        S0[(ng + 2) * LDW + l] = f2b(b2f(v.z) * d);
        S0[(ng + 3) * LDW + l] = f2b(b2f(v.w) * d);
    }
    __syncthreads();
    f32x4 tacc[8] = {};
    for (int kk = 0; kk < 4; ++kk) {
        bf16x8 afs = *(const bf16x8*)(Xt + (w * 16 + (lane & 15)) * LDW
                                      + kk * 32 + (lane >> 4) * 8);
        #pragma unroll
        for (int j = 0; j < 8; ++j) {
            bf16x8 bfs = *(const bf16x8*)(S0 + (j * 16 + (lane & 15)) * LDW
                                          + kk * 32 + (lane >> 4) * 8);
            tacc[j] = __builtin_amdgcn_mfma_f32_16x16x32_bf16(afs, bfs, tacc[j], 0, 0, 0);
        }
    }
    size_t sb = (size_t)blockIdx.x * (HD * DSTATE);
    #pragma unroll
    for (int j = 0; j < 8; ++j)
        #pragma unroll
        for (int r = 0; r < 4; ++r) {
            int p = w * 16 + (lane >> 4) * 4 + r;
            int n = j * 16 + (lane & 15);
            st[sb + (size_t)p * DSTATE + n] = f2b(tacc[j][r]);
        }
}

// ---------------- inter-chunk scan (in place, bf16), both dirs ----------------
__global__ void k_scan(u16* __restrict__ st0, const float* __restrict__ cd0)
{
    int i = blockIdx.x * blockDim.x + threadIdx.x;
    if (i >= 2 * BATCH * NH * HD * DSTATE) return;
    int dir = i >> 19;                  // BATCH*NH*HD*DSTATE == 1<<19
    int j = i & ((1 << 19) - 1);
    u16* st = st0 + (size_t)dir * N_ST;
    const float* cd = cd0 + (size_t)dir * BATCH * NH * NCH;
    int n = j & 127;
    int rest = j >> 7;
    int p = rest & 63; rest >>= 6;
    int h = rest & 31;
    int b = rest >> 5;
    float s = 0.f;
    for (int c = 0; c < NCH; ++c) {
        size_t idx = ((size_t)((b * NCH + c) * NH + h) * HD + p) * DSTATE + n;
        float v = b2f(st[idx]);
        st[idx] = f2b(s);                              // prev_c
        s = s * cd[(b * NH + h) * NCH + c] + v;        // carry (fp32)
    }
}

// ---------------- Y_off: y += exp(acs[l]) * C@prev^T + xh*D; z = dir ----------------
__global__ __launch_bounds__(256) void k_yoff(
    const u16* __restrict__ xbcb0, const u16* __restrict__ prev0,
    const float* __restrict__ acs0,
    const float* __restrict__ D_f, const float* __restrict__ D_b,
    u16* __restrict__ y0)
{
    int dir = blockIdx.z;
    const u16* xbcb = xbcb0 + (size_t)dir * T * CONVCH;
    const u16* prev = prev0 + (size_t)dir * N_ST;
    const float* acs = acs0 + (size_t)dir * BATCH * NH * NCH * CHUNK;
    const float* Dp = dir ? D_b : D_f;
    u16* y = y0 + (size_t)dir * T * DINNER;

    __shared__ u16 Pv[64 * LDW];
    __shared__ float acs_s[128];
    int tid = threadIdx.x, lane = tid & 63, w = tid >> 6;
    int h = blockIdx.x & 31;
    int bc = blockIdx.x >> 5;
    int c = bc & 15, b = bc >> 4;
    int row0 = b * SEQL + c * CHUNK;
    size_t sb = (size_t)blockIdx.x * (HD * DSTATE);
    for (int i = tid; i < 64 * 16; i += 256) {
        int p = i >> 4, m8 = (i & 15) * 8;
        *(uint4*)(Pv + p * LDW + m8) = *(const uint4*)(prev + sb + (size_t)p * DSTATE + m8);
    }
    if (tid < 128) acs_s[tid] = acs[(((size_t)(b * NH + h) * NCH + c) << 7) + tid];
    __syncthreads();
    const u16* cbase = xbcb + (size_t)row0 * CONVCH + DINNER + DSTATE;
    f32x4 acc[2][4] = {};
    for (int kk = 0; kk < 4; ++kk) {
        bf16x8 af[2], bfr[4];
        #pragma unroll
        for (int i = 0; i < 2; ++i)
            af[i] = *(const bf16x8*)(cbase + (size_t)(w * 32 + i * 16 + (lane & 15)) * CONVCH
                                     + kk * 32 + (lane >> 4) * 8);
        #pragma unroll
        for (int j = 0; j < 4; ++j)
            bfr[j] = *(const bf16x8*)(Pv + (j * 16 + (lane & 15)) * LDW
                                      + kk * 32 + (lane >> 4) * 8);
        #pragma unroll
        for (int i = 0; i < 2; ++i)
            #pragma unroll
            for (int j = 0; j < 4; ++j)
                acc[i][j] = __builtin_amdgcn_mfma_f32_16x16x32_bf16(af[i], bfr[j], acc[i][j], 0, 0, 0);
    }
    float Dh = Dp[h];
    #pragma unroll
    for (int i = 0; i < 2; ++i)
        #pragma unroll
        for (int j = 0; j < 4; ++j)
            #pragma unroll
            for (int r = 0; r < 4; ++r) {
                int l = w * 32 + i * 16 + (lane >> 4) * 4 + r;
                int p = j * 16 + (lane & 15);
                size_t yi = (size_t)(row0 + l) * DINNER + h * HD + p;
                float val = b2f(y[yi]) + __expf(acs_s[l]) * acc[i][j][r]
                          + b2f(xbcb[(size_t)(row0 + l) * CONVCH + h * HD + p]) * Dh;
                y[yi] = f2b(val);
            }
}

// ---------------- gated rmsnorm -> bf16; z = dir ----------------
__global__ __launch_bounds__(256) void k_gate(
    const u16* __restrict__ y0, const u16* __restrict__ zb0,
    const float* __restrict__ gw_f, const float* __restrict__ gw_b,
    u16* __restrict__ out0)
{
    int dir = blockIdx.z;
    const u16* y = y0 + (size_t)dir * T * DINNER;
    const u16* zb = zb0 + (size_t)dir * T * DINNER;
    const float* gw = dir ? gw_b : gw_f;
    u16* out = out0 + (size_t)dir * T * DINNER;

    int r = blockIdx.x;
    __shared__ float tbuf[DINNER];
    int tid = threadIdx.x;
    float ss = 0.f;
    #pragma unroll
    for (int it = 0; it < 2; ++it) {
        int i = (it * 256 + tid) * 4;
        ushort4 yv = *(const ushort4*)(y + (size_t)r * DINNER + i);
        ushort4 zv = *(const ushort4*)(zb + (size_t)r * DINNER + i);
        float z0 = b2f(zv.x), z1 = b2f(zv.y), z2 = b2f(zv.z), z3 = b2f(zv.w);
        float t0 = b2f(yv.x) * (z0 / (1.f + __expf(-z0)));
        float t1 = b2f(yv.y) * (z1 / (1.f + __expf(-z1)));
        float t2 = b2f(yv.z) * (z2 / (1.f + __expf(-z2)));
        float t3 = b2f(yv.w) * (z3 / (1.f + __expf(-z3)));
        tbuf[i] = t0; tbuf[i + 1] = t1; tbuf[i + 2] = t2; tbuf[i + 3] = t3;
        ss += t0 * t0 + t1 * t1 + t2 * t2 + t3 * t3;
    }
    float tot = blockReduceSum(ss);
    float sc = rsqrtf(tot / DINNER + EPS);
    #pragma unroll
    for (int it = 0; it < 2; ++it) {
        int i = (it * 256 + tid) * 4;
        ushort4 o;
        o.x = f2b(tbuf[i] * sc * gw[i]);
        o.y = f2b(tbuf[i + 1] * sc * gw[i + 1]);
        o.z = f2b(tbuf[i + 2] * sc * gw[i + 2]);
        o.w = f2b(tbuf[i + 3] * sc * gw[i + 3]);
        *(ushort4*)(out + (size_t)r * DINNER + i) = o;
    }
}

// ---------------- launch ----------------
extern "C" void kernel_launch(void* const* d_in, const int* in_sizes, int n_in,
                              void* d_out, int out_size, void* d_ws, size_t ws_size,
                              hipStream_t stream)
{
    const float* x         = (const float*)d_in[0];
    const float* norm_w    = (const float*)d_in[1];
    const float* out_w_blk = (const float*)d_in[2];
    const float* out_b_blk = (const float*)d_in[3];
    const float* f_in_w    = (const float*)d_in[4];
    const float* f_conv_w  = (const float*)d_in[5];
    const float* f_conv_b  = (const float*)d_in[6];
    const float* f_dt_bias = (const float*)d_in[7];
    const float* f_A_log   = (const float*)d_in[8];
    const float* f_D       = (const float*)d_in[9];
    const float* f_gnorm_w = (const float*)d_in[10];
    const float* f_out_w   = (const float*)d_in[11];
    const float* b_in_w    = (const float*)d_in[12];
    const float* b_conv_w  = (const float*)d_in[13];
    const float* b_conv_b  = (const float*)d_in[14];
    const float* b_dt_bias = (const float*)d_in[15];
    const float* b_A_log   = (const float*)d_in[16];
    const float* b_D       = (const float*)d_in[17];
    const float* b_gnorm_w = (const float*)d_in[18];
    const float* b_out_w   = (const float*)d_in[19];
    float* out = (float*)d_out;

    // ---- workspace layout with liveness overlap (total ~207 MB) ----
    char* ws = (char*)d_ws;
    u16*  xnb    = (u16*)ws;   ws += (size_t)T * DMODEL * 2;          // 8.4 MB
    u16*  zb     = (u16*)ws;   ws += (size_t)2 * T * DINNER * 2;      // 33.6 MB (z, live->gate)
    u16*  xbcraw = (u16*)ws;   ws += (size_t)2 * T * CONVCH * 2;      // 37.7 MB (dead after conv)
    u16*  xbcb   = (u16*)ws;   ws += (size_t)2 * T * CONVCH * 2;      // 37.7 MB (dead after yoff)
    u16*  xdtb   = (u16*)ws;   ws += (size_t)2 * T * DINNER * 2;      // 33.6 MB (dead after chunk)
    float* dtb   = (float*)ws; ws += (size_t)2 * T * NH * 4;          // 1 MB
    float* acs   = (float*)ws; ws += (size_t)2 * BATCH * NH * NCH * CHUNK * 4;  // 1 MB
    float* cd    = (float*)ws; ws += (size_t)2 * BATCH * NH * NCH * 4;          // 8 KB
    u16*  stb    = (u16*)ws;   ws += (size_t)2 * N_ST * 2;            // 33.6 MB (bf16)
    u16*  inwb   = (u16*)ws;   ws += (size_t)2 * N_INW * 2;           // 17.8 MB
    u16*  outwb  = (u16*)ws;   ws += (size_t)2 * N_OUTW * 2;          // 8.4 MB
    u16*  owbb   = (u16*)ws;   ws += (size_t)N_OUTW * 2;              // 4.2 MB
    // aliases (liveness-safe reuse)
    u16*  yb16 = xbcraw;   // Y (bf16, 2*T*DINNER <= 2*T*CONVCH), written by k_chunk
    u16*  ybb  = xdtb;     // gated-norm output, written by k_gate
    u16*  catb = xbcb;     // concat buffer (T*2*DMODEL <= 2*T*CONVCH), written by out-proj

    k_rmsnorm<<<T, 256, 0, stream>>>(x, norm_w, xnb);
    {
        size_t tot = 2 * N_INW + 3 * N_OUTW;
        int blocks = (int)((tot / 4 + 255) / 256);
        k_f2b_all<<<blocks, 256, 0, stream>>>(f_in_w, b_in_w, f_out_w, b_out_w,
                                              out_w_blk, inwb, outwb, owbb);
    }

    // in-proj both dirs: z -> zb, xBC -> xbcraw
    {
        dim3 g(DPROJ2 / 128, T / 128, 2);
        k_mm_in<<<g, 256, 0, stream>>>(xnb, inwb, zb, xbcraw);
    }
    {
        dim3 g(T / 4, 1, 2);
        k_dt2<<<g, 256, 0, stream>>>(xnb, f_in_w, b_in_w, f_dt_bias, b_dt_bias, dtb);
    }
    {
        dim3 g((T * (CONVCH / 8) + 255) / 256, 1, 2);
        k_conv<<<g, 256, 0, stream>>>(xbcraw, f_conv_w, b_conv_w, f_conv_b, b_conv_b,
                                      dtb, xbcb, xdtb);
    }
    {
        dim3 g(BATCH * NH * NCH, 1, 2);
        k_acs<<<g, 128, 0, stream>>>(dtb, f_A_log, b_A_log, acs, cd);
    }
    {
        dim3 g(BATCH * NCH * NH, 1, 2);
        k_chunk<<<g, 256, 0, stream>>>(xbcb, xdtb, acs, yb16, stb);
    }
    k_scan<<<(2 * BATCH * NH * HD * DSTATE) / 256, 256, 0, stream>>>(stb, cd);
    {
        dim3 g(BATCH * NCH * NH, 1, 2);
        k_yoff<<<g, 256, 0, stream>>>(xbcb, stb, acs, f_D, b_D, yb16);
    }
    {
        dim3 g(T, 1, 2);
        k_gate<<<g, 256, 0, stream>>>(yb16, zb, f_gnorm_w, b_gnorm_w, ybb);
    }
    // out-proj both dirs -> catb (bf16), bwd rows un-flipped at A-read
    {
        dim3 g(DMODEL / 64, T / 64, 2);
        k_mm64<<<g, 256, 0, stream>>>(ybb, (size_t)T * DINNER,
                                      outwb, N_OUTW, DINNER,
                                      catb, nullptr, 2 * DMODEL, DMODEL, 1,
                                      nullptr, nullptr, 0);
    }
    // final: out = cat @ out_w_blk^T + bias + x
    {
        dim3 g(DMODEL / 64, T / 64, 1);
        k_mm64<<<g, 256, 0, stream>>>(catb, 0,
                                      owbb, 0, DINNER,
                                      nullptr, out, DMODEL, 0, 0,
                                      out_b_blk, x, DMODEL);
    }
}

// Round 8
// 601.614 us; speedup vs baseline: 7.5067x; 1.0712x over previous
//
#include <hip/hip_runtime.h>
#include <hip/hip_bf16.h>
#include <math.h>

#define BATCH 2
#define SEQL 2048
#define T 4096            // BATCH*SEQL tokens
#define DMODEL 1024
#define DINNER 2048
#define DSTATE 128
#define NH 32
#define HD 64
#define DPROJ2 4352       // z (2048) + xBC (2304); dt handled separately in fp32
#define CONVCH 2304
#define NCH 16            // chunks per sequence
#define CHUNK 128
#define EPS 1e-5f

#define N_INW ((size_t)DPROJ2 * DMODEL)   // 4,456,448
#define N_OUTW ((size_t)DMODEL * DINNER)  // 2,097,152
#define N_ST ((size_t)BATCH * NCH * NH * HD * DSTATE)  // 8,388,608 per dir

typedef unsigned short u16;
typedef __bf16 bf16x8 __attribute__((ext_vector_type(8)));
typedef float f32x4 __attribute__((ext_vector_type(4)));

__device__ __forceinline__ u16 f2b(float f) {
    union { float f; unsigned u; } v; v.f = f;
    unsigned r = v.u + 0x7fffu + ((v.u >> 16) & 1u);
    return (u16)(r >> 16);
}
__device__ __forceinline__ float b2f(u16 b) {
    union { unsigned u; float f; } v; v.u = ((unsigned)b) << 16;
    return v.f;
}
__device__ __forceinline__ int flipseq(int r) {
    return (r & ~(SEQL - 1)) | ((SEQL - 1) - (r & (SEQL - 1)));
}
__device__ __forceinline__ void gload16(const u16* g, u16* l) {
    __builtin_amdgcn_global_load_lds(
        (const __attribute__((address_space(1))) void*)g,
        (__attribute__((address_space(3))) void*)l, 16, 0, 0);
}

// ---------------- block reduce ----------------
__device__ __forceinline__ float blockReduceSum(float v) {
    __shared__ float red_[4];
    for (int off = 32; off > 0; off >>= 1) v += __shfl_down(v, off);
    int lane = threadIdx.x & 63, wid = threadIdx.x >> 6;
    if (lane == 0) red_[wid] = v;
    __syncthreads();
    if (threadIdx.x == 0) {
        float s = 0.f;
        int nw = blockDim.x >> 6;
        for (int i = 0; i < nw; ++i) s += red_[i];
        red_[0] = s;
    }
    __syncthreads();
    return red_[0];
}

// ---------------- input rmsnorm -> bf16 ----------------
__global__ __launch_bounds__(256) void k_rmsnorm(
    const float* __restrict__ x, const float* __restrict__ w,
    u16* __restrict__ outb)
{
    int row = blockIdx.x;
    const float* xr = x + (size_t)row * DMODEL;
    float ss = 0.f;
    for (int i = threadIdx.x; i < DMODEL; i += 256) { float v = xr[i]; ss += v * v; }
    float tot = blockReduceSum(ss);
    float sc = rsqrtf(tot / DMODEL + EPS);
    for (int i = threadIdx.x; i < DMODEL; i += 256)
        outb[(size_t)row * DMODEL + i] = f2b(xr[i] * sc * w[i]);
}

// ---------------- weights fp32 -> bf16 (in_w x2, out_w_blk) ----------------
__global__ void k_f2b_all(
    const float* __restrict__ s0, const float* __restrict__ s1,  // f_in_w, b_in_w
    const float* __restrict__ s4,                                // out_w_blk
    u16* __restrict__ d_inwb, u16* __restrict__ d_owbb)
{
    size_t i = ((size_t)blockIdx.x * 256 + threadIdx.x) * 4;
    const float* s; u16* d; size_t off;
    if (i < 2 * N_INW) {
        int dir = i >= N_INW;
        off = i - (size_t)dir * N_INW;
        s = dir ? s1 : s0; d = d_inwb + (size_t)dir * N_INW;
    } else {
        off = i - 2 * N_INW;
        if (off >= N_OUTW) return;
        s = s4; d = d_owbb;
    }
    float4 v = *(const float4*)(s + off);
    ushort4 o;
    o.x = f2b(v.x); o.y = f2b(v.y); o.z = f2b(v.z); o.w = f2b(v.w);
    *(ushort4*)(d + off) = o;
}

// ---------------- out_w (1024 x 2048) -> transposed bf16 (2048 x 1024); z = dir ----------------
__global__ __launch_bounds__(256) void k_tw(
    const float* __restrict__ fw, const float* __restrict__ bw, u16* __restrict__ dst)
{
    int dir = blockIdx.z;
    const float* src = dir ? bw : fw;
    u16* d = dst + (size_t)dir * N_OUTW;
    __shared__ u16 t[64][65];
    int e0 = blockIdx.y * 64, c0 = blockIdx.x * 64;
    for (int i = threadIdx.x; i < 64 * 16; i += 256) {
        int el = i >> 4, c4 = (i & 15) * 4;
        float4 v = *(const float4*)(src + (size_t)(e0 + el) * DINNER + c0 + c4);
        t[c4 + 0][el] = f2b(v.x); t[c4 + 1][el] = f2b(v.y);
        t[c4 + 2][el] = f2b(v.z); t[c4 + 3][el] = f2b(v.w);
    }
    __syncthreads();
    for (int i = threadIdx.x; i < 64 * 16; i += 256) {
        int cl = i >> 4, e4 = (i & 15) * 4;
        ushort4 o;
        o.x = t[cl][e4]; o.y = t[cl][e4 + 1]; o.z = t[cl][e4 + 2]; o.w = t[cl][e4 + 3];
        *(ushort4*)(d + (size_t)(c0 + cl) * DMODEL + e0 + e4) = o;
    }
}

// ---------------- in-proj: bf16 MFMA GEMM 128x128, BK=64 (two BK=32 panels), z = dir ----------------
// Two-panel LDS keeps the verified stride-32 fragment layout (no new bank conflicts)
// while halving barrier-drain count (32 -> 16 K-iterations).
__global__ __launch_bounds__(256, 4) void k_mm_in(
    const u16* __restrict__ A, const u16* __restrict__ W0,
    u16* __restrict__ zb0, u16* __restrict__ xbcraw0)
{
    const int K = DMODEL;
    int dir = blockIdx.z;
    const u16* W = W0 + (size_t)dir * N_INW;
    int m0 = blockIdx.y * 128, n0 = blockIdx.x * 128;

    // block-uniform output select
    u16* Cout;
    int ldcc, nbase;
    if (n0 < DINNER) {
        Cout = zb0 + (size_t)dir * T * DINNER;
        ldcc = DINNER;
        nbase = n0;
    } else {
        Cout = xbcraw0 + (size_t)dir * T * CONVCH;
        ldcc = CONVCH;
        nbase = n0 - DINNER;
    }

    __shared__ u16 As[2 * 128 * 32];   // panel0: k 0-31, panel1: k 32-63
    __shared__ u16 Bs[2 * 128 * 32];
    int tid = threadIdx.x;
    int lane = tid & 63;
    int wrow = ((tid >> 6) & 1) * 64, wcol = (tid >> 7) * 64;

    int srow = tid >> 2, skof = (tid & 3) * 8;
    int ar1 = m0 + srow, ar2 = ar1 + 64;
    if (dir) { ar1 = flipseq(ar1); ar2 = flipseq(ar2); }
    const u16* ga1 = A + (size_t)ar1 * K + skof;
    const u16* ga2 = A + (size_t)ar2 * K + skof;
    const u16* gb1 = W + (size_t)(n0 + srow) * K + skof;
    const u16* gb2 = gb1 + (size_t)64 * K;
    u16* la1 = As + tid * 8;
    u16* la2 = As + 2048 + tid * 8;
    u16* lb1 = Bs + tid * 8;
    u16* lb2 = Bs + 2048 + tid * 8;

    int aoff[4], boff[4];
    #pragma unroll
    for (int i = 0; i < 4; ++i) {
        aoff[i] = (wrow + i * 16 + (lane & 15)) * 32 + ((lane >> 4) * 8);
        boff[i] = (wcol + i * 16 + (lane & 15)) * 32 + ((lane >> 4) * 8);
    }

    f32x4 acc[4][4] = {};
    for (int kt = 0; kt < K; kt += 64) {
        // panel 0 (k 0-31) and panel 1 (k 32-63)
        gload16(ga1, la1);        gload16(ga2, la2);
        gload16(ga1 + 32, la1 + 4096); gload16(ga2 + 32, la2 + 4096);
        gload16(gb1, lb1);        gload16(gb2, lb2);
        gload16(gb1 + 32, lb1 + 4096); gload16(gb2 + 32, lb2 + 4096);
        ga1 += 64; ga2 += 64; gb1 += 64; gb2 += 64;
        __syncthreads();
        #pragma unroll
        for (int ks = 0; ks < 2; ++ks) {
            bf16x8 af[4], bfv[4];
            #pragma unroll
            for (int i = 0; i < 4; ++i) af[i] = *(const bf16x8*)(As + ks * 4096 + aoff[i]);
            #pragma unroll
            for (int j = 0; j < 4; ++j) bfv[j] = *(const bf16x8*)(Bs + ks * 4096 + boff[j]);
            #pragma unroll
            for (int i = 0; i < 4; ++i)
                #pragma unroll
                for (int j = 0; j < 4; ++j)
                    acc[i][j] = __builtin_amdgcn_mfma_f32_16x16x32_bf16(af[i], bfv[j], acc[i][j], 0, 0, 0);
        }
        __syncthreads();
    }

    int rbase = m0 + wrow + ((lane >> 4) << 2);
    int cbase = nbase + wcol + (lane & 15);
    #pragma unroll
    for (int i = 0; i < 4; ++i)
        #pragma unroll
        for (int j = 0; j < 4; ++j)
            #pragma unroll
            for (int r = 0; r < 4; ++r)
                Cout[(size_t)(rbase + i * 16 + r) * ldcc + cbase + j * 16] = f2b(acc[i][j][r]);
}

// ---------------- bf16 MFMA GEMM, 64x64 tile, z-batched, lda-aware ----------------
__global__ __launch_bounds__(256) void k_mm64(
    const u16* __restrict__ A, size_t astride, int lda,
    const u16* __restrict__ W, size_t wstride, int K,
    u16* __restrict__ Cb, int ldc, int coffStride)
{
    int dir = blockIdx.z;
    A += (size_t)dir * astride;
    W += (size_t)dir * wstride;
    int coff = dir * coffStride;

    __shared__ u16 As[64 * 32];
    __shared__ u16 Bs[64 * 32];
    int tid = threadIdx.x;
    int lane = tid & 63;
    int w = tid >> 6;
    int m0 = blockIdx.y * 64, n0 = blockIdx.x * 64;
    int wrow = (w & 1) * 32, wcol = (w >> 1) * 32;

    int srow = tid >> 2, skof = (tid & 3) * 8;
    const u16* ga = A + (size_t)(m0 + srow) * lda + skof;
    const u16* gb = W + (size_t)(n0 + srow) * K + skof;
    u16* la = As + tid * 8;
    u16* lb = Bs + tid * 8;

    int aoff[2], boff[2];
    #pragma unroll
    for (int i = 0; i < 2; ++i) {
        aoff[i] = (wrow + i * 16 + (lane & 15)) * 32 + ((lane >> 4) * 8);
        boff[i] = (wcol + i * 16 + (lane & 15)) * 32 + ((lane >> 4) * 8);
    }

    f32x4 acc[2][2] = {};
    for (int kt = 0; kt < K; kt += 32) {
        gload16(ga, la);
        gload16(gb, lb);
        ga += 32; gb += 32;
        __syncthreads();
        bf16x8 af[2], bfv[2];
        #pragma unroll
        for (int i = 0; i < 2; ++i) af[i] = *(const bf16x8*)(As + aoff[i]);
        #pragma unroll
        for (int j = 0; j < 2; ++j) bfv[j] = *(const bf16x8*)(Bs + boff[j]);
        #pragma unroll
        for (int i = 0; i < 2; ++i)
            #pragma unroll
            for (int j = 0; j < 2; ++j)
                acc[i][j] = __builtin_amdgcn_mfma_f32_16x16x32_bf16(af[i], bfv[j], acc[i][j], 0, 0, 0);
        __syncthreads();
    }

    int rbase = m0 + wrow + ((lane >> 4) << 2);
    int cbase = n0 + wcol + (lane & 15);
    #pragma unroll
    for (int i = 0; i < 2; ++i)
        #pragma unroll
        for (int j = 0; j < 2; ++j)
            #pragma unroll
            for (int r = 0; r < 4; ++r)
                Cb[(size_t)(rbase + i * 16 + r) * ldc + coff + cbase + j * 16] = f2b(acc[i][j][r]);
}

// ---------------- final fused GEMM: out = ybb_f@Mf^T + flip(ybb_b)@Mb^T + bias + x ----------------
__global__ __launch_bounds__(256) void k_mm_fin(
    const u16* __restrict__ A1, const u16* __restrict__ A2,
    const u16* __restrict__ W,      // Mcomb: 1024 x 4096 (Mf | Mb), k-contig
    float* __restrict__ out, const float* __restrict__ bias,
    const float* __restrict__ resid)
{
    __shared__ u16 As[64 * 32];
    __shared__ u16 Bs[64 * 32];
    int tid = threadIdx.x;
    int lane = tid & 63;
    int w = tid >> 6;
    int m0 = blockIdx.y * 64, n0 = blockIdx.x * 64;
    int wrow = (w & 1) * 32, wcol = (w >> 1) * 32;

    int srow = tid >> 2, skof = (tid & 3) * 8;
    const u16* ga1 = A1 + (size_t)(m0 + srow) * DINNER + skof;
    const u16* ga2 = A2 + (size_t)flipseq(m0 + srow) * DINNER + skof;
    const u16* gb = W + (size_t)(n0 + srow) * 4096 + skof;
    u16* la = As + tid * 8;
    u16* lb = Bs + tid * 8;

    int aoff[2], boff[2];
    #pragma unroll
    for (int i = 0; i < 2; ++i) {
        aoff[i] = (wrow + i * 16 + (lane & 15)) * 32 + ((lane >> 4) * 8);
        boff[i] = (wcol + i * 16 + (lane & 15)) * 32 + ((lane >> 4) * 8);
    }

    f32x4 acc[2][2] = {};
    #pragma unroll
    for (int half = 0; half < 2; ++half) {
        const u16* ga = half ? ga2 : ga1;
        for (int kt = 0; kt < DINNER; kt += 32) {
            gload16(ga, la);
            gload16(gb, lb);
            ga += 32; gb += 32;
            __syncthreads();
            bf16x8 af[2], bfv[2];
            #pragma unroll
            for (int i = 0; i < 2; ++i) af[i] = *(const bf16x8*)(As + aoff[i]);
            #pragma unroll
            for (int j = 0; j < 2; ++j) bfv[j] = *(const bf16x8*)(Bs + boff[j]);
            #pragma unroll
            for (int i = 0; i < 2; ++i)
                #pragma unroll
                for (int j = 0; j < 2; ++j)
                    acc[i][j] = __builtin_amdgcn_mfma_f32_16x16x32_bf16(af[i], bfv[j], acc[i][j], 0, 0, 0);
            __syncthreads();
        }
    }

    int rbase = m0 + wrow + ((lane >> 4) << 2);
    int cbase = n0 + wcol + (lane & 15);
    #pragma unroll
    for (int i = 0; i < 2; ++i)
        #pragma unroll
        for (int j = 0; j < 2; ++j)
            #pragma unroll
            for (int r = 0; r < 4; ++r) {
                int row = rbase + i * 16 + r, col = cbase + j * 16;
                out[(size_t)row * DMODEL + col] =
                    acc[i][j][r] + bias[col] + resid[(size_t)row * DMODEL + col];
            }
}

// ---------------- dt = softplus(xn . w_dt + bias), 4 rows/block, z = dir ----------------
__global__ __launch_bounds__(256) void k_dt2(
    const u16* __restrict__ xnb,
    const float* __restrict__ inw_f, const float* __restrict__ inw_b,
    const float* __restrict__ dtb_f, const float* __restrict__ dtb_b,
    float* __restrict__ dt)
{
    int dir = blockIdx.z;
    const float* wbase = dir ? inw_b : inw_f;
    const float* dtbia = dir ? dtb_b : dtb_f;
    float* dtp = dt + (size_t)dir * T * NH;

    int r0 = blockIdx.x * 4;
    __shared__ float xs[4][1024];
    int tid = threadIdx.x;
    #pragma unroll
    for (int rr = 0; rr < 4; ++rr) {
        int src = dir ? flipseq(r0 + rr) : (r0 + rr);
        ushort4 v = *(const ushort4*)(xnb + (size_t)src * DMODEL + tid * 4);
        xs[rr][tid * 4 + 0] = b2f(v.x); xs[rr][tid * 4 + 1] = b2f(v.y);
        xs[rr][tid * 4 + 2] = b2f(v.z); xs[rr][tid * 4 + 3] = b2f(v.w);
    }
    __syncthreads();
    int h = tid >> 3, part = tid & 7;
    const float* w = wbase + (size_t)(DPROJ2 + h) * DMODEL;
    float a0 = 0.f, a1 = 0.f, a2 = 0.f, a3 = 0.f;
    for (int kk = 0; kk < 128; ++kk) {
        int k = part + (kk << 3);
        float wv = w[k];
        a0 += xs[0][k] * wv; a1 += xs[1][k] * wv;
        a2 += xs[2][k] * wv; a3 += xs[3][k] * wv;
    }
    #pragma unroll
    for (int off = 4; off > 0; off >>= 1) {
        a0 += __shfl_down(a0, off, 8); a1 += __shfl_down(a1, off, 8);
        a2 += __shfl_down(a2, off, 8); a3 += __shfl_down(a3, off, 8);
    }
    if (part == 0) {
        float bsh = dtbia[h];
        float vv[4] = {a0, a1, a2, a3};
        #pragma unroll
        for (int rr = 0; rr < 4; ++rr) {
            float v = vv[rr] + bsh;
            dtp[(size_t)(r0 + rr) * NH + h] = (v > 20.f) ? v : log1pf(expf(v));
        }
    }
}

// ---------------- conv4 + silu -> bf16 xbcb; x-part * dt -> xdtb; z = dir ----------------
__global__ void k_conv(const u16* __restrict__ xraw0,
                       const float* __restrict__ cw_f, const float* __restrict__ cw_b,
                       const float* __restrict__ cb_f, const float* __restrict__ cb_b,
                       const float* __restrict__ dt0,
                       u16* __restrict__ xbcb0, u16* __restrict__ xdtb0)
{
    int dir = blockIdx.z;
    const u16* xraw = xraw0 + (size_t)dir * T * CONVCH;
    const float* cw = dir ? cw_b : cw_f;
    const float* cb = dir ? cb_b : cb_f;
    const float* dt = dt0 + (size_t)dir * T * NH;
    u16* xbcb = xbcb0 + (size_t)dir * T * CONVCH;
    u16* xdtb = xdtb0 + (size_t)dir * T * DINNER;

    int idx = blockIdx.x * blockDim.x + threadIdx.x;
    if (idx >= T * (CONVCH / 8)) return;
    int r = idx / (CONVCH / 8);
    int c8 = (idx - r * (CONVCH / 8)) * 8;
    int t = r & (SEQL - 1);
    int b0 = r - t;
    float4 cwv[8];
    #pragma unroll
    for (int j = 0; j < 8; ++j) cwv[j] = *(const float4*)(cw + (size_t)(c8 + j) * 4);
    float acc[8];
    {
        float4 c0 = *(const float4*)(cb + c8);
        float4 c1 = *(const float4*)(cb + c8 + 4);
        acc[0] = c0.x; acc[1] = c0.y; acc[2] = c0.z; acc[3] = c0.w;
        acc[4] = c1.x; acc[5] = c1.y; acc[6] = c1.z; acc[7] = c1.w;
    }
    #pragma unroll
    for (int k = 0; k < 4; ++k) {
        int tt = t + k - 3;
        if (tt < 0) continue;
        const u16* src = xraw + (size_t)(b0 + tt) * CONVCH + c8;
        ushort4 v0 = *(const ushort4*)src;
        ushort4 v1 = *(const ushort4*)(src + 4);
        float xv[8] = {b2f(v0.x), b2f(v0.y), b2f(v0.z), b2f(v0.w),
                       b2f(v1.x), b2f(v1.y), b2f(v1.z), b2f(v1.w)};
        #pragma unroll
        for (int j = 0; j < 8; ++j) {
            float wv = (k == 0) ? cwv[j].x : (k == 1) ? cwv[j].y : (k == 2) ? cwv[j].z : cwv[j].w;
            acc[j] += xv[j] * wv;
        }
    }
    ushort4 o0, o1;
    float s[8];
    #pragma unroll
    for (int j = 0; j < 8; ++j) s[j] = acc[j] / (1.f + __expf(-acc[j]));
    o0.x = f2b(s[0]); o0.y = f2b(s[1]); o0.z = f2b(s[2]); o0.w = f2b(s[3]);
    o1.x = f2b(s[4]); o1.y = f2b(s[5]); o1.z = f2b(s[6]); o1.w = f2b(s[7]);
    *(ushort4*)(xbcb + (size_t)r * CONVCH + c8) = o0;
    *(ushort4*)(xbcb + (size_t)r * CONVCH + c8 + 4) = o1;
    if (c8 < DINNER) {
        float dv = dt[(size_t)r * NH + (c8 >> 6)];
        ushort4 d0, d1;
        d0.x = f2b(s[0] * dv); d0.y = f2b(s[1] * dv); d0.z = f2b(s[2] * dv); d0.w = f2b(s[3] * dv);
        d1.x = f2b(s[4] * dv); d1.y = f2b(s[5] * dv); d1.z = f2b(s[6] * dv); d1.w = f2b(s[7] * dv);
        *(ushort4*)(xdtb + (size_t)r * DINNER + c8) = d0;
        *(ushort4*)(xdtb + (size_t)r * DINNER + c8 + 4) = d1;
    }
}

// ---------------- per-chunk cumsum of A*dt; z = dir ----------------
__global__ void k_acs(const float* __restrict__ dt0,
                      const float* __restrict__ Alog_f, const float* __restrict__ Alog_b,
                      float* __restrict__ acs0, float* __restrict__ cd0)
{
    int dir = blockIdx.z;
    const float* dt = dt0 + (size_t)dir * T * NH;
    const float* A_log = dir ? Alog_b : Alog_f;
    float* acs = acs0 + (size_t)dir * BATCH * NH * NCH * CHUNK;
    float* cd = cd0 + (size_t)dir * BATCH * NH * NCH;

    int bid = blockIdx.x;            // (b*NH + h)*NCH + c
    int c = bid & 15;
    int bh = bid >> 4;
    int h = bh & 31;
    int b = bh >> 5;
    int l = threadIdx.x;
    __shared__ float s[128];
    float Ah = -expf(A_log[h]);
    int r = b * SEQL + c * CHUNK + l;
    s[l] = Ah * dt[(size_t)r * NH + h];
    __syncthreads();
    for (int off = 1; off < 128; off <<= 1) {
        float t = (l >= off) ? s[l - off] : 0.f;
        __syncthreads();
        s[l] += t;
        __syncthreads();
    }
    acs[(size_t)bid * 128 + l] = s[l];
    if (l == 127) cd[bid] = expf(s[127]);
}

// ---------------- per-(b,c,h): MFMA Y_diag + chunk states; z = dir ----------------
#define LDW 136
__global__ __launch_bounds__(256) void k_chunk(
    const u16* __restrict__ xbcb0, const u16* __restrict__ xdtb0,
    const float* __restrict__ acs0, u16* __restrict__ y0, u16* __restrict__ st0)
{
    int dir = blockIdx.z;
    const u16* xbcb = xbcb0 + (size_t)dir * T * CONVCH;
    const u16* xdtb = xdtb0 + (size_t)dir * T * DINNER;
    const float* acs = acs0 + (size_t)dir * BATCH * NH * NCH * CHUNK;
    u16* y = y0 + (size_t)dir * T * DINNER;
    u16* st = st0 + (size_t)dir * N_ST;

    __shared__ u16 S0[128 * LDW];   // Bs -> Ps -> Bt(dec-folded)
    __shared__ u16 Xt[64 * LDW];    // Xt[p][l] = X[l][p]*dt[l]
    __shared__ float acs_s[128];
    __shared__ float dec_s[128];
    int tid = threadIdx.x;
    int lane = tid & 63;
    int w = tid >> 6;
    int h = blockIdx.x & 31;
    int bc = blockIdx.x >> 5;
    int c = bc & 15, b = bc >> 4;
    int row0 = b * SEQL + c * CHUNK;

    if (tid < 128) {
        float a = acs[(((size_t)(b * NH + h) * NCH + c) << 7) + tid];
        acs_s[tid] = a;
    }
    for (int i = tid; i < 128 * 16; i += 256) {
        int s = i >> 4, m8 = (i & 15) * 8;
        *(uint4*)(S0 + s * LDW + m8) =
            *(const uint4*)(xbcb + (size_t)(row0 + s) * CONVCH + DINNER + m8);
    }
    for (int i = tid; i < 128 * 16; i += 256) {
        int l = i >> 4, pg = (i & 15) * 4;
        ushort4 v = *(const ushort4*)(xdtb + (size_t)(row0 + l) * DINNER + h * HD + pg);
        Xt[(pg + 0) * LDW + l] = v.x; Xt[(pg + 1) * LDW + l] = v.y;
        Xt[(pg + 2) * LDW + l] = v.z; Xt[(pg + 3) * LDW + l] = v.w;
    }
    __syncthreads();
    float a_last = acs_s[127];
    if (tid < 128) dec_s[tid] = __expf(a_last - acs_s[tid]);

    int wrow = (w & 1) * 64, wcol = (w >> 1) * 64;
    const u16* cbase = xbcb + (size_t)row0 * CONVCH + DINNER + DSTATE;
    f32x4 sacc[4][4] = {};
    for (int kk = 0; kk < 4; ++kk) {
        bf16x8 af[4], bfr[4];
        #pragma unroll
        for (int i = 0; i < 4; ++i)
            af[i] = *(const bf16x8*)(cbase + (size_t)(wrow + i * 16 + (lane & 15)) * CONVCH
                                     + kk * 32 + (lane >> 4) * 8);
        #pragma unroll
        for (int j = 0; j < 4; ++j)
            bfr[j] = *(const bf16x8*)(S0 + (wcol + j * 16 + (lane & 15)) * LDW
                                      + kk * 32 + (lane >> 4) * 8);
        #pragma unroll
        for (int i = 0; i < 4; ++i)
            #pragma unroll
            for (int j = 0; j < 4; ++j)
                if (wcol + j * 16 <= wrow + i * 16 + 15)
                    sacc[i][j] = __builtin_amdgcn_mfma_f32_16x16x32_bf16(af[i], bfr[j], sacc[i][j], 0, 0, 0);
    }
    __syncthreads();
    #pragma unroll
    for (int i = 0; i < 4; ++i)
        #pragma unroll
        for (int j = 0; j < 4; ++j) {
            int s = wcol + j * 16 + (lane & 15);
            #pragma unroll
            for (int r = 0; r < 4; ++r) {
                int l = wrow + i * 16 + (lane >> 4) * 4 + r;
                float v = (s <= l) ? sacc[i][j][r] * __expf(acs_s[l] - acs_s[s]) : 0.f;
                S0[l * LDW + s] = f2b(v);
            }
        }
    __syncthreads();
    f32x4 yacc[2][4] = {};
    for (int kk = 0; kk < 4; ++kk) {
        bf16x8 af[2], bfr[4];
        #pragma unroll
        for (int i = 0; i < 2; ++i)
            af[i] = *(const bf16x8*)(S0 + (w * 32 + i * 16 + (lane & 15)) * LDW
                                     + kk * 32 + (lane >> 4) * 8);
        #pragma unroll
        for (int j = 0; j < 4; ++j)
            bfr[j] = *(const bf16x8*)(Xt + (j * 16 + (lane & 15)) * LDW
                                      + kk * 32 + (lane >> 4) * 8);
        #pragma unroll
        for (int i = 0; i < 2; ++i)
            #pragma unroll
            for (int j = 0; j < 4; ++j)
                yacc[i][j] = __builtin_amdgcn_mfma_f32_16x16x32_bf16(af[i], bfr[j], yacc[i][j], 0, 0, 0);
    }
    #pragma unroll
    for (int i = 0; i < 2; ++i)
        #pragma unroll
        for (int j = 0; j < 4; ++j)
            #pragma unroll
            for (int r = 0; r < 4; ++r) {
                int l = w * 32 + i * 16 + (lane >> 4) * 4 + r;
                int p = j * 16 + (lane & 15);
                y[(size_t)(row0 + l) * DINNER + h * HD + p] = f2b(yacc[i][j][r]);
            }
    __syncthreads();
    for (int i = tid; i < 128 * 32; i += 256) {
        int l = i >> 5, ng = (i & 31) * 4;
        ushort4 v = *(const ushort4*)(xbcb + (size_t)(row0 + l) * CONVCH + DINNER + ng);
        float d = dec_s[l];
        S0[(ng + 0) * LDW + l] = f2b(b2f(v.x) * d);
        S0[(ng + 1) * LDW + l] = f2b(b2f(v.y) * d);
        S0[(ng + 2) * LDW + l] = f2b(b2f(v.z) * d);
        S0[(ng + 3) * LDW + l] = f2b(b2f(v.w) * d);
    }
    __syncthreads();
    f32x4 tacc[8] = {};
    for (int kk = 0; kk < 4; ++kk) {
        bf16x8 afs = *(const bf16x8*)(Xt + (w * 16 + (lane & 15)) * LDW
                                      + kk * 32 + (lane >> 4) * 8);
        #pragma unroll
        for (int j = 0; j < 8; ++j) {
            bf16x8 bfs = *(const bf16x8*)(S0 + (j * 16 + (lane & 15)) * LDW
                                          + kk * 32 + (lane >> 4) * 8);
            tacc[j] = __builtin_amdgcn_mfma_f32_16x16x32_bf16(afs, bfs, tacc[j], 0, 0, 0);
        }
    }
    size_t sb = (size_t)blockIdx.x * (HD * DSTATE);
    #pragma unroll
    for (int j = 0; j < 8; ++j)
        #pragma unroll
        for (int r = 0; r < 4; ++r) {
            int p = w * 16 + (lane >> 4) * 4 + r;
            int n = j * 16 + (lane & 15);
            st[sb + (size_t)p * DSTATE + n] = f2b(tacc[j][r]);
        }
}

// ---------------- inter-chunk scan (in place, bf16), both dirs ----------------
__global__ void k_scan(u16* __restrict__ st0, const float* __restrict__ cd0)
{
    int i = blockIdx.x * blockDim.x + threadIdx.x;
    if (i >= 2 * BATCH * NH * HD * DSTATE) return;
    int dir = i >> 19;                  // BATCH*NH*HD*DSTATE == 1<<19
    int j = i & ((1 << 19) - 1);
    u16* st = st0 + (size_t)dir * N_ST;
    const float* cd = cd0 + (size_t)dir * BATCH * NH * NCH;
    int n = j & 127;
    int rest = j >> 7;
    int p = rest & 63; rest >>= 6;
    int h = rest & 31;
    int b = rest >> 5;
    float s = 0.f;
    for (int c = 0; c < NCH; ++c) {
        size_t idx = ((size_t)((b * NCH + c) * NH + h) * HD + p) * DSTATE + n;
        float v = b2f(st[idx]);
        st[idx] = f2b(s);                              // prev_c
        s = s * cd[(b * NH + h) * NCH + c] + v;        // carry (fp32)
    }
}

// ---------------- Y_off: y += exp(acs[l]) * C@prev^T + xh*D; z = dir ----------------
__global__ __launch_bounds__(256) void k_yoff(
    const u16* __restrict__ xbcb0, const u16* __restrict__ prev0,
    const float* __restrict__ acs0,
    const float* __restrict__ D_f, const float* __restrict__ D_b,
    u16* __restrict__ y0)
{
    int dir = blockIdx.z;
    const u16* xbcb = xbcb0 + (size_t)dir * T * CONVCH;
    const u16* prev = prev0 + (size_t)dir * N_ST;
    const float* acs = acs0 + (size_t)dir * BATCH * NH * NCH * CHUNK;
    const float* Dp = dir ? D_b : D_f;
    u16* y = y0 + (size_t)dir * T * DINNER;

    __shared__ u16 Pv[64 * LDW];
    __shared__ float acs_s[128];
    int tid = threadIdx.x, lane = tid & 63, w = tid >> 6;
    int h = blockIdx.x & 31;
    int bc = blockIdx.x >> 5;
    int c = bc & 15, b = bc >> 4;
    int row0 = b * SEQL + c * CHUNK;
    size_t sb = (size_t)blockIdx.x * (HD * DSTATE);
    for (int i = tid; i < 64 * 16; i += 256) {
        int p = i >> 4, m8 = (i & 15) * 8;
        *(uint4*)(Pv + p * LDW + m8) = *(const uint4*)(prev + sb + (size_t)p * DSTATE + m8);
    }
    if (tid < 128) acs_s[tid] = acs[(((size_t)(b * NH + h) * NCH + c) << 7) + tid];
    __syncthreads();
    const u16* cbase = xbcb + (size_t)row0 * CONVCH + DINNER + DSTATE;
    f32x4 acc[2][4] = {};
    for (int kk = 0; kk < 4; ++kk) {
        bf16x8 af[2], bfr[4];
        #pragma unroll
        for (int i = 0; i < 2; ++i)
            af[i] = *(const bf16x8*)(cbase + (size_t)(w * 32 + i * 16 + (lane & 15)) * CONVCH
                                     + kk * 32 + (lane >> 4) * 8);
        #pragma unroll
        for (int j = 0; j < 4; ++j)
            bfr[j] = *(const bf16x8*)(Pv + (j * 16 + (lane & 15)) * LDW
                                      + kk * 32 + (lane >> 4) * 8);
        #pragma unroll
        for (int i = 0; i < 2; ++i)
            #pragma unroll
            for (int j = 0; j < 4; ++j)
                acc[i][j] = __builtin_amdgcn_mfma_f32_16x16x32_bf16(af[i], bfr[j], acc[i][j], 0, 0, 0);
    }
    float Dh = Dp[h];
    #pragma unroll
    for (int i = 0; i < 2; ++i)
        #pragma unroll
        for (int j = 0; j < 4; ++j)
            #pragma unroll
            for (int r = 0; r < 4; ++r) {
                int l = w * 32 + i * 16 + (lane >> 4) * 4 + r;
                int p = j * 16 + (lane & 15);
                size_t yi = (size_t)(row0 + l) * DINNER + h * HD + p;
                float val = b2f(y[yi]) + __expf(acs_s[l]) * acc[i][j][r]
                          + b2f(xbcb[(size_t)(row0 + l) * CONVCH + h * HD + p]) * Dh;
                y[yi] = f2b(val);
            }
}

// ---------------- gated rmsnorm -> bf16; z = dir ----------------
__global__ __launch_bounds__(256) void k_gate(
    const u16* __restrict__ y0, const u16* __restrict__ zb0,
    const float* __restrict__ gw_f, const float* __restrict__ gw_b,
    u16* __restrict__ out0)
{
    int dir = blockIdx.z;
    const u16* y = y0 + (size_t)dir * T * DINNER;
    const u16* zb = zb0 + (size_t)dir * T * DINNER;
    const float* gw = dir ? gw_b : gw_f;
    u16* out = out0 + (size_t)dir * T * DINNER;

    int r = blockIdx.x;
    __shared__ float tbuf[DINNER];
    int tid = threadIdx.x;
    float ss = 0.f;
    #pragma unroll
    for (int it = 0; it < 2; ++it) {
        int i = (it * 256 + tid) * 4;
        ushort4 yv = *(const ushort4*)(y + (size_t)r * DINNER + i);
        ushort4 zv = *(const ushort4*)(zb + (size_t)r * DINNER + i);
        float z0 = b2f(zv.x), z1 = b2f(zv.y), z2 = b2f(zv.z), z3 = b2f(zv.w);
        float t0 = b2f(yv.x) * (z0 / (1.f + __expf(-z0)));
        float t1 = b2f(yv.y) * (z1 / (1.f + __expf(-z1)));
        float t2 = b2f(yv.z) * (z2 / (1.f + __expf(-z2)));
        float t3 = b2f(yv.w) * (z3 / (1.f + __expf(-z3)));
        tbuf[i] = t0; tbuf[i + 1] = t1; tbuf[i + 2] = t2; tbuf[i + 3] = t3;
        ss += t0 * t0 + t1 * t1 + t2 * t2 + t3 * t3;
    }
    float tot = blockReduceSum(ss);
    float sc = rsqrtf(tot / DINNER + EPS);
    #pragma unroll
    for (int it = 0; it < 2; ++it) {
        int i = (it * 256 + tid) * 4;
        ushort4 o;
        o.x = f2b(tbuf[i] * sc * gw[i]);
        o.y = f2b(tbuf[i + 1] * sc * gw[i + 1]);
        o.z = f2b(tbuf[i + 2] * sc * gw[i + 2]);
        o.w = f2b(tbuf[i + 3] * sc * gw[i + 3]);
        *(ushort4*)(out + (size_t)r * DINNER + i) = o;
    }
}

// ---------------- launch ----------------
extern "C" void kernel_launch(void* const* d_in, const int* in_sizes, int n_in,
                              void* d_out, int out_size, void* d_ws, size_t ws_size,
                              hipStream_t stream)
{
    const float* x         = (const float*)d_in[0];
    const float* norm_w    = (const float*)d_in[1];
    const float* out_w_blk = (const float*)d_in[2];
    const float* out_b_blk = (const float*)d_in[3];
    const float* f_in_w    = (const float*)d_in[4];
    const float* f_conv_w  = (const float*)d_in[5];
    const float* f_conv_b  = (const float*)d_in[6];
    const float* f_dt_bias = (const float*)d_in[7];
    const float* f_A_log   = (const float*)d_in[8];
    const float* f_D       = (const float*)d_in[9];
    const float* f_gnorm_w = (const float*)d_in[10];
    const float* f_out_w   = (const float*)d_in[11];
    const float* b_in_w    = (const float*)d_in[12];
    const float* b_conv_w  = (const float*)d_in[13];
    const float* b_conv_b  = (const float*)d_in[14];
    const float* b_dt_bias = (const float*)d_in[15];
    const float* b_A_log   = (const float*)d_in[16];
    const float* b_D       = (const float*)d_in[17];
    const float* b_gnorm_w = (const float*)d_in[18];
    const float* b_out_w   = (const float*)d_in[19];
    float* out = (float*)d_out;

    // ---- workspace layout with liveness overlap (~207 MiB) ----
    char* ws = (char*)d_ws;
    u16*  xnb    = (u16*)ws;   ws += (size_t)T * DMODEL * 2;
    u16*  zb     = (u16*)ws;   ws += (size_t)2 * T * DINNER * 2;
    u16*  xbcraw = (u16*)ws;   ws += (size_t)2 * T * CONVCH * 2;   // dead after conv -> y
    u16*  xbcb   = (u16*)ws;   ws += (size_t)2 * T * CONVCH * 2;   // dead after yoff -> Mcomb
    u16*  xdtb   = (u16*)ws;   ws += (size_t)2 * T * DINNER * 2;   // dead after chunk -> ybb
    float* dtb   = (float*)ws; ws += (size_t)2 * T * NH * 4;
    float* acs   = (float*)ws; ws += (size_t)2 * BATCH * NH * NCH * CHUNK * 4;
    float* cd    = (float*)ws; ws += (size_t)2 * BATCH * NH * NCH * 4;
    u16*  stb    = (u16*)ws;   ws += (size_t)2 * N_ST * 2;
    u16*  inwb   = (u16*)ws;   ws += (size_t)2 * N_INW * 2;
    u16*  fowT2  = (u16*)ws;   ws += (size_t)2 * N_OUTW * 2;       // transposed out_w (bf16)
    u16*  owbb   = (u16*)ws;   ws += (size_t)N_OUTW * 2;           // out_w_blk bf16
    // aliases
    u16*  yb16  = xbcraw;   // Y bf16 (2*T*DINNER <= 2*T*CONVCH)
    u16*  ybb   = xdtb;     // gated-norm output
    u16*  Mcomb = xbcb;     // combined weights 1024 x 4096 (8.4 MB <= 37.7 MB)

    k_rmsnorm<<<T, 256, 0, stream>>>(x, norm_w, xnb);
    {
        size_t tot = 2 * N_INW + N_OUTW;
        int blocks = (int)((tot / 4 + 255) / 256);
        k_f2b_all<<<blocks, 256, 0, stream>>>(f_in_w, b_in_w, out_w_blk, inwb, owbb);
    }
    {
        dim3 g(DINNER / 64, DMODEL / 64, 2);
        k_tw<<<g, 256, 0, stream>>>(f_out_w, b_out_w, fowT2);
    }

    // in-proj both dirs: z -> zb, xBC -> xbcraw
    {
        dim3 g(DPROJ2 / 128, T / 128, 2);
        k_mm_in<<<g, 256, 0, stream>>>(xnb, inwb, zb, xbcraw);
    }
    {
        dim3 g(T / 4, 1, 2);
        k_dt2<<<g, 256, 0, stream>>>(xnb, f_in_w, b_in_w, f_dt_bias, b_dt_bias, dtb);
    }
    {
        dim3 g((T * (CONVCH / 8) + 255) / 256, 1, 2);
        k_conv<<<g, 256, 0, stream>>>(xbcraw, f_conv_w, b_conv_w, f_conv_b, b_conv_b,
                                      dtb, xbcb, xdtb);
    }
    {
        dim3 g(BATCH * NH * NCH, 1, 2);
        k_acs<<<g, 128, 0, stream>>>(dtb, f_A_log, b_A_log, acs, cd);
    }
    {
        dim3 g(BATCH * NCH * NH, 1, 2);
        k_chunk<<<g, 256, 0, stream>>>(xbcb, xdtb, acs, yb16, stb);
    }
    k_scan<<<(2 * BATCH * NH * HD * DSTATE) / 256, 256, 0, stream>>>(stb, cd);
    {
        dim3 g(BATCH * NCH * NH, 1, 2);
        k_yoff<<<g, 256, 0, stream>>>(xbcb, stb, acs, f_D, b_D, yb16);
    }
    {
        dim3 g(T, 1, 2);
        k_gate<<<g, 256, 0, stream>>>(yb16, zb, f_gnorm_w, b_gnorm_w, ybb);
    }
    // combine weights: Mf/Mb[d,c] = sum_e owb[d, dir*1024+e] * out_w[e,c]  (xbcb dead -> Mcomb)
    {
        dim3 g(DINNER / 64, DMODEL / 64, 2);
        k_mm64<<<g, 256, 0, stream>>>(owbb, (size_t)DMODEL, DINNER,
                                      fowT2, N_OUTW, DMODEL,
                                      Mcomb, 2 * DINNER, DINNER);
    }
    // final fused: out = ybb_f @ Mf^T + flip(ybb_b) @ Mb^T + bias + x
    {
        dim3 g(DMODEL / 64, T / 64, 1);
        k_mm_fin<<<g, 256, 0, stream>>>(ybb, ybb + (size_t)T * DINNER, Mcomb,
                                        out, out_b_blk, x);
    }
}

// Round 9
// 587.636 us; speedup vs baseline: 7.6853x; 1.0238x over previous
//
#include <hip/hip_runtime.h>
#include <hip/hip_bf16.h>
#include <math.h>

#define BATCH 2
#define SEQL 2048
#define T 4096            // BATCH*SEQL tokens
#define DMODEL 1024
#define DINNER 2048
#define DSTATE 128
#define NH 32
#define HD 64
#define DPROJ2 4352       // z (2048) + xBC (2304); dt handled separately in fp32
#define CONVCH 2304
#define NCH 16            // chunks per sequence
#define CHUNK 128
#define EPS 1e-5f

#define N_INW ((size_t)DPROJ2 * DMODEL)   // 4,456,448
#define N_OUTW ((size_t)DMODEL * DINNER)  // 2,097,152
#define N_ST ((size_t)BATCH * NCH * NH * HD * DSTATE)  // 8,388,608 per dir

typedef unsigned short u16;
typedef __bf16 bf16x8 __attribute__((ext_vector_type(8)));
typedef float f32x4 __attribute__((ext_vector_type(4)));

__device__ __forceinline__ u16 f2b(float f) {
    union { float f; unsigned u; } v; v.f = f;
    unsigned r = v.u + 0x7fffu + ((v.u >> 16) & 1u);
    return (u16)(r >> 16);
}
__device__ __forceinline__ float b2f(u16 b) {
    union { unsigned u; float f; } v; v.u = ((unsigned)b) << 16;
    return v.f;
}
__device__ __forceinline__ int flipseq(int r) {
    return (r & ~(SEQL - 1)) | ((SEQL - 1) - (r & (SEQL - 1)));
}
__device__ __forceinline__ void gload16(const u16* g, u16* l) {
    __builtin_amdgcn_global_load_lds(
        (const __attribute__((address_space(1))) void*)g,
        (__attribute__((address_space(3))) void*)l, 16, 0, 0);
}

// ---------------- block reduce ----------------
__device__ __forceinline__ float blockReduceSum(float v) {
    __shared__ float red_[4];
    for (int off = 32; off > 0; off >>= 1) v += __shfl_down(v, off);
    int lane = threadIdx.x & 63, wid = threadIdx.x >> 6;
    if (lane == 0) red_[wid] = v;
    __syncthreads();
    if (threadIdx.x == 0) {
        float s = 0.f;
        int nw = blockDim.x >> 6;
        for (int i = 0; i < nw; ++i) s += red_[i];
        red_[0] = s;
    }
    __syncthreads();
    return red_[0];
}

// ---------------- input rmsnorm -> bf16 ----------------
__global__ __launch_bounds__(256) void k_rmsnorm(
    const float* __restrict__ x, const float* __restrict__ w,
    u16* __restrict__ outb)
{
    int row = blockIdx.x;
    const float* xr = x + (size_t)row * DMODEL;
    float ss = 0.f;
    for (int i = threadIdx.x; i < DMODEL; i += 256) { float v = xr[i]; ss += v * v; }
    float tot = blockReduceSum(ss);
    float sc = rsqrtf(tot / DMODEL + EPS);
    for (int i = threadIdx.x; i < DMODEL; i += 256)
        outb[(size_t)row * DMODEL + i] = f2b(xr[i] * sc * w[i]);
}

// ---------------- weights fp32 -> bf16 (in_w x2, out_w_blk) ----------------
__global__ void k_f2b_all(
    const float* __restrict__ s0, const float* __restrict__ s1,  // f_in_w, b_in_w
    const float* __restrict__ s4,                                // out_w_blk
    u16* __restrict__ d_inwb, u16* __restrict__ d_owbb)
{
    size_t i = ((size_t)blockIdx.x * 256 + threadIdx.x) * 4;
    const float* s; u16* d; size_t off;
    if (i < 2 * N_INW) {
        int dir = i >= N_INW;
        off = i - (size_t)dir * N_INW;
        s = dir ? s1 : s0; d = d_inwb + (size_t)dir * N_INW;
    } else {
        off = i - 2 * N_INW;
        if (off >= N_OUTW) return;
        s = s4; d = d_owbb;
    }
    float4 v = *(const float4*)(s + off);
    ushort4 o;
    o.x = f2b(v.x); o.y = f2b(v.y); o.z = f2b(v.z); o.w = f2b(v.w);
    *(ushort4*)(d + off) = o;
}

// ---------------- out_w (1024 x 2048) -> transposed bf16 (2048 x 1024); z = dir ----------------
__global__ __launch_bounds__(256) void k_tw(
    const float* __restrict__ fw, const float* __restrict__ bw, u16* __restrict__ dst)
{
    int dir = blockIdx.z;
    const float* src = dir ? bw : fw;
    u16* d = dst + (size_t)dir * N_OUTW;
    __shared__ u16 t[64][65];
    int e0 = blockIdx.y * 64, c0 = blockIdx.x * 64;
    for (int i = threadIdx.x; i < 64 * 16; i += 256) {
        int el = i >> 4, c4 = (i & 15) * 4;
        float4 v = *(const float4*)(src + (size_t)(e0 + el) * DINNER + c0 + c4);
        t[c4 + 0][el] = f2b(v.x); t[c4 + 1][el] = f2b(v.y);
        t[c4 + 2][el] = f2b(v.z); t[c4 + 3][el] = f2b(v.w);
    }
    __syncthreads();
    for (int i = threadIdx.x; i < 64 * 16; i += 256) {
        int cl = i >> 4, e4 = (i & 15) * 4;
        ushort4 o;
        o.x = t[cl][e4]; o.y = t[cl][e4 + 1]; o.z = t[cl][e4 + 2]; o.w = t[cl][e4 + 3];
        *(ushort4*)(d + (size_t)(c0 + cl) * DMODEL + e0 + e4) = o;
    }
}

// ---------------- in-proj: bf16 MFMA GEMM 128x128, BK=64 (two BK=32 panels), z = dir ----------------
__global__ __launch_bounds__(256, 4) void k_mm_in(
    const u16* __restrict__ A, const u16* __restrict__ W0,
    u16* __restrict__ zb0, u16* __restrict__ xbcraw0)
{
    const int K = DMODEL;
    int dir = blockIdx.z;
    const u16* W = W0 + (size_t)dir * N_INW;
    int m0 = blockIdx.y * 128, n0 = blockIdx.x * 128;

    // block-uniform output select
    u16* Cout;
    int ldcc, nbase;
    if (n0 < DINNER) {
        Cout = zb0 + (size_t)dir * T * DINNER;
        ldcc = DINNER;
        nbase = n0;
    } else {
        Cout = xbcraw0 + (size_t)dir * T * CONVCH;
        ldcc = CONVCH;
        nbase = n0 - DINNER;
    }

    __shared__ u16 As[2 * 128 * 32];
    __shared__ u16 Bs[2 * 128 * 32];
    int tid = threadIdx.x;
    int lane = tid & 63;
    int wrow = ((tid >> 6) & 1) * 64, wcol = (tid >> 7) * 64;

    int srow = tid >> 2, skof = (tid & 3) * 8;
    int ar1 = m0 + srow, ar2 = ar1 + 64;
    if (dir) { ar1 = flipseq(ar1); ar2 = flipseq(ar2); }
    const u16* ga1 = A + (size_t)ar1 * K + skof;
    const u16* ga2 = A + (size_t)ar2 * K + skof;
    const u16* gb1 = W + (size_t)(n0 + srow) * K + skof;
    const u16* gb2 = gb1 + (size_t)64 * K;
    u16* la1 = As + tid * 8;
    u16* la2 = As + 2048 + tid * 8;
    u16* lb1 = Bs + tid * 8;
    u16* lb2 = Bs + 2048 + tid * 8;

    int aoff[4], boff[4];
    #pragma unroll
    for (int i = 0; i < 4; ++i) {
        aoff[i] = (wrow + i * 16 + (lane & 15)) * 32 + ((lane >> 4) * 8);
        boff[i] = (wcol + i * 16 + (lane & 15)) * 32 + ((lane >> 4) * 8);
    }

    f32x4 acc[4][4] = {};
    for (int kt = 0; kt < K; kt += 64) {
        gload16(ga1, la1);        gload16(ga2, la2);
        gload16(ga1 + 32, la1 + 4096); gload16(ga2 + 32, la2 + 4096);
        gload16(gb1, lb1);        gload16(gb2, lb2);
        gload16(gb1 + 32, lb1 + 4096); gload16(gb2 + 32, lb2 + 4096);
        ga1 += 64; ga2 += 64; gb1 += 64; gb2 += 64;
        __syncthreads();
        #pragma unroll
        for (int ks = 0; ks < 2; ++ks) {
            bf16x8 af[4], bfv[4];
            #pragma unroll
            for (int i = 0; i < 4; ++i) af[i] = *(const bf16x8*)(As + ks * 4096 + aoff[i]);
            #pragma unroll
            for (int j = 0; j < 4; ++j) bfv[j] = *(const bf16x8*)(Bs + ks * 4096 + boff[j]);
            #pragma unroll
            for (int i = 0; i < 4; ++i)
                #pragma unroll
                for (int j = 0; j < 4; ++j)
                    acc[i][j] = __builtin_amdgcn_mfma_f32_16x16x32_bf16(af[i], bfv[j], acc[i][j], 0, 0, 0);
        }
        __syncthreads();
    }

    int rbase = m0 + wrow + ((lane >> 4) << 2);
    int cbase = nbase + wcol + (lane & 15);
    #pragma unroll
    for (int i = 0; i < 4; ++i)
        #pragma unroll
        for (int j = 0; j < 4; ++j)
            #pragma unroll
            for (int r = 0; r < 4; ++r)
                Cout[(size_t)(rbase + i * 16 + r) * ldcc + cbase + j * 16] = f2b(acc[i][j][r]);
}

// ---------------- bf16 MFMA GEMM, 64x64 tile, BK=64 two-panel, z-batched, lda-aware ----------------
__global__ __launch_bounds__(256) void k_mm64(
    const u16* __restrict__ A, size_t astride, int lda,
    const u16* __restrict__ W, size_t wstride, int K,
    u16* __restrict__ Cb, int ldc, int coffStride)
{
    int dir = blockIdx.z;
    A += (size_t)dir * astride;
    W += (size_t)dir * wstride;
    int coff = dir * coffStride;

    __shared__ u16 As[2 * 64 * 32];
    __shared__ u16 Bs[2 * 64 * 32];
    int tid = threadIdx.x;
    int lane = tid & 63;
    int w = tid >> 6;
    int m0 = blockIdx.y * 64, n0 = blockIdx.x * 64;
    int wrow = (w & 1) * 32, wcol = (w >> 1) * 32;

    int srow = tid >> 2, skof = (tid & 3) * 8;
    const u16* ga = A + (size_t)(m0 + srow) * lda + skof;
    const u16* gb = W + (size_t)(n0 + srow) * K + skof;
    u16* la = As + tid * 8;
    u16* lb = Bs + tid * 8;

    int aoff[2], boff[2];
    #pragma unroll
    for (int i = 0; i < 2; ++i) {
        aoff[i] = (wrow + i * 16 + (lane & 15)) * 32 + ((lane >> 4) * 8);
        boff[i] = (wcol + i * 16 + (lane & 15)) * 32 + ((lane >> 4) * 8);
    }

    f32x4 acc[2][2] = {};
    for (int kt = 0; kt < K; kt += 64) {
        gload16(ga, la);      gload16(ga + 32, la + 2048);
        gload16(gb, lb);      gload16(gb + 32, lb + 2048);
        ga += 64; gb += 64;
        __syncthreads();
        #pragma unroll
        for (int ks = 0; ks < 2; ++ks) {
            bf16x8 af[2], bfv[2];
            #pragma unroll
            for (int i = 0; i < 2; ++i) af[i] = *(const bf16x8*)(As + ks * 2048 + aoff[i]);
            #pragma unroll
            for (int j = 0; j < 2; ++j) bfv[j] = *(const bf16x8*)(Bs + ks * 2048 + boff[j]);
            #pragma unroll
            for (int i = 0; i < 2; ++i)
                #pragma unroll
                for (int j = 0; j < 2; ++j)
                    acc[i][j] = __builtin_amdgcn_mfma_f32_16x16x32_bf16(af[i], bfv[j], acc[i][j], 0, 0, 0);
        }
        __syncthreads();
    }

    int rbase = m0 + wrow + ((lane >> 4) << 2);
    int cbase = n0 + wcol + (lane & 15);
    #pragma unroll
    for (int i = 0; i < 2; ++i)
        #pragma unroll
        for (int j = 0; j < 2; ++j)
            #pragma unroll
            for (int r = 0; r < 4; ++r)
                Cb[(size_t)(rbase + i * 16 + r) * ldc + coff + cbase + j * 16] = f2b(acc[i][j][r]);
}

// ---------------- final fused GEMM: out = ybb_f@Mf^T + flip(ybb_b)@Mb^T + bias + x ----------------
__global__ __launch_bounds__(256) void k_mm_fin(
    const u16* __restrict__ A1, const u16* __restrict__ A2,
    const u16* __restrict__ W,      // Mcomb: 1024 x 4096 (Mf | Mb), k-contig
    float* __restrict__ out, const float* __restrict__ bias,
    const float* __restrict__ resid)
{
    __shared__ u16 As[2 * 64 * 32];
    __shared__ u16 Bs[2 * 64 * 32];
    int tid = threadIdx.x;
    int lane = tid & 63;
    int w = tid >> 6;
    int m0 = blockIdx.y * 64, n0 = blockIdx.x * 64;
    int wrow = (w & 1) * 32, wcol = (w >> 1) * 32;

    int srow = tid >> 2, skof = (tid & 3) * 8;
    const u16* ga1 = A1 + (size_t)(m0 + srow) * DINNER + skof;
    const u16* ga2 = A2 + (size_t)flipseq(m0 + srow) * DINNER + skof;
    const u16* gb = W + (size_t)(n0 + srow) * 4096 + skof;
    u16* la = As + tid * 8;
    u16* lb = Bs + tid * 8;

    int aoff[2], boff[2];
    #pragma unroll
    for (int i = 0; i < 2; ++i) {
        aoff[i] = (wrow + i * 16 + (lane & 15)) * 32 + ((lane >> 4) * 8);
        boff[i] = (wcol + i * 16 + (lane & 15)) * 32 + ((lane >> 4) * 8);
    }

    f32x4 acc[2][2] = {};
    #pragma unroll
    for (int half = 0; half < 2; ++half) {
        const u16* ga = half ? ga2 : ga1;
        for (int kt = 0; kt < DINNER; kt += 64) {
            gload16(ga, la);      gload16(ga + 32, la + 2048);
            gload16(gb, lb);      gload16(gb + 32, lb + 2048);
            ga += 64; gb += 64;
            __syncthreads();
            #pragma unroll
            for (int ks = 0; ks < 2; ++ks) {
                bf16x8 af[2], bfv[2];
                #pragma unroll
                for (int i = 0; i < 2; ++i) af[i] = *(const bf16x8*)(As + ks * 2048 + aoff[i]);
                #pragma unroll
                for (int j = 0; j < 2; ++j) bfv[j] = *(const bf16x8*)(Bs + ks * 2048 + boff[j]);
                #pragma unroll
                for (int i = 0; i < 2; ++i)
                    #pragma unroll
                    for (int j = 0; j < 2; ++j)
                        acc[i][j] = __builtin_amdgcn_mfma_f32_16x16x32_bf16(af[i], bfv[j], acc[i][j], 0, 0, 0);
            }
            __syncthreads();
        }
    }

    int rbase = m0 + wrow + ((lane >> 4) << 2);
    int cbase = n0 + wcol + (lane & 15);
    #pragma unroll
    for (int i = 0; i < 2; ++i)
        #pragma unroll
        for (int j = 0; j < 2; ++j)
            #pragma unroll
            for (int r = 0; r < 4; ++r) {
                int row = rbase + i * 16 + r, col = cbase + j * 16;
                out[(size_t)row * DMODEL + col] =
                    acc[i][j][r] + bias[col] + resid[(size_t)row * DMODEL + col];
            }
}

// ---------------- dt = softplus(xn . w_dt + bias), 4 rows/block, z = dir ----------------
__global__ __launch_bounds__(256) void k_dt2(
    const u16* __restrict__ xnb,
    const float* __restrict__ inw_f, const float* __restrict__ inw_b,
    const float* __restrict__ dtb_f, const float* __restrict__ dtb_b,
    float* __restrict__ dt)
{
    int dir = blockIdx.z;
    const float* wbase = dir ? inw_b : inw_f;
    const float* dtbia = dir ? dtb_b : dtb_f;
    float* dtp = dt + (size_t)dir * T * NH;

    int r0 = blockIdx.x * 4;
    __shared__ float xs[4][1024];
    int tid = threadIdx.x;
    #pragma unroll
    for (int rr = 0; rr < 4; ++rr) {
        int src = dir ? flipseq(r0 + rr) : (r0 + rr);
        ushort4 v = *(const ushort4*)(xnb + (size_t)src * DMODEL + tid * 4);
        xs[rr][tid * 4 + 0] = b2f(v.x); xs[rr][tid * 4 + 1] = b2f(v.y);
        xs[rr][tid * 4 + 2] = b2f(v.z); xs[rr][tid * 4 + 3] = b2f(v.w);
    }
    __syncthreads();
    int h = tid >> 3, part = tid & 7;
    const float* w = wbase + (size_t)(DPROJ2 + h) * DMODEL;
    float a0 = 0.f, a1 = 0.f, a2 = 0.f, a3 = 0.f;
    for (int kk = 0; kk < 128; ++kk) {
        int k = part + (kk << 3);
        float wv = w[k];
        a0 += xs[0][k] * wv; a1 += xs[1][k] * wv;
        a2 += xs[2][k] * wv; a3 += xs[3][k] * wv;
    }
    #pragma unroll
    for (int off = 4; off > 0; off >>= 1) {
        a0 += __shfl_down(a0, off, 8); a1 += __shfl_down(a1, off, 8);
        a2 += __shfl_down(a2, off, 8); a3 += __shfl_down(a3, off, 8);
    }
    if (part == 0) {
        float bsh = dtbia[h];
        float vv[4] = {a0, a1, a2, a3};
        #pragma unroll
        for (int rr = 0; rr < 4; ++rr) {
            float v = vv[rr] + bsh;
            dtp[(size_t)(r0 + rr) * NH + h] = (v > 20.f) ? v : log1pf(expf(v));
        }
    }
}

// ---------------- conv4 + silu -> bf16 xbcb; x-part * dt -> xdtb; z = dir ----------------
__global__ void k_conv(const u16* __restrict__ xraw0,
                       const float* __restrict__ cw_f, const float* __restrict__ cw_b,
                       const float* __restrict__ cb_f, const float* __restrict__ cb_b,
                       const float* __restrict__ dt0,
                       u16* __restrict__ xbcb0, u16* __restrict__ xdtb0)
{
    int dir = blockIdx.z;
    const u16* xraw = xraw0 + (size_t)dir * T * CONVCH;
    const float* cw = dir ? cw_b : cw_f;
    const float* cb = dir ? cb_b : cb_f;
    const float* dt = dt0 + (size_t)dir * T * NH;
    u16* xbcb = xbcb0 + (size_t)dir * T * CONVCH;
    u16* xdtb = xdtb0 + (size_t)dir * T * DINNER;

    int idx = blockIdx.x * blockDim.x + threadIdx.x;
    if (idx >= T * (CONVCH / 8)) return;
    int r = idx / (CONVCH / 8);
    int c8 = (idx - r * (CONVCH / 8)) * 8;
    int t = r & (SEQL - 1);
    int b0 = r - t;
    float4 cwv[8];
    #pragma unroll
    for (int j = 0; j < 8; ++j) cwv[j] = *(const float4*)(cw + (size_t)(c8 + j) * 4);
    float acc[8];
    {
        float4 c0 = *(const float4*)(cb + c8);
        float4 c1 = *(const float4*)(cb + c8 + 4);
        acc[0] = c0.x; acc[1] = c0.y; acc[2] = c0.z; acc[3] = c0.w;
        acc[4] = c1.x; acc[5] = c1.y; acc[6] = c1.z; acc[7] = c1.w;
    }
    #pragma unroll
    for (int k = 0; k < 4; ++k) {
        int tt = t + k - 3;
        if (tt < 0) continue;
        const u16* src = xraw + (size_t)(b0 + tt) * CONVCH + c8;
        ushort4 v0 = *(const ushort4*)src;
        ushort4 v1 = *(const ushort4*)(src + 4);
        float xv[8] = {b2f(v0.x), b2f(v0.y), b2f(v0.z), b2f(v0.w),
                       b2f(v1.x), b2f(v1.y), b2f(v1.z), b2f(v1.w)};
        #pragma unroll
        for (int j = 0; j < 8; ++j) {
            float wv = (k == 0) ? cwv[j].x : (k == 1) ? cwv[j].y : (k == 2) ? cwv[j].z : cwv[j].w;
            acc[j] += xv[j] * wv;
        }
    }
    ushort4 o0, o1;
    float s[8];
    #pragma unroll
    for (int j = 0; j < 8; ++j) s[j] = acc[j] / (1.f + __expf(-acc[j]));
    o0.x = f2b(s[0]); o0.y = f2b(s[1]); o0.z = f2b(s[2]); o0.w = f2b(s[3]);
    o1.x = f2b(s[4]); o1.y = f2b(s[5]); o1.z = f2b(s[6]); o1.w = f2b(s[7]);
    *(ushort4*)(xbcb + (size_t)r * CONVCH + c8) = o0;
    *(ushort4*)(xbcb + (size_t)r * CONVCH + c8 + 4) = o1;
    if (c8 < DINNER) {
        float dv = dt[(size_t)r * NH + (c8 >> 6)];
        ushort4 d0, d1;
        d0.x = f2b(s[0] * dv); d0.y = f2b(s[1] * dv); d0.z = f2b(s[2] * dv); d0.w = f2b(s[3] * dv);
        d1.x = f2b(s[4] * dv); d1.y = f2b(s[5] * dv); d1.z = f2b(s[6] * dv); d1.w = f2b(s[7] * dv);
        *(ushort4*)(xdtb + (size_t)r * DINNER + c8) = d0;
        *(ushort4*)(xdtb + (size_t)r * DINNER + c8 + 4) = d1;
    }
}

// ---------------- per-chunk cumsum of A*dt; z = dir ----------------
__global__ void k_acs(const float* __restrict__ dt0,
                      const float* __restrict__ Alog_f, const float* __restrict__ Alog_b,
                      float* __restrict__ acs0, float* __restrict__ cd0)
{
    int dir = blockIdx.z;
    const float* dt = dt0 + (size_t)dir * T * NH;
    const float* A_log = dir ? Alog_b : Alog_f;
    float* acs = acs0 + (size_t)dir * BATCH * NH * NCH * CHUNK;
    float* cd = cd0 + (size_t)dir * BATCH * NH * NCH;

    int bid = blockIdx.x;            // (b*NH + h)*NCH + c
    int c = bid & 15;
    int bh = bid >> 4;
    int h = bh & 31;
    int b = bh >> 5;
    int l = threadIdx.x;
    __shared__ float s[128];
    float Ah = -expf(A_log[h]);
    int r = b * SEQL + c * CHUNK + l;
    s[l] = Ah * dt[(size_t)r * NH + h];
    __syncthreads();
    for (int off = 1; off < 128; off <<= 1) {
        float t = (l >= off) ? s[l - off] : 0.f;
        __syncthreads();
        s[l] += t;
        __syncthreads();
    }
    acs[(size_t)bid * 128 + l] = s[l];
    if (l == 127) cd[bid] = expf(s[127]);
}

#define LDW 136
// ---------------- chunk states only: st = (X*dt)^T @ (B*dec); z = dir ----------------
__global__ __launch_bounds__(256) void k_states(
    const u16* __restrict__ xbcb0, const u16* __restrict__ xdtb0,
    const float* __restrict__ acs0, u16* __restrict__ st0)
{
    int dir = blockIdx.z;
    const u16* xbcb = xbcb0 + (size_t)dir * T * CONVCH;
    const u16* xdtb = xdtb0 + (size_t)dir * T * DINNER;
    const float* acs = acs0 + (size_t)dir * BATCH * NH * NCH * CHUNK;
    u16* st = st0 + (size_t)dir * N_ST;

    __shared__ u16 Bt[128 * LDW];   // Bt[n][l] = B[l][n]*dec[l]
    __shared__ u16 Xt[64 * LDW];    // Xt[p][l] = X[l][p]*dt[l]
    __shared__ float acs_s[128];
    __shared__ float dec_s[128];
    int tid = threadIdx.x;
    int lane = tid & 63;
    int w = tid >> 6;
    int h = blockIdx.x & 31;
    int bc = blockIdx.x >> 5;
    int c = bc & 15, b = bc >> 4;
    int row0 = b * SEQL + c * CHUNK;

    if (tid < 128)
        acs_s[tid] = acs[(((size_t)(b * NH + h) * NCH + c) << 7) + tid];
    for (int i = tid; i < 128 * 16; i += 256) {
        int l = i >> 4, pg = (i & 15) * 4;
        ushort4 v = *(const ushort4*)(xdtb + (size_t)(row0 + l) * DINNER + h * HD + pg);
        Xt[(pg + 0) * LDW + l] = v.x; Xt[(pg + 1) * LDW + l] = v.y;
        Xt[(pg + 2) * LDW + l] = v.z; Xt[(pg + 3) * LDW + l] = v.w;
    }
    __syncthreads();
    float a_last = acs_s[127];
    if (tid < 128) dec_s[tid] = __expf(a_last - acs_s[tid]);
    __syncthreads();
    for (int i = tid; i < 128 * 32; i += 256) {
        int l = i >> 5, ng = (i & 31) * 4;
        ushort4 v = *(const ushort4*)(xbcb + (size_t)(row0 + l) * CONVCH + DINNER + ng);
        float d = dec_s[l];
        Bt[(ng + 0) * LDW + l] = f2b(b2f(v.x) * d);
        Bt[(ng + 1) * LDW + l] = f2b(b2f(v.y) * d);
        Bt[(ng + 2) * LDW + l] = f2b(b2f(v.z) * d);
        Bt[(ng + 3) * LDW + l] = f2b(b2f(v.w) * d);
    }
    __syncthreads();
    f32x4 tacc[8] = {};
    for (int kk = 0; kk < 4; ++kk) {
        bf16x8 afs = *(const bf16x8*)(Xt + (w * 16 + (lane & 15)) * LDW
                                      + kk * 32 + (lane >> 4) * 8);
        #pragma unroll
        for (int j = 0; j < 8; ++j) {
            bf16x8 bfs = *(const bf16x8*)(Bt + (j * 16 + (lane & 15)) * LDW
                                          + kk * 32 + (lane >> 4) * 8);
            tacc[j] = __builtin_amdgcn_mfma_f32_16x16x32_bf16(afs, bfs, tacc[j], 0, 0, 0);
        }
    }
    size_t sb = (size_t)blockIdx.x * (HD * DSTATE);
    #pragma unroll
    for (int j = 0; j < 8; ++j)
        #pragma unroll
        for (int r = 0; r < 4; ++r) {
            int p = w * 16 + (lane >> 4) * 4 + r;
            int n = j * 16 + (lane & 15);
            st[sb + (size_t)p * DSTATE + n] = f2b(tacc[j][r]);
        }
}

// ---------------- inter-chunk scan (in place, bf16), both dirs ----------------
__global__ void k_scan(u16* __restrict__ st0, const float* __restrict__ cd0)
{
    int i = blockIdx.x * blockDim.x + threadIdx.x;
    if (i >= 2 * BATCH * NH * HD * DSTATE) return;
    int dir = i >> 19;                  // BATCH*NH*HD*DSTATE == 1<<19
    int j = i & ((1 << 19) - 1);
    u16* st = st0 + (size_t)dir * N_ST;
    const float* cd = cd0 + (size_t)dir * BATCH * NH * NCH;
    int n = j & 127;
    int rest = j >> 7;
    int p = rest & 63; rest >>= 6;
    int h = rest & 31;
    int b = rest >> 5;
    float s = 0.f;
    for (int c = 0; c < NCH; ++c) {
        size_t idx = ((size_t)((b * NCH + c) * NH + h) * HD + p) * DSTATE + n;
        float v = b2f(st[idx]);
        st[idx] = f2b(s);                              // prev_c
        s = s * cd[(b * NH + h) * NCH + c] + v;        // carry (fp32)
    }
}

// ---------------- fused per-(b,c,h): Y_diag + Y_off + xh*D -> y (single write); z = dir ----------------
__global__ __launch_bounds__(256) void k_chunk(
    const u16* __restrict__ xbcb0, const u16* __restrict__ xdtb0,
    const float* __restrict__ acs0, const u16* __restrict__ prev0,
    const float* __restrict__ D_f, const float* __restrict__ D_b,
    u16* __restrict__ y0)
{
    int dir = blockIdx.z;
    const u16* xbcb = xbcb0 + (size_t)dir * T * CONVCH;
    const u16* xdtb = xdtb0 + (size_t)dir * T * DINNER;
    const float* acs = acs0 + (size_t)dir * BATCH * NH * NCH * CHUNK;
    const u16* prev = prev0 + (size_t)dir * N_ST;
    const float* Dp = dir ? D_b : D_f;
    u16* y = y0 + (size_t)dir * T * DINNER;

    __shared__ u16 S0[128 * LDW];   // Bs -> Ps -> Pv(prev)
    __shared__ u16 Xt[64 * LDW];    // Xt[p][l] = X[l][p]*dt[l]
    __shared__ float acs_s[128];
    int tid = threadIdx.x;
    int lane = tid & 63;
    int w = tid >> 6;
    int h = blockIdx.x & 31;
    int bc = blockIdx.x >> 5;
    int c = bc & 15, b = bc >> 4;
    int row0 = b * SEQL + c * CHUNK;

    if (tid < 128)
        acs_s[tid] = acs[(((size_t)(b * NH + h) * NCH + c) << 7) + tid];
    // stage Bs: S0[s][n] = B[s][n]
    for (int i = tid; i < 128 * 16; i += 256) {
        int s = i >> 4, m8 = (i & 15) * 8;
        *(uint4*)(S0 + s * LDW + m8) =
            *(const uint4*)(xbcb + (size_t)(row0 + s) * CONVCH + DINNER + m8);
    }
    // stage Xt
    for (int i = tid; i < 128 * 16; i += 256) {
        int l = i >> 4, pg = (i & 15) * 4;
        ushort4 v = *(const ushort4*)(xdtb + (size_t)(row0 + l) * DINNER + h * HD + pg);
        Xt[(pg + 0) * LDW + l] = v.x; Xt[(pg + 1) * LDW + l] = v.y;
        Xt[(pg + 2) * LDW + l] = v.z; Xt[(pg + 3) * LDW + l] = v.w;
    }
    __syncthreads();

    // ---- S phase: S[l][s] = sum_n C[l][n]*B[s][n] (lower-triangular tiles only) ----
    int wrow = (w & 1) * 64, wcol = (w >> 1) * 64;
    const u16* cbase = xbcb + (size_t)row0 * CONVCH + DINNER + DSTATE;
    f32x4 sacc[4][4] = {};
    for (int kk = 0; kk < 4; ++kk) {
        bf16x8 af[4], bfr[4];
        #pragma unroll
        for (int i = 0; i < 4; ++i)
            af[i] = *(const bf16x8*)(cbase + (size_t)(wrow + i * 16 + (lane & 15)) * CONVCH
                                     + kk * 32 + (lane >> 4) * 8);
        #pragma unroll
        for (int j = 0; j < 4; ++j)
            bfr[j] = *(const bf16x8*)(S0 + (wcol + j * 16 + (lane & 15)) * LDW
                                      + kk * 32 + (lane >> 4) * 8);
        #pragma unroll
        for (int i = 0; i < 4; ++i)
            #pragma unroll
            for (int j = 0; j < 4; ++j)
                if (wcol + j * 16 <= wrow + i * 16 + 15)
                    sacc[i][j] = __builtin_amdgcn_mfma_f32_16x16x32_bf16(af[i], bfr[j], sacc[i][j], 0, 0, 0);
    }
    __syncthreads();
    // ---- mask * L -> P (bf16) into S0 ----
    #pragma unroll
    for (int i = 0; i < 4; ++i)
        #pragma unroll
        for (int j = 0; j < 4; ++j) {
            int s = wcol + j * 16 + (lane & 15);
            #pragma unroll
            for (int r = 0; r < 4; ++r) {
                int l = wrow + i * 16 + (lane >> 4) * 4 + r;
                float v = (s <= l) ? sacc[i][j][r] * __expf(acs_s[l] - acs_s[s]) : 0.f;
                S0[l * LDW + s] = f2b(v);
            }
        }
    __syncthreads();
    // ---- Y_diag: yacc = P @ Xt ----
    f32x4 yacc[2][4] = {};
    for (int kk = 0; kk < 4; ++kk) {
        bf16x8 af[2], bfr[4];
        #pragma unroll
        for (int i = 0; i < 2; ++i)
            af[i] = *(const bf16x8*)(S0 + (w * 32 + i * 16 + (lane & 15)) * LDW
                                     + kk * 32 + (lane >> 4) * 8);
        #pragma unroll
        for (int j = 0; j < 4; ++j)
            bfr[j] = *(const bf16x8*)(Xt + (j * 16 + (lane & 15)) * LDW
                                      + kk * 32 + (lane >> 4) * 8);
        #pragma unroll
        for (int i = 0; i < 2; ++i)
            #pragma unroll
            for (int j = 0; j < 4; ++j)
                yacc[i][j] = __builtin_amdgcn_mfma_f32_16x16x32_bf16(af[i], bfr[j], yacc[i][j], 0, 0, 0);
    }
    __syncthreads();
    // ---- stage Pv(prev) into S0 ----
    size_t sb = (size_t)blockIdx.x * (HD * DSTATE);
    for (int i = tid; i < 64 * 16; i += 256) {
        int p = i >> 4, m8 = (i & 15) * 8;
        *(uint4*)(S0 + p * LDW + m8) = *(const uint4*)(prev + sb + (size_t)p * DSTATE + m8);
    }
    __syncthreads();
    // ---- Y_off: oacc = C @ prev^T ----
    f32x4 oacc[2][4] = {};
    for (int kk = 0; kk < 4; ++kk) {
        bf16x8 af[2], bfr[4];
        #pragma unroll
        for (int i = 0; i < 2; ++i)
            af[i] = *(const bf16x8*)(cbase + (size_t)(w * 32 + i * 16 + (lane & 15)) * CONVCH
                                     + kk * 32 + (lane >> 4) * 8);
        #pragma unroll
        for (int j = 0; j < 4; ++j)
            bfr[j] = *(const bf16x8*)(S0 + (j * 16 + (lane & 15)) * LDW
                                      + kk * 32 + (lane >> 4) * 8);
        #pragma unroll
        for (int i = 0; i < 2; ++i)
            #pragma unroll
            for (int j = 0; j < 4; ++j)
                oacc[i][j] = __builtin_amdgcn_mfma_f32_16x16x32_bf16(af[i], bfr[j], oacc[i][j], 0, 0, 0);
    }
    // ---- epilogue: y = Ydiag + exp(acs)*Yoff + xh*D (single bf16 write) ----
    float Dh = Dp[h];
    #pragma unroll
    for (int i = 0; i < 2; ++i)
        #pragma unroll
        for (int j = 0; j < 4; ++j)
            #pragma unroll
            for (int r = 0; r < 4; ++r) {
                int l = w * 32 + i * 16 + (lane >> 4) * 4 + r;
                int p = j * 16 + (lane & 15);
                float val = yacc[i][j][r] + __expf(acs_s[l]) * oacc[i][j][r]
                          + b2f(xbcb[(size_t)(row0 + l) * CONVCH + h * HD + p]) * Dh;
                y[(size_t)(row0 + l) * DINNER + h * HD + p] = f2b(val);
            }
}

// ---------------- gated rmsnorm -> bf16; z = dir ----------------
__global__ __launch_bounds__(256) void k_gate(
    const u16* __restrict__ y0, const u16* __restrict__ zb0,
    const float* __restrict__ gw_f, const float* __restrict__ gw_b,
    u16* __restrict__ out0)
{
    int dir = blockIdx.z;
    const u16* y = y0 + (size_t)dir * T * DINNER;
    const u16* zb = zb0 + (size_t)dir * T * DINNER;
    const float* gw = dir ? gw_b : gw_f;
    u16* out = out0 + (size_t)dir * T * DINNER;

    int r = blockIdx.x;
    __shared__ float tbuf[DINNER];
    int tid = threadIdx.x;
    float ss = 0.f;
    #pragma unroll
    for (int it = 0; it < 2; ++it) {
        int i = (it * 256 + tid) * 4;
        ushort4 yv = *(const ushort4*)(y + (size_t)r * DINNER + i);
        ushort4 zv = *(const ushort4*)(zb + (size_t)r * DINNER + i);
        float z0 = b2f(zv.x), z1 = b2f(zv.y), z2 = b2f(zv.z), z3 = b2f(zv.w);
        float t0 = b2f(yv.x) * (z0 / (1.f + __expf(-z0)));
        float t1 = b2f(yv.y) * (z1 / (1.f + __expf(-z1)));
        float t2 = b2f(yv.z) * (z2 / (1.f + __expf(-z2)));
        float t3 = b2f(yv.w) * (z3 / (1.f + __expf(-z3)));
        tbuf[i] = t0; tbuf[i + 1] = t1; tbuf[i + 2] = t2; tbuf[i + 3] = t3;
        ss += t0 * t0 + t1 * t1 + t2 * t2 + t3 * t3;
    }
    float tot = blockReduceSum(ss);
    float sc = rsqrtf(tot / DINNER + EPS);
    #pragma unroll
    for (int it = 0; it < 2; ++it) {
        int i = (it * 256 + tid) * 4;
        ushort4 o;
        o.x = f2b(tbuf[i] * sc * gw[i]);
        o.y = f2b(tbuf[i + 1] * sc * gw[i + 1]);
        o.z = f2b(tbuf[i + 2] * sc * gw[i + 2]);
        o.w = f2b(tbuf[i + 3] * sc * gw[i + 3]);
        *(ushort4*)(out + (size_t)r * DINNER + i) = o;
    }
}

// ---------------- launch ----------------
extern "C" void kernel_launch(void* const* d_in, const int* in_sizes, int n_in,
                              void* d_out, int out_size, void* d_ws, size_t ws_size,
                              hipStream_t stream)
{
    const float* x         = (const float*)d_in[0];
    const float* norm_w    = (const float*)d_in[1];
    const float* out_w_blk = (const float*)d_in[2];
    const float* out_b_blk = (const float*)d_in[3];
    const float* f_in_w    = (const float*)d_in[4];
    const float* f_conv_w  = (const float*)d_in[5];
    const float* f_conv_b  = (const float*)d_in[6];
    const float* f_dt_bias = (const float*)d_in[7];
    const float* f_A_log   = (const float*)d_in[8];
    const float* f_D       = (const float*)d_in[9];
    const float* f_gnorm_w = (const float*)d_in[10];
    const float* f_out_w   = (const float*)d_in[11];
    const float* b_in_w    = (const float*)d_in[12];
    const float* b_conv_w  = (const float*)d_in[13];
    const float* b_conv_b  = (const float*)d_in[14];
    const float* b_dt_bias = (const float*)d_in[15];
    const float* b_A_log   = (const float*)d_in[16];
    const float* b_D       = (const float*)d_in[17];
    const float* b_gnorm_w = (const float*)d_in[18];
    const float* b_out_w   = (const float*)d_in[19];
    float* out = (float*)d_out;

    // ---- workspace layout with liveness overlap (~207 MiB) ----
    char* ws = (char*)d_ws;
    u16*  xnb    = (u16*)ws;   ws += (size_t)T * DMODEL * 2;
    u16*  zb     = (u16*)ws;   ws += (size_t)2 * T * DINNER * 2;
    u16*  xbcraw = (u16*)ws;   ws += (size_t)2 * T * CONVCH * 2;   // dead after conv -> y
    u16*  xbcb   = (u16*)ws;   ws += (size_t)2 * T * CONVCH * 2;   // dead after chunk -> Mcomb
    u16*  xdtb   = (u16*)ws;   ws += (size_t)2 * T * DINNER * 2;   // dead after chunk -> ybb
    float* dtb   = (float*)ws; ws += (size_t)2 * T * NH * 4;
    float* acs   = (float*)ws; ws += (size_t)2 * BATCH * NH * NCH * CHUNK * 4;
    float* cd    = (float*)ws; ws += (size_t)2 * BATCH * NH * NCH * 4;
    u16*  stb    = (u16*)ws;   ws += (size_t)2 * N_ST * 2;
    u16*  inwb   = (u16*)ws;   ws += (size_t)2 * N_INW * 2;
    u16*  fowT2  = (u16*)ws;   ws += (size_t)2 * N_OUTW * 2;       // transposed out_w (bf16)
    u16*  owbb   = (u16*)ws;   ws += (size_t)N_OUTW * 2;           // out_w_blk bf16
    // aliases
    u16*  yb16  = xbcraw;   // Y bf16 (2*T*DINNER <= 2*T*CONVCH)
    u16*  ybb   = xdtb;     // gated-norm output
    u16*  Mcomb = xbcb;     // combined weights 1024 x 4096 (8.4 MB <= 37.7 MB)

    k_rmsnorm<<<T, 256, 0, stream>>>(x, norm_w, xnb);
    {
        size_t tot = 2 * N_INW + N_OUTW;
        int blocks = (int)((tot / 4 + 255) / 256);
        k_f2b_all<<<blocks, 256, 0, stream>>>(f_in_w, b_in_w, out_w_blk, inwb, owbb);
    }
    {
        dim3 g(DINNER / 64, DMODEL / 64, 2);
        k_tw<<<g, 256, 0, stream>>>(f_out_w, b_out_w, fowT2);
    }

    // in-proj both dirs: z -> zb, xBC -> xbcraw
    {
        dim3 g(DPROJ2 / 128, T / 128, 2);
        k_mm_in<<<g, 256, 0, stream>>>(xnb, inwb, zb, xbcraw);
    }
    {
        dim3 g(T / 4, 1, 2);
        k_dt2<<<g, 256, 0, stream>>>(xnb, f_in_w, b_in_w, f_dt_bias, b_dt_bias, dtb);
    }
    {
        dim3 g((T * (CONVCH / 8) + 255) / 256, 1, 2);
        k_conv<<<g, 256, 0, stream>>>(xbcraw, f_conv_w, b_conv_w, f_conv_b, b_conv_b,
                                      dtb, xbcb, xdtb);
    }
    {
        dim3 g(BATCH * NH * NCH, 1, 2);
        k_acs<<<g, 128, 0, stream>>>(dtb, f_A_log, b_A_log, acs, cd);
    }
    {
        dim3 g(BATCH * NCH * NH, 1, 2);
        k_states<<<g, 256, 0, stream>>>(xbcb, xdtb, acs, stb);
    }
    k_scan<<<(2 * BATCH * NH * HD * DSTATE) / 256, 256, 0, stream>>>(stb, cd);
    {
        dim3 g(BATCH * NCH * NH, 1, 2);
        k_chunk<<<g, 256, 0, stream>>>(xbcb, xdtb, acs, stb, f_D, b_D, yb16);
    }
    {
        dim3 g(T, 1, 2);
        k_gate<<<g, 256, 0, stream>>>(yb16, zb, f_gnorm_w, b_gnorm_w, ybb);
    }
    // combine weights: Mf/Mb[d,c] = sum_e owb[d, dir*1024+e] * out_w[e,c]  (xbcb dead -> Mcomb)
    {
        dim3 g(DINNER / 64, DMODEL / 64, 2);
        k_mm64<<<g, 256, 0, stream>>>(owbb, (size_t)DMODEL, DINNER,
                                      fowT2, N_OUTW, DMODEL,
                                      Mcomb, 2 * DINNER, DINNER);
    }
    // final fused: out = ybb_f @ Mf^T + flip(ybb_b) @ Mb^T + bias + x
    {
        dim3 g(DMODEL / 64, T / 64, 1);
        k_mm_fin<<<g, 256, 0, stream>>>(ybb, ybb + (size_t)T * DINNER, Mcomb,
                                        out, out_b_blk, x);
    }
}